// Round 2
// baseline (1091.780 us; speedup 1.0000x reference)
//
#include <hip/hip_runtime.h>
#include <hip/hip_bf16.h>

// ---- problem constants ----
#define N_NODES 32768
#define NGRAPH  64
#define NPG     512
#define TOPK    256
#define HID     256
#define FDIM    768
#define NEDGE   262144
#define NCLS    10
#define BN_EPS  1e-5f

// dtype switches: NaN oracle from round 1 says inputs are fp32 (fp32 read as
// bf16 => ~0.4% NaN shorts => NaN logits, which is what we saw). Outputs fp32.
#define IN_BF16 0
#define OUT_BF16 0

typedef __attribute__((ext_vector_type(8))) short short8;
typedef __attribute__((ext_vector_type(4))) float f32x4;

__device__ __forceinline__ float bf2f(unsigned short u) {
    return __uint_as_float(((unsigned)u) << 16);
}
__device__ __forceinline__ unsigned short f2bf(float f) {
    unsigned x = __float_as_uint(f);
    unsigned r = (x + 0x7fffu + ((x >> 16) & 1u)) >> 16;
    return (unsigned short)r;
}
__device__ __forceinline__ float in_ld(const void* p, size_t i) {
#if IN_BF16
    return bf2f(((const unsigned short*)p)[i]);
#else
    return ((const float*)p)[i];
#endif
}
__device__ __forceinline__ void st_out(void* o, size_t i, float v) {
#if OUT_BF16
    ((unsigned short*)o)[i] = f2bf(v);
#else
    ((float*)o)[i] = v;
#endif
}

// ---------------- fp32 -> bf16 conversion for GEMM operands ----------------
__global__ __launch_bounds__(256) void cvt_kernel(const float* __restrict__ in,
                                                  unsigned short* __restrict__ out, int n) {
    int i = blockIdx.x * 256 + threadIdx.x;
    if (i < n) out[i] = f2bf(in[i]);
}

// ---------------- edge dtype detection + CSR build ----------------
// If edge_index is int64 (little-endian, values < 2^31), every odd 32-bit word is 0.
__global__ __launch_bounds__(256) void detect_kernel(const int* __restrict__ eb, int* __restrict__ flag) {
    int i = blockIdx.x * 256 + threadIdx.x;          // i < NEDGE
    int v = eb[2 * (size_t)i + 1];
    unsigned long long b = __ballot(v != 0);
    if ((threadIdx.x & 63) == 0 && b)
        atomicAdd(flag, (int)__popcll(b));
}

__global__ __launch_bounds__(256) void hist_kernel(const int* __restrict__ eb, const int* __restrict__ flag,
                                                   int* __restrict__ deg) {
    int e = blockIdx.x * 256 + threadIdx.x;
    int st = (*flag == 0) ? 2 : 1;                   // 0 nonzero odd words -> int64 layout
    unsigned d = ((const unsigned*)eb)[(size_t)(NEDGE + e) * st] & (N_NODES - 1);
    atomicAdd(&deg[d], 1);
}

__global__ __launch_bounds__(256) void dinv_kernel(const int* __restrict__ deg, float* __restrict__ dinv) {
    int i = blockIdx.x * 256 + threadIdx.x;
    dinv[i] = rsqrtf((float)deg[i] + 1.0f);
}

__global__ __launch_bounds__(1024) void scan_kernel(const int* __restrict__ cnt, int* __restrict__ rowptr,
                                                    int* __restrict__ cursor) {
    __shared__ int part[1024];
    int t = threadIdx.x;
    int base = t * 32;
    int loc[32];
    int s = 0;
#pragma unroll
    for (int i = 0; i < 32; i++) { loc[i] = cnt[base + i]; s += loc[i]; }
    part[t] = s;
    __syncthreads();
    for (int off = 1; off < 1024; off <<= 1) {
        int v = (t >= off) ? part[t - off] : 0;
        __syncthreads();
        part[t] += v;
        __syncthreads();
    }
    int run = (t == 0) ? 0 : part[t - 1];
#pragma unroll
    for (int i = 0; i < 32; i++) {
        rowptr[base + i] = run;
        cursor[base + i] = run;
        run += loc[i];
    }
    if (t == 1023) rowptr[N_NODES] = run;
}

__global__ __launch_bounds__(256) void scatter_kernel(const int* __restrict__ eb, const int* __restrict__ flag,
                                                      int* __restrict__ cursor, int* __restrict__ srcs) {
    int e = blockIdx.x * 256 + threadIdx.x;
    int st = (*flag == 0) ? 2 : 1;
    unsigned s = ((const unsigned*)eb)[(size_t)e * st] & (N_NODES - 1);
    unsigned d = ((const unsigned*)eb)[(size_t)(NEDGE + e) * st] & (N_NODES - 1);
    int p = atomicAdd(&cursor[d], 1);
    srcs[p] = (int)s;
}

// ---------------- MFMA GEMM: C[M x Nn] = A[M x K](bf16, ld=K) @ W[K x Nn](bf16) ----------------
// epi: 0 = none, 1 = sigmoid. bias (fp32) may be null. C is bf16.
__global__ __launch_bounds__(256) void gemm_kernel(const unsigned short* __restrict__ A,
                                                   const unsigned short* __restrict__ W,
                                                   const void* __restrict__ bias,
                                                   unsigned short* __restrict__ C,
                                                   int M, int K, int Nn, int ldC, int colOff, int epi) {
    __shared__ short As[64][36];
    __shared__ short Bs[64][36];
    const int tid = threadIdx.x;
    const int bm = blockIdx.x * 64;
    const int bn = blockIdx.y * 64;
    const int wave = tid >> 6;
    const int lane = tid & 63;
    const int l15 = lane & 15;
    const int q = lane >> 4;
    const int wm = (wave >> 1) * 32;
    const int wn = (wave & 1) * 32;

    f32x4 acc[2][2] = {};

    const int ar = tid >> 2, ac = (tid & 3) * 8;   // A tile: 64 x 32
    const int br = tid >> 3, bc = (tid & 7) * 8;   // W tile: 32 x 64

    union U8 { uint4 u; short8 s; };

    for (int k0 = 0; k0 < K; k0 += 32) {
        __syncthreads();
        uint4 av = *(const uint4*)(A + (size_t)(bm + ar) * K + k0 + ac);
        uint4 wv = *(const uint4*)(W + (size_t)(k0 + br) * Nn + bn + bc);
        *(uint2*)&As[ar][ac]     = make_uint2(av.x, av.y);
        *(uint2*)&As[ar][ac + 4] = make_uint2(av.z, av.w);
        unsigned short wt[8];
        *(uint4*)wt = wv;
#pragma unroll
        for (int j = 0; j < 8; j++) Bs[bc + j][br] = (short)wt[j];
        __syncthreads();

        short8 af[2], bfr[2];
#pragma unroll
        for (int t = 0; t < 2; t++) {
            const short* pa = &As[wm + t * 16 + l15][q * 8];
            uint2 lo = *(const uint2*)pa;
            uint2 hi = *(const uint2*)(pa + 4);
            U8 ua; ua.u = make_uint4(lo.x, lo.y, hi.x, hi.y);
            af[t] = ua.s;
            const short* pb = &Bs[wn + t * 16 + l15][q * 8];
            uint2 lo2 = *(const uint2*)pb;
            uint2 hi2 = *(const uint2*)(pb + 4);
            U8 ub; ub.u = make_uint4(lo2.x, lo2.y, hi2.x, hi2.y);
            bfr[t] = ub.s;
        }
#pragma unroll
        for (int tm = 0; tm < 2; tm++)
#pragma unroll
            for (int tn = 0; tn < 2; tn++)
                acc[tm][tn] = __builtin_amdgcn_mfma_f32_16x16x32_bf16(af[tm], bfr[tn], acc[tm][tn], 0, 0, 0);
    }

#pragma unroll
    for (int tm = 0; tm < 2; tm++) {
#pragma unroll
        for (int tn = 0; tn < 2; tn++) {
#pragma unroll
            for (int r = 0; r < 4; r++) {
                int row = bm + wm + tm * 16 + q * 4 + r;
                int col = bn + wn + tn * 16 + l15;
                float v = acc[tm][tn][r];
                if (bias) v += in_ld(bias, col);
                if (epi == 1) v = 1.0f / (1.0f + __expf(-v));
                C[(size_t)row * ldC + colOff + col] = f2bf(v);
            }
        }
    }
}

// ---------------- GCN aggregation (256-dim), fused self-loop + bias + optional leaky-relu ----------------
// h bf16, bias fp32, out bf16
__global__ __launch_bounds__(256) void agg_kernel(const unsigned short* __restrict__ h,
                                                  const int* __restrict__ rowptr, const int* __restrict__ srcs,
                                                  const float* __restrict__ dinv, const void* __restrict__ bias,
                                                  unsigned short* __restrict__ out, int ldOut, int colOff,
                                                  int do_lrelu) {
    int wave = threadIdx.x >> 6, lane = threadIdx.x & 63;
    int v = blockIdx.x * 4 + wave;
    int f0 = lane * 4;
    float a0 = 0.f, a1 = 0.f, a2 = 0.f, a3 = 0.f;
    int s = rowptr[v], e = rowptr[v + 1];
    for (int i = s; i < e; i++) {
        int u = srcs[i] & (N_NODES - 1);
        float du = dinv[u];
        uint2 hv = *(const uint2*)(h + (size_t)u * 256 + f0);
        a0 += bf2f((unsigned short)(hv.x & 0xffff)) * du;
        a1 += bf2f((unsigned short)(hv.x >> 16)) * du;
        a2 += bf2f((unsigned short)(hv.y & 0xffff)) * du;
        a3 += bf2f((unsigned short)(hv.y >> 16)) * du;
    }
    float dv = dinv[v], dv2 = dv * dv;
    uint2 sv = *(const uint2*)(h + (size_t)v * 256 + f0);
    float r0 = dv * a0 + bf2f((unsigned short)(sv.x & 0xffff)) * dv2 + in_ld(bias, f0 + 0);
    float r1 = dv * a1 + bf2f((unsigned short)(sv.x >> 16)) * dv2 + in_ld(bias, f0 + 1);
    float r2 = dv * a2 + bf2f((unsigned short)(sv.y & 0xffff)) * dv2 + in_ld(bias, f0 + 2);
    float r3 = dv * a3 + bf2f((unsigned short)(sv.y >> 16)) * dv2 + in_ld(bias, f0 + 3);
    if (do_lrelu) {
        r0 = r0 > 0.f ? r0 : 0.01f * r0;
        r1 = r1 > 0.f ? r1 : 0.01f * r1;
        r2 = r2 > 0.f ? r2 : 0.01f * r2;
        r3 = r3 > 0.f ? r3 : 0.01f * r3;
    }
    unsigned o0 = f2bf(r0), o1 = f2bf(r1), o2 = f2bf(r2), o3 = f2bf(r3);
    uint2 ov = make_uint2((o1 << 16) | o0, (o3 << 16) | o2);
    *(uint2*)(out + (size_t)v * ldOut + colOff + f0) = ov;
}

// ---------------- score matvec: sv = h_final @ w (768 -> 1), fp32 accumulate ----------------
__global__ __launch_bounds__(256) void score_mv_kernel(const unsigned short* __restrict__ hf,
                                                       const void* __restrict__ wp, const void* __restrict__ wn,
                                                       float* __restrict__ svp, float* __restrict__ svn) {
    int wave = threadIdx.x >> 6, lane = threadIdx.x & 63;
    int v = blockIdx.x * 4 + wave;
    float sp = 0.f, sn = 0.f;
#pragma unroll
    for (int i = 0; i < 3; i++) {
        int k = i * 256 + lane * 4;
        uint2 hv = *(const uint2*)(hf + (size_t)v * 768 + k);
        float x0 = bf2f((unsigned short)(hv.x & 0xffff));
        float x1 = bf2f((unsigned short)(hv.x >> 16));
        float x2 = bf2f((unsigned short)(hv.y & 0xffff));
        float x3 = bf2f((unsigned short)(hv.y >> 16));
        sp += x0 * in_ld(wp, k) + x1 * in_ld(wp, k + 1) + x2 * in_ld(wp, k + 2) + x3 * in_ld(wp, k + 3);
        sn += x0 * in_ld(wn, k) + x1 * in_ld(wn, k + 1) + x2 * in_ld(wn, k + 2) + x3 * in_ld(wn, k + 3);
    }
    for (int off = 32; off >= 1; off >>= 1) {
        sp += __shfl_down(sp, off, 64);
        sn += __shfl_down(sn, off, 64);
    }
    if (lane == 0) { svp[v] = sp; svn[v] = sn; }
}

// ---------------- scalar GCN agg on scores + sigmoid; writes fp32 ws + outputs ----------------
__global__ __launch_bounds__(256) void score_agg_kernel(const float* __restrict__ svp, const float* __restrict__ svn,
                                                        const int* __restrict__ rowptr, const int* __restrict__ srcs,
                                                        const float* __restrict__ dinv,
                                                        const void* __restrict__ bp, const void* __restrict__ bn_,
                                                        float* __restrict__ scp, float* __restrict__ scn,
                                                        void* __restrict__ dout) {
    int v = blockIdx.x * 256 + threadIdx.x;
    float ap = 0.f, an = 0.f;
    int s = rowptr[v], e = rowptr[v + 1];
    for (int i = s; i < e; i++) {
        int u = srcs[i] & (N_NODES - 1);
        float du = dinv[u];
        ap += svp[u] * du;
        an += svn[u] * du;
    }
    float dv = dinv[v], dv2 = dv * dv;
    float zp = dv * ap + svp[v] * dv2 + in_ld(bp, 0);
    float zn = dv * an + svn[v] * dv2 + in_ld(bn_, 0);
    float pp = 1.0f / (1.0f + __expf(-zp));
    float pn = 1.0f / (1.0f + __expf(-zn));
    scp[v] = pp;
    scn[v] = pn;
    st_out(dout, 1920 + (size_t)v, pp);
    st_out(dout, 1920 + (size_t)N_NODES + v, pn);
}

// ---------------- top-k mask per graph (rank counting, matches jax.lax.top_k stable ties) ----------------
__global__ __launch_bounds__(512) void topk_kernel(const float* __restrict__ sc, unsigned char* __restrict__ mask) {
    __shared__ float s[512];
    int g = blockIdx.x, i = threadIdx.x;
    float my = sc[(size_t)g * 512 + i];
    s[i] = my;
    __syncthreads();
    int cnt = 0;
    for (int j = 0; j < 512; j++) {
        float o = s[j];
        cnt += (int)((o > my) || ((o == my) && (j < i)));
    }
    mask[(size_t)g * 512 + i] = (cnt < TOPK) ? 1 : 0;
}

// ---------------- masked mean/max readout -> e[(base+g) x 1536] (fp32) ----------------
__global__ __launch_bounds__(256) void readout_kernel(const unsigned short* __restrict__ xt,
                                                      const unsigned char* __restrict__ mask,
                                                      float* __restrict__ eout, int base) {
    int g = blockIdx.x, t = threadIdx.x;
    float s0 = 0.f, s1 = 0.f, s2 = 0.f;
    float m0 = -1e30f, m1 = -1e30f, m2 = -1e30f;
    const unsigned char* mk = mask + (size_t)g * 512;
    for (int v = 0; v < 512; v++) {
        if (mk[v]) {
            const unsigned short* row = xt + (size_t)(g * 512 + v) * 768;
            float x0 = bf2f(row[t]);
            float x1 = bf2f(row[t + 256]);
            float x2 = bf2f(row[t + 512]);
            s0 += x0; s1 += x1; s2 += x2;
            m0 = fmaxf(m0, x0); m1 = fmaxf(m1, x1); m2 = fmaxf(m2, x2);
        }
    }
    float* er = eout + (size_t)(base + g) * 1536;
    er[t] = s0 * (1.0f / TOPK);
    er[t + 256] = s1 * (1.0f / TOPK);
    er[t + 512] = s2 * (1.0f / TOPK);
    er[768 + t] = m0;
    er[768 + t + 256] = m1;
    er[768 + t + 512] = m2;
}

// ---------------- tiny MLP pieces (fp32 weights) ----------------
__global__ __launch_bounds__(256) void mlp_gemm_kernel(const float* __restrict__ in, const void* __restrict__ W,
                                                       const void* __restrict__ b, float* __restrict__ out, int K) {
    __shared__ float row[1536];
    int r = blockIdx.x, c = threadIdx.x;
    for (int k = c; k < K; k += 256) row[k] = in[(size_t)r * K + k];
    __syncthreads();
    float acc = in_ld(b, c);
    for (int k = 0; k < K; k++) acc += row[k] * in_ld(W, (size_t)k * 256 + c);
    out[(size_t)r * 256 + c] = acc;
}

// BN over each group of 64 rows (population var) + relu + optional residual
__global__ __launch_bounds__(64) void bn_kernel(const float* __restrict__ z, const void* __restrict__ gamma,
                                                const void* __restrict__ beta, const float* __restrict__ res,
                                                float* __restrict__ out) {
    int f = blockIdx.x & 255, g = blockIdx.x >> 8, r = threadIdx.x;
    size_t idx = (size_t)(g * 64 + r) * 256 + f;
    float x = z[idx];
    float s = x, sq = x * x;
    for (int off = 1; off < 64; off <<= 1) {
        s += __shfl_xor(s, off, 64);
        sq += __shfl_xor(sq, off, 64);
    }
    float m = s * (1.0f / 64.0f);
    float var = sq * (1.0f / 64.0f) - m * m;
    float y = (x - m) * rsqrtf(var + BN_EPS) * in_ld(gamma, f) + in_ld(beta, f);
    y = fmaxf(y, 0.0f);
    if (res) y += res[idx];
    out[idx] = y;
}

__global__ __launch_bounds__(64) void logits_kernel(const float* __restrict__ act, const void* __restrict__ w4,
                                                    const void* __restrict__ b4, float* __restrict__ lg) {
    int idx = blockIdx.x * 64 + threadIdx.x;
    if (idx >= 128 * NCLS) return;
    int r = idx / NCLS, c = idx % NCLS;
    float acc = in_ld(b4, c);
    for (int k = 0; k < 256; k++) acc += act[(size_t)r * 256 + k] * in_ld(w4, (size_t)k * NCLS + c);
    lg[idx] = acc;
}

__global__ __launch_bounds__(64) void softmax_kernel(const float* __restrict__ lg, void* __restrict__ dout) {
    int r = blockIdx.x * 64 + threadIdx.x;
    if (r >= 128) return;
    float l[NCLS];
    float mx = -1e30f;
    for (int c = 0; c < NCLS; c++) { l[c] = lg[(size_t)r * NCLS + c]; mx = fmaxf(mx, l[c]); }
    float sum = 0.f;
    float ex[NCLS];
    for (int c = 0; c < NCLS; c++) { ex[c] = __expf(l[c] - mx); sum += ex[c]; }
    float inv = 1.0f / sum;
    int g = r >> 6, rr = r & 63;
    if (g == 0) {
        for (int c = 0; c < NCLS; c++) st_out(dout, (size_t)rr * NCLS + c, l[c]);              // logits_pos
        for (int c = 0; c < NCLS; c++) st_out(dout, 640 + (size_t)rr * NCLS + c, ex[c] * inv); // probs_pos
    } else {
        for (int c = 0; c < NCLS; c++) st_out(dout, 1280 + (size_t)rr * NCLS + c, ex[c] * inv); // probs_neg
    }
}

__global__ __launch_bounds__(256) void batch_kernel(void* __restrict__ dout) {
    int i = blockIdx.x * 256 + threadIdx.x;
    st_out(dout, 1920 + 2 * (size_t)N_NODES + i, (float)(i >> 9));
}

// ---------------- host launcher ----------------
extern "C" void kernel_launch(void* const* d_in, const int* in_sizes, int n_in,
                              void* d_out, int out_size, void* d_ws, size_t ws_size,
                              hipStream_t stream) {
    (void)in_sizes; (void)n_in; (void)out_size; (void)ws_size;

    const float* x = (const float*)d_in[0];
    const int* eb = (const int*)d_in[1];
    const float* w_s1 = (const float*)d_in[3];
    const void* b_s1 = d_in[4];
    const float* w_s21 = (const float*)d_in[5];
    const void* b_s21 = d_in[6];
    const float* w_s22 = (const float*)d_in[7];
    const void* b_s22 = d_in[8];
    const float* w_raw = (const float*)d_in[9];
    const void* b_raw = d_in[10];
    const void* w_pos = d_in[11];
    const void* b_pos = d_in[12];
    const void* w_neg = d_in[13];
    const void* b_neg = d_in[14];
    const float* w_pool = (const float*)d_in[15];
    const void* b_pool = d_in[16];
    const void* w1 = d_in[17];  const void* b1 = d_in[18];  const void* g1 = d_in[19];  const void* be1 = d_in[20];
    const void* w2 = d_in[21];  const void* b2 = d_in[22];  const void* g2 = d_in[23];  const void* be2 = d_in[24];
    const void* w3 = d_in[25];  const void* b3 = d_in[26];  const void* g3 = d_in[27];  const void* be3 = d_in[28];
    const void* w4 = d_in[29];  const void* b4 = d_in[30];

    char* ws = (char*)d_ws;
    size_t off = 0;
    auto alloc = [&](size_t b) -> void* {
        void* p = ws + off;
        off += (b + 255) & ~(size_t)255;
        return p;
    };
    int* flag = (int*)alloc(256);
    int* deg = (int*)alloc((size_t)N_NODES * 4);
    float* dinv = (float*)alloc((size_t)N_NODES * 4);
    int* rowptr = (int*)alloc((size_t)(N_NODES + 1) * 4);
    int* cursor = (int*)alloc((size_t)N_NODES * 4);
    int* srcs = (int*)alloc((size_t)NEDGE * 4);
    unsigned short* xbf = (unsigned short*)alloc((size_t)N_NODES * 256 * 2);
    unsigned short* wb_s1 = (unsigned short*)alloc((size_t)256 * 256 * 2);
    unsigned short* wb_s21 = (unsigned short*)alloc((size_t)256 * 256 * 2);
    unsigned short* wb_s22 = (unsigned short*)alloc((size_t)256 * 256 * 2);
    unsigned short* wb_raw = (unsigned short*)alloc((size_t)256 * 256 * 2);
    unsigned short* wb_pool = (unsigned short*)alloc((size_t)768 * 768 * 2);
    unsigned short* tmpA = (unsigned short*)alloc((size_t)N_NODES * 256 * 2);
    unsigned short* tmpB = (unsigned short*)alloc((size_t)N_NODES * 256 * 2);
    unsigned short* hfin = (unsigned short*)alloc((size_t)N_NODES * 768 * 2);
    unsigned short* xt = (unsigned short*)alloc((size_t)N_NODES * 768 * 2);
    float* svp = (float*)alloc((size_t)N_NODES * 4);
    float* svn = (float*)alloc((size_t)N_NODES * 4);
    float* scp = (float*)alloc((size_t)N_NODES * 4);
    float* scn = (float*)alloc((size_t)N_NODES * 4);
    unsigned char* maskp = (unsigned char*)alloc(N_NODES);
    unsigned char* maskn = (unsigned char*)alloc(N_NODES);
    float* ebuf = (float*)alloc((size_t)128 * 1536 * 4);
    float* zb = (float*)alloc((size_t)128 * 256 * 4);
    float* act1 = (float*)alloc((size_t)128 * 256 * 4);
    float* act2 = (float*)alloc((size_t)128 * 256 * 4);
    float* act3 = (float*)alloc((size_t)128 * 256 * 4);
    float* lg = (float*)alloc((size_t)128 * NCLS * 4);

    hipMemsetAsync(flag, 0, 256, stream);
    hipMemsetAsync(deg, 0, (size_t)N_NODES * 4, stream);
    detect_kernel<<<NEDGE / 256, 256, 0, stream>>>(eb, flag);
    hist_kernel<<<NEDGE / 256, 256, 0, stream>>>(eb, flag, deg);
    dinv_kernel<<<N_NODES / 256, 256, 0, stream>>>(deg, dinv);
    scan_kernel<<<1, 1024, 0, stream>>>(deg, rowptr, cursor);
    scatter_kernel<<<NEDGE / 256, 256, 0, stream>>>(eb, flag, cursor, srcs);

    // fp32 -> bf16 conversions for MFMA operands
    cvt_kernel<<<(N_NODES * 256 + 255) / 256, 256, 0, stream>>>(x, xbf, N_NODES * 256);
    cvt_kernel<<<(256 * 256 + 255) / 256, 256, 0, stream>>>(w_s1, wb_s1, 256 * 256);
    cvt_kernel<<<(256 * 256 + 255) / 256, 256, 0, stream>>>(w_s21, wb_s21, 256 * 256);
    cvt_kernel<<<(256 * 256 + 255) / 256, 256, 0, stream>>>(w_s22, wb_s22, 256 * 256);
    cvt_kernel<<<(256 * 256 + 255) / 256, 256, 0, stream>>>(w_raw, wb_raw, 256 * 256);
    cvt_kernel<<<(768 * 768 + 255) / 256, 256, 0, stream>>>(w_pool, wb_pool, 768 * 768);

    dim3 gA(N_NODES / 64, 256 / 64);   // (512, 4)
    dim3 gP(N_NODES / 64, 768 / 64);   // (512, 12)

    // h_s1 branch
    gemm_kernel<<<gA, 256, 0, stream>>>(xbf, wb_s1, nullptr, tmpA, N_NODES, 256, 256, 256, 0, 0);
    agg_kernel<<<N_NODES / 4, 256, 0, stream>>>(tmpA, rowptr, srcs, dinv, b_s1, hfin, 768, 0, 1);
    // h_s2 branch (two GCN layers)
    gemm_kernel<<<gA, 256, 0, stream>>>(xbf, wb_s21, nullptr, tmpA, N_NODES, 256, 256, 256, 0, 0);
    agg_kernel<<<N_NODES / 4, 256, 0, stream>>>(tmpA, rowptr, srcs, dinv, b_s21, tmpB, 256, 0, 1);
    gemm_kernel<<<gA, 256, 0, stream>>>(tmpB, wb_s22, nullptr, tmpA, N_NODES, 256, 256, 256, 0, 0);
    agg_kernel<<<N_NODES / 4, 256, 0, stream>>>(tmpA, rowptr, srcs, dinv, b_s22, hfin, 768, 256, 1);
    // h_raw
    gemm_kernel<<<gA, 256, 0, stream>>>(xbf, wb_raw, b_raw, hfin, N_NODES, 256, 256, 768, 512, 0);
    // xt = sigmoid(h_final @ w_pool + b_pool)
    gemm_kernel<<<gP, 256, 0, stream>>>(hfin, wb_pool, b_pool, xt, N_NODES, 768, 768, 768, 0, 1);
    // scores
    score_mv_kernel<<<N_NODES / 4, 256, 0, stream>>>(hfin, w_pos, w_neg, svp, svn);
    score_agg_kernel<<<N_NODES / 256, 256, 0, stream>>>(svp, svn, rowptr, srcs, dinv, b_pos, b_neg, scp, scn, d_out);
    // top-k + readout
    topk_kernel<<<NGRAPH, 512, 0, stream>>>(scp, maskp);
    topk_kernel<<<NGRAPH, 512, 0, stream>>>(scn, maskn);
    readout_kernel<<<NGRAPH, 256, 0, stream>>>(xt, maskp, ebuf, 0);
    readout_kernel<<<NGRAPH, 256, 0, stream>>>(xt, maskn, ebuf, 64);
    // MLP (128 rows = pos 0..63, neg 64..127; BN stats per 64-row group)
    mlp_gemm_kernel<<<128, 256, 0, stream>>>(ebuf, w1, b1, zb, 1536);
    bn_kernel<<<512, 64, 0, stream>>>(zb, g1, be1, nullptr, act1);
    mlp_gemm_kernel<<<128, 256, 0, stream>>>(act1, w2, b2, zb, 256);
    bn_kernel<<<512, 64, 0, stream>>>(zb, g2, be2, act1, act2);
    mlp_gemm_kernel<<<128, 256, 0, stream>>>(act2, w3, b3, zb, 256);
    bn_kernel<<<512, 64, 0, stream>>>(zb, g3, be3, act2, act3);
    logits_kernel<<<(128 * NCLS + 63) / 64, 64, 0, stream>>>(act3, w4, b4, lg);
    softmax_kernel<<<2, 64, 0, stream>>>(lg, d_out);
    batch_kernel<<<N_NODES / 256, 256, 0, stream>>>(d_out);
}

// Round 3
// 788.864 us; speedup vs baseline: 1.3840x; 1.3840x over previous
//
#include <hip/hip_runtime.h>
#include <hip/hip_bf16.h>

// ---- problem constants ----
#define N_NODES 32768
#define NGRAPH  64
#define NPG     512
#define TOPK    256
#define HID     256
#define FDIM    768
#define NEDGE   262144
#define NCLS    10
#define BN_EPS  1e-5f

// inputs/outputs are fp32 (verified round 2); MFMA internals bf16
#define IN_BF16 0
#define OUT_BF16 0

typedef __attribute__((ext_vector_type(8))) short short8;
typedef __attribute__((ext_vector_type(4))) float f32x4;

__device__ __forceinline__ float bf2f(unsigned short u) {
    return __uint_as_float(((unsigned)u) << 16);
}
__device__ __forceinline__ unsigned short f2bf(float f) {
    unsigned x = __float_as_uint(f);
    unsigned r = (x + 0x7fffu + ((x >> 16) & 1u)) >> 16;
    return (unsigned short)r;
}
__device__ __forceinline__ float in_ld(const void* p, size_t i) {
#if IN_BF16
    return bf2f(((const unsigned short*)p)[i]);
#else
    return ((const float*)p)[i];
#endif
}
__device__ __forceinline__ void st_out(void* o, size_t i, float v) {
#if OUT_BF16
    ((unsigned short*)o)[i] = f2bf(v);
#else
    ((float*)o)[i] = v;
#endif
}

// ---------------- fp32 -> bf16 conversion for GEMM operands ----------------
__global__ __launch_bounds__(256) void cvt_kernel(const float* __restrict__ in,
                                                  unsigned short* __restrict__ out, int n) {
    int i = blockIdx.x * 256 + threadIdx.x;
    if (i < n) out[i] = f2bf(in[i]);
}

// ---------------- edge dtype detection + CSR build ----------------
// If edge_index is int64 (little-endian, values < 2^31), every odd 32-bit word is 0.
__global__ __launch_bounds__(256) void detect_kernel(const int* __restrict__ eb, int* __restrict__ flag) {
    int i = blockIdx.x * 256 + threadIdx.x;          // i < NEDGE
    int v = eb[2 * (size_t)i + 1];
    unsigned long long b = __ballot(v != 0);
    if ((threadIdx.x & 63) == 0 && b)
        atomicAdd(flag, (int)__popcll(b));
}

__global__ __launch_bounds__(256) void hist_kernel(const int* __restrict__ eb, const int* __restrict__ flag,
                                                   int* __restrict__ deg) {
    int e = blockIdx.x * 256 + threadIdx.x;
    int st = (*flag == 0) ? 2 : 1;                   // 0 nonzero odd words -> int64 layout
    unsigned d = ((const unsigned*)eb)[(size_t)(NEDGE + e) * st] & (N_NODES - 1);
    atomicAdd(&deg[d], 1);
}

__global__ __launch_bounds__(256) void dinv_kernel(const int* __restrict__ deg, float* __restrict__ dinv) {
    int i = blockIdx.x * 256 + threadIdx.x;
    dinv[i] = rsqrtf((float)deg[i] + 1.0f);
}

__global__ __launch_bounds__(1024) void scan_kernel(const int* __restrict__ cnt, int* __restrict__ rowptr,
                                                    int* __restrict__ cursor) {
    __shared__ int part[1024];
    int t = threadIdx.x;
    int base = t * 32;
    int loc[32];
    int s = 0;
#pragma unroll
    for (int i = 0; i < 32; i++) { loc[i] = cnt[base + i]; s += loc[i]; }
    part[t] = s;
    __syncthreads();
    for (int off = 1; off < 1024; off <<= 1) {
        int v = (t >= off) ? part[t - off] : 0;
        __syncthreads();
        part[t] += v;
        __syncthreads();
    }
    int run = (t == 0) ? 0 : part[t - 1];
#pragma unroll
    for (int i = 0; i < 32; i++) {
        rowptr[base + i] = run;
        cursor[base + i] = run;
        run += loc[i];
    }
    if (t == 1023) rowptr[N_NODES] = run;
}

__global__ __launch_bounds__(256) void scatter_kernel(const int* __restrict__ eb, const int* __restrict__ flag,
                                                      int* __restrict__ cursor, int* __restrict__ srcs) {
    int e = blockIdx.x * 256 + threadIdx.x;
    int st = (*flag == 0) ? 2 : 1;
    unsigned s = ((const unsigned*)eb)[(size_t)e * st] & (N_NODES - 1);
    unsigned d = ((const unsigned*)eb)[(size_t)(NEDGE + e) * st] & (N_NODES - 1);
    int p = atomicAdd(&cursor[d], 1);
    srcs[p] = (int)s;
}

// ---------------- MFMA GEMM: C[M x Nn] = A[M x K](bf16, ld=K) @ W[K x Nn](bf16) ----------------
// epi: 0 = none, 1 = sigmoid. bias (fp32) may be null. C is bf16.
__global__ __launch_bounds__(256) void gemm_kernel(const unsigned short* __restrict__ A,
                                                   const unsigned short* __restrict__ W,
                                                   const void* __restrict__ bias,
                                                   unsigned short* __restrict__ C,
                                                   int M, int K, int Nn, int ldC, int colOff, int epi) {
    __shared__ short As[64][36];
    __shared__ short Bs[64][36];
    const int tid = threadIdx.x;
    const int bm = blockIdx.x * 64;
    const int bn = blockIdx.y * 64;
    const int wave = tid >> 6;
    const int lane = tid & 63;
    const int l15 = lane & 15;
    const int q = lane >> 4;
    const int wm = (wave >> 1) * 32;
    const int wn = (wave & 1) * 32;

    f32x4 acc[2][2] = {};

    const int ar = tid >> 2, ac = (tid & 3) * 8;   // A tile: 64 x 32
    const int br = tid >> 3, bc = (tid & 7) * 8;   // W tile: 32 x 64

    union U8 { uint4 u; short8 s; };

    for (int k0 = 0; k0 < K; k0 += 32) {
        __syncthreads();
        uint4 av = *(const uint4*)(A + (size_t)(bm + ar) * K + k0 + ac);
        uint4 wv = *(const uint4*)(W + (size_t)(k0 + br) * Nn + bn + bc);
        *(uint2*)&As[ar][ac]     = make_uint2(av.x, av.y);
        *(uint2*)&As[ar][ac + 4] = make_uint2(av.z, av.w);
        unsigned short wt[8];
        *(uint4*)wt = wv;
#pragma unroll
        for (int j = 0; j < 8; j++) Bs[bc + j][br] = (short)wt[j];
        __syncthreads();

        short8 af[2], bfr[2];
#pragma unroll
        for (int t = 0; t < 2; t++) {
            const short* pa = &As[wm + t * 16 + l15][q * 8];
            uint2 lo = *(const uint2*)pa;
            uint2 hi = *(const uint2*)(pa + 4);
            U8 ua; ua.u = make_uint4(lo.x, lo.y, hi.x, hi.y);
            af[t] = ua.s;
            const short* pb = &Bs[wn + t * 16 + l15][q * 8];
            uint2 lo2 = *(const uint2*)pb;
            uint2 hi2 = *(const uint2*)(pb + 4);
            U8 ub; ub.u = make_uint4(lo2.x, lo2.y, hi2.x, hi2.y);
            bfr[t] = ub.s;
        }
#pragma unroll
        for (int tm = 0; tm < 2; tm++)
#pragma unroll
            for (int tn = 0; tn < 2; tn++)
                acc[tm][tn] = __builtin_amdgcn_mfma_f32_16x16x32_bf16(af[tm], bfr[tn], acc[tm][tn], 0, 0, 0);
    }

#pragma unroll
    for (int tm = 0; tm < 2; tm++) {
#pragma unroll
        for (int tn = 0; tn < 2; tn++) {
#pragma unroll
            for (int r = 0; r < 4; r++) {
                int row = bm + wm + tm * 16 + q * 4 + r;
                int col = bn + wn + tn * 16 + l15;
                float v = acc[tm][tn][r];
                if (bias) v += in_ld(bias, col);
                if (epi == 1) v = 1.0f / (1.0f + __expf(-v));
                C[(size_t)row * ldC + colOff + col] = f2bf(v);
            }
        }
    }
}

// ---------------- GCN aggregation (256-dim), fused self-loop + bias + optional leaky-relu ----------------
// h bf16, bias fp32, out bf16
__global__ __launch_bounds__(256) void agg_kernel(const unsigned short* __restrict__ h,
                                                  const int* __restrict__ rowptr, const int* __restrict__ srcs,
                                                  const float* __restrict__ dinv, const void* __restrict__ bias,
                                                  unsigned short* __restrict__ out, int ldOut, int colOff,
                                                  int do_lrelu) {
    int wave = threadIdx.x >> 6, lane = threadIdx.x & 63;
    int v = blockIdx.x * 4 + wave;
    int f0 = lane * 4;
    float a0 = 0.f, a1 = 0.f, a2 = 0.f, a3 = 0.f;
    int s = rowptr[v], e = rowptr[v + 1];
    for (int i = s; i < e; i++) {
        int u = srcs[i] & (N_NODES - 1);
        float du = dinv[u];
        uint2 hv = *(const uint2*)(h + (size_t)u * 256 + f0);
        a0 += bf2f((unsigned short)(hv.x & 0xffff)) * du;
        a1 += bf2f((unsigned short)(hv.x >> 16)) * du;
        a2 += bf2f((unsigned short)(hv.y & 0xffff)) * du;
        a3 += bf2f((unsigned short)(hv.y >> 16)) * du;
    }
    float dv = dinv[v], dv2 = dv * dv;
    uint2 sv = *(const uint2*)(h + (size_t)v * 256 + f0);
    float r0 = dv * a0 + bf2f((unsigned short)(sv.x & 0xffff)) * dv2 + in_ld(bias, f0 + 0);
    float r1 = dv * a1 + bf2f((unsigned short)(sv.x >> 16)) * dv2 + in_ld(bias, f0 + 1);
    float r2 = dv * a2 + bf2f((unsigned short)(sv.y & 0xffff)) * dv2 + in_ld(bias, f0 + 2);
    float r3 = dv * a3 + bf2f((unsigned short)(sv.y >> 16)) * dv2 + in_ld(bias, f0 + 3);
    if (do_lrelu) {
        r0 = r0 > 0.f ? r0 : 0.01f * r0;
        r1 = r1 > 0.f ? r1 : 0.01f * r1;
        r2 = r2 > 0.f ? r2 : 0.01f * r2;
        r3 = r3 > 0.f ? r3 : 0.01f * r3;
    }
    unsigned o0 = f2bf(r0), o1 = f2bf(r1), o2 = f2bf(r2), o3 = f2bf(r3);
    uint2 ov = make_uint2((o1 << 16) | o0, (o3 << 16) | o2);
    *(uint2*)(out + (size_t)v * ldOut + colOff + f0) = ov;
}

// ---------------- score matvec: sv = h_final @ w (768 -> 1), fp32 accumulate ----------------
__global__ __launch_bounds__(256) void score_mv_kernel(const unsigned short* __restrict__ hf,
                                                       const void* __restrict__ wp, const void* __restrict__ wn,
                                                       float* __restrict__ svp, float* __restrict__ svn) {
    int wave = threadIdx.x >> 6, lane = threadIdx.x & 63;
    int v = blockIdx.x * 4 + wave;
    float sp = 0.f, sn = 0.f;
#pragma unroll
    for (int i = 0; i < 3; i++) {
        int k = i * 256 + lane * 4;
        uint2 hv = *(const uint2*)(hf + (size_t)v * 768 + k);
        float x0 = bf2f((unsigned short)(hv.x & 0xffff));
        float x1 = bf2f((unsigned short)(hv.x >> 16));
        float x2 = bf2f((unsigned short)(hv.y & 0xffff));
        float x3 = bf2f((unsigned short)(hv.y >> 16));
        sp += x0 * in_ld(wp, k) + x1 * in_ld(wp, k + 1) + x2 * in_ld(wp, k + 2) + x3 * in_ld(wp, k + 3);
        sn += x0 * in_ld(wn, k) + x1 * in_ld(wn, k + 1) + x2 * in_ld(wn, k + 2) + x3 * in_ld(wn, k + 3);
    }
    for (int off = 32; off >= 1; off >>= 1) {
        sp += __shfl_down(sp, off, 64);
        sn += __shfl_down(sn, off, 64);
    }
    if (lane == 0) { svp[v] = sp; svn[v] = sn; }
}

// ---------------- scalar GCN agg on scores + sigmoid; writes fp32 ws + outputs ----------------
__global__ __launch_bounds__(256) void score_agg_kernel(const float* __restrict__ svp, const float* __restrict__ svn,
                                                        const int* __restrict__ rowptr, const int* __restrict__ srcs,
                                                        const float* __restrict__ dinv,
                                                        const void* __restrict__ bp, const void* __restrict__ bn_,
                                                        float* __restrict__ scp, float* __restrict__ scn,
                                                        void* __restrict__ dout) {
    int v = blockIdx.x * 256 + threadIdx.x;
    float ap = 0.f, an = 0.f;
    int s = rowptr[v], e = rowptr[v + 1];
    for (int i = s; i < e; i++) {
        int u = srcs[i] & (N_NODES - 1);
        float du = dinv[u];
        ap += svp[u] * du;
        an += svn[u] * du;
    }
    float dv = dinv[v], dv2 = dv * dv;
    float zp = dv * ap + svp[v] * dv2 + in_ld(bp, 0);
    float zn = dv * an + svn[v] * dv2 + in_ld(bn_, 0);
    float pp = 1.0f / (1.0f + __expf(-zp));
    float pn = 1.0f / (1.0f + __expf(-zn));
    scp[v] = pp;
    scn[v] = pn;
    st_out(dout, 1920 + (size_t)v, pp);
    st_out(dout, 1920 + (size_t)N_NODES + v, pn);
}

// ---------------- top-k mask per graph (rank counting, matches jax.lax.top_k stable ties) ----------------
__global__ __launch_bounds__(512) void topk_kernel(const float* __restrict__ sc, unsigned char* __restrict__ mask) {
    __shared__ float s[512];
    int g = blockIdx.x, i = threadIdx.x;
    float my = sc[(size_t)g * 512 + i];
    s[i] = my;
    __syncthreads();
    int cnt = 0;
    for (int j = 0; j < 512; j++) {
        float o = s[j];
        cnt += (int)((o > my) || ((o == my) && (j < i)));
    }
    mask[(size_t)g * 512 + i] = (cnt < TOPK) ? 1 : 0;
}

// ---------------- fused dual-mask readout ----------------
// grid (NGRAPH, FDIM/64); block 256 = 4 node-slices x 64 feature lanes.
// Reads xt once, produces pos rows [0..63] and neg rows [64..127] of e[128 x 1536].
__global__ __launch_bounds__(256) void readout2_kernel(const unsigned short* __restrict__ xt,
                                                       const unsigned char* __restrict__ maskp,
                                                       const unsigned char* __restrict__ maskn,
                                                       float* __restrict__ eout) {
    int g = blockIdx.x;
    int c = blockIdx.y;
    int wv = threadIdx.x >> 6, lane = threadIdx.x & 63;
    int f = c * 64 + lane;
    __shared__ unsigned char mp[512], mn[512];
    __shared__ float red[4][64][4];
    for (int i = threadIdx.x; i < 512; i += 256) {
        mp[i] = maskp[(size_t)g * 512 + i];
        mn[i] = maskn[(size_t)g * 512 + i];
    }
    __syncthreads();
    float sp = 0.f, sn = 0.f, xp = -INFINITY, xn = -INFINITY;
    const unsigned short* base = xt + ((size_t)g * 512 + wv * 128) * 768 + f;
    for (int v = 0; v < 128; v++) {
        float x = bf2f(base[(size_t)v * 768]);
        // mask bytes are wave-uniform (same v for all 64 lanes) -> no divergence
        if (mp[wv * 128 + v]) { sp += x; xp = fmaxf(xp, x); }
        if (mn[wv * 128 + v]) { sn += x; xn = fmaxf(xn, x); }
    }
    red[wv][lane][0] = sp; red[wv][lane][1] = xp;
    red[wv][lane][2] = sn; red[wv][lane][3] = xn;
    __syncthreads();
    if (wv == 0) {
#pragma unroll
        for (int w = 1; w < 4; w++) {
            sp += red[w][lane][0]; xp = fmaxf(xp, red[w][lane][1]);
            sn += red[w][lane][2]; xn = fmaxf(xn, red[w][lane][3]);
        }
        float* erp = eout + (size_t)g * 1536;
        float* ern = eout + (size_t)(64 + g) * 1536;
        erp[f] = sp * (1.0f / TOPK);
        erp[768 + f] = xp;
        ern[f] = sn * (1.0f / TOPK);
        ern[768 + f] = xn;
    }
}

// ---------------- tiny MLP pieces (fp32 weights) ----------------
__global__ __launch_bounds__(256) void mlp_gemm_kernel(const float* __restrict__ in, const void* __restrict__ W,
                                                       const void* __restrict__ b, float* __restrict__ out, int K) {
    __shared__ float row[1536];
    int r = blockIdx.x, c = threadIdx.x;
    for (int k = c; k < K; k += 256) row[k] = in[(size_t)r * K + k];
    __syncthreads();
    float acc = in_ld(b, c);
    for (int k = 0; k < K; k++) acc += row[k] * in_ld(W, (size_t)k * 256 + c);
    out[(size_t)r * 256 + c] = acc;
}

// BN over each group of 64 rows (population var) + relu + optional residual
__global__ __launch_bounds__(64) void bn_kernel(const float* __restrict__ z, const void* __restrict__ gamma,
                                                const void* __restrict__ beta, const float* __restrict__ res,
                                                float* __restrict__ out) {
    int f = blockIdx.x & 255, g = blockIdx.x >> 8, r = threadIdx.x;
    size_t idx = (size_t)(g * 64 + r) * 256 + f;
    float x = z[idx];
    float s = x, sq = x * x;
    for (int off = 1; off < 64; off <<= 1) {
        s += __shfl_xor(s, off, 64);
        sq += __shfl_xor(sq, off, 64);
    }
    float m = s * (1.0f / 64.0f);
    float var = sq * (1.0f / 64.0f) - m * m;
    float y = (x - m) * rsqrtf(var + BN_EPS) * in_ld(gamma, f) + in_ld(beta, f);
    y = fmaxf(y, 0.0f);
    if (res) y += res[idx];
    out[idx] = y;
}

__global__ __launch_bounds__(64) void logits_kernel(const float* __restrict__ act, const void* __restrict__ w4,
                                                    const void* __restrict__ b4, float* __restrict__ lg) {
    int idx = blockIdx.x * 64 + threadIdx.x;
    if (idx >= 128 * NCLS) return;
    int r = idx / NCLS, c = idx % NCLS;
    float acc = in_ld(b4, c);
    for (int k = 0; k < 256; k++) acc += act[(size_t)r * 256 + k] * in_ld(w4, (size_t)k * NCLS + c);
    lg[idx] = acc;
}

__global__ __launch_bounds__(64) void softmax_kernel(const float* __restrict__ lg, void* __restrict__ dout) {
    int r = blockIdx.x * 64 + threadIdx.x;
    if (r >= 128) return;
    float l[NCLS];
    float mx = -1e30f;
    for (int c = 0; c < NCLS; c++) { l[c] = lg[(size_t)r * NCLS + c]; mx = fmaxf(mx, l[c]); }
    float sum = 0.f;
    float ex[NCLS];
    for (int c = 0; c < NCLS; c++) { ex[c] = __expf(l[c] - mx); sum += ex[c]; }
    float inv = 1.0f / sum;
    int g = r >> 6, rr = r & 63;
    if (g == 0) {
        for (int c = 0; c < NCLS; c++) st_out(dout, (size_t)rr * NCLS + c, l[c]);              // logits_pos
        for (int c = 0; c < NCLS; c++) st_out(dout, 640 + (size_t)rr * NCLS + c, ex[c] * inv); // probs_pos
    } else {
        for (int c = 0; c < NCLS; c++) st_out(dout, 1280 + (size_t)rr * NCLS + c, ex[c] * inv); // probs_neg
    }
}

__global__ __launch_bounds__(256) void batch_kernel(void* __restrict__ dout) {
    int i = blockIdx.x * 256 + threadIdx.x;
    st_out(dout, 1920 + 2 * (size_t)N_NODES + i, (float)(i >> 9));
}

// ---------------- host launcher ----------------
extern "C" void kernel_launch(void* const* d_in, const int* in_sizes, int n_in,
                              void* d_out, int out_size, void* d_ws, size_t ws_size,
                              hipStream_t stream) {
    (void)in_sizes; (void)n_in; (void)out_size; (void)ws_size;

    const float* x = (const float*)d_in[0];
    const int* eb = (const int*)d_in[1];
    const float* w_s1 = (const float*)d_in[3];
    const void* b_s1 = d_in[4];
    const float* w_s21 = (const float*)d_in[5];
    const void* b_s21 = d_in[6];
    const float* w_s22 = (const float*)d_in[7];
    const void* b_s22 = d_in[8];
    const float* w_raw = (const float*)d_in[9];
    const void* b_raw = d_in[10];
    const void* w_pos = d_in[11];
    const void* b_pos = d_in[12];
    const void* w_neg = d_in[13];
    const void* b_neg = d_in[14];
    const float* w_pool = (const float*)d_in[15];
    const void* b_pool = d_in[16];
    const void* w1 = d_in[17];  const void* b1 = d_in[18];  const void* g1 = d_in[19];  const void* be1 = d_in[20];
    const void* w2 = d_in[21];  const void* b2 = d_in[22];  const void* g2 = d_in[23];  const void* be2 = d_in[24];
    const void* w3 = d_in[25];  const void* b3 = d_in[26];  const void* g3 = d_in[27];  const void* be3 = d_in[28];
    const void* w4 = d_in[29];  const void* b4 = d_in[30];

    char* ws = (char*)d_ws;
    size_t off = 0;
    auto alloc = [&](size_t b) -> void* {
        void* p = ws + off;
        off += (b + 255) & ~(size_t)255;
        return p;
    };
    int* flag = (int*)alloc(256);
    int* deg = (int*)alloc((size_t)N_NODES * 4);
    float* dinv = (float*)alloc((size_t)N_NODES * 4);
    int* rowptr = (int*)alloc((size_t)(N_NODES + 1) * 4);
    int* cursor = (int*)alloc((size_t)N_NODES * 4);
    int* srcs = (int*)alloc((size_t)NEDGE * 4);
    unsigned short* xbf = (unsigned short*)alloc((size_t)N_NODES * 256 * 2);
    unsigned short* wb_s1 = (unsigned short*)alloc((size_t)256 * 256 * 2);
    unsigned short* wb_s21 = (unsigned short*)alloc((size_t)256 * 256 * 2);
    unsigned short* wb_s22 = (unsigned short*)alloc((size_t)256 * 256 * 2);
    unsigned short* wb_raw = (unsigned short*)alloc((size_t)256 * 256 * 2);
    unsigned short* wb_pool = (unsigned short*)alloc((size_t)768 * 768 * 2);
    unsigned short* tmpA = (unsigned short*)alloc((size_t)N_NODES * 256 * 2);
    unsigned short* tmpB = (unsigned short*)alloc((size_t)N_NODES * 256 * 2);
    unsigned short* hfin = (unsigned short*)alloc((size_t)N_NODES * 768 * 2);
    unsigned short* xt = (unsigned short*)alloc((size_t)N_NODES * 768 * 2);
    float* svp = (float*)alloc((size_t)N_NODES * 4);
    float* svn = (float*)alloc((size_t)N_NODES * 4);
    float* scp = (float*)alloc((size_t)N_NODES * 4);
    float* scn = (float*)alloc((size_t)N_NODES * 4);
    unsigned char* maskp = (unsigned char*)alloc(N_NODES);
    unsigned char* maskn = (unsigned char*)alloc(N_NODES);
    float* ebuf = (float*)alloc((size_t)128 * 1536 * 4);
    float* zb = (float*)alloc((size_t)128 * 256 * 4);
    float* act1 = (float*)alloc((size_t)128 * 256 * 4);
    float* act2 = (float*)alloc((size_t)128 * 256 * 4);
    float* act3 = (float*)alloc((size_t)128 * 256 * 4);
    float* lg = (float*)alloc((size_t)128 * NCLS * 4);

    hipMemsetAsync(flag, 0, 256, stream);
    hipMemsetAsync(deg, 0, (size_t)N_NODES * 4, stream);
    detect_kernel<<<NEDGE / 256, 256, 0, stream>>>(eb, flag);
    hist_kernel<<<NEDGE / 256, 256, 0, stream>>>(eb, flag, deg);
    dinv_kernel<<<N_NODES / 256, 256, 0, stream>>>(deg, dinv);
    scan_kernel<<<1, 1024, 0, stream>>>(deg, rowptr, cursor);
    scatter_kernel<<<NEDGE / 256, 256, 0, stream>>>(eb, flag, cursor, srcs);

    // fp32 -> bf16 conversions for MFMA operands
    cvt_kernel<<<(N_NODES * 256 + 255) / 256, 256, 0, stream>>>(x, xbf, N_NODES * 256);
    cvt_kernel<<<(256 * 256 + 255) / 256, 256, 0, stream>>>(w_s1, wb_s1, 256 * 256);
    cvt_kernel<<<(256 * 256 + 255) / 256, 256, 0, stream>>>(w_s21, wb_s21, 256 * 256);
    cvt_kernel<<<(256 * 256 + 255) / 256, 256, 0, stream>>>(w_s22, wb_s22, 256 * 256);
    cvt_kernel<<<(256 * 256 + 255) / 256, 256, 0, stream>>>(w_raw, wb_raw, 256 * 256);
    cvt_kernel<<<(768 * 768 + 255) / 256, 256, 0, stream>>>(w_pool, wb_pool, 768 * 768);

    dim3 gA(N_NODES / 64, 256 / 64);   // (512, 4)
    dim3 gP(N_NODES / 64, 768 / 64);   // (512, 12)

    // h_s1 branch
    gemm_kernel<<<gA, 256, 0, stream>>>(xbf, wb_s1, nullptr, tmpA, N_NODES, 256, 256, 256, 0, 0);
    agg_kernel<<<N_NODES / 4, 256, 0, stream>>>(tmpA, rowptr, srcs, dinv, b_s1, hfin, 768, 0, 1);
    // h_s2 branch (two GCN layers)
    gemm_kernel<<<gA, 256, 0, stream>>>(xbf, wb_s21, nullptr, tmpA, N_NODES, 256, 256, 256, 0, 0);
    agg_kernel<<<N_NODES / 4, 256, 0, stream>>>(tmpA, rowptr, srcs, dinv, b_s21, tmpB, 256, 0, 1);
    gemm_kernel<<<gA, 256, 0, stream>>>(tmpB, wb_s22, nullptr, tmpA, N_NODES, 256, 256, 256, 0, 0);
    agg_kernel<<<N_NODES / 4, 256, 0, stream>>>(tmpA, rowptr, srcs, dinv, b_s22, hfin, 768, 256, 1);
    // h_raw
    gemm_kernel<<<gA, 256, 0, stream>>>(xbf, wb_raw, b_raw, hfin, N_NODES, 256, 256, 768, 512, 0);
    // xt = sigmoid(h_final @ w_pool + b_pool)
    gemm_kernel<<<gP, 256, 0, stream>>>(hfin, wb_pool, b_pool, xt, N_NODES, 768, 768, 768, 0, 1);
    // scores
    score_mv_kernel<<<N_NODES / 4, 256, 0, stream>>>(hfin, w_pos, w_neg, svp, svn);
    score_agg_kernel<<<N_NODES / 256, 256, 0, stream>>>(svp, svn, rowptr, srcs, dinv, b_pos, b_neg, scp, scn, d_out);
    // top-k + fused readout (xt read once for both masks)
    topk_kernel<<<NGRAPH, 512, 0, stream>>>(scp, maskp);
    topk_kernel<<<NGRAPH, 512, 0, stream>>>(scn, maskn);
    {
        dim3 gR(NGRAPH, FDIM / 64);    // (64, 12)
        readout2_kernel<<<gR, 256, 0, stream>>>(xt, maskp, maskn, ebuf);
    }
    // MLP (128 rows = pos 0..63, neg 64..127; BN stats per 64-row group)
    mlp_gemm_kernel<<<128, 256, 0, stream>>>(ebuf, w1, b1, zb, 1536);
    bn_kernel<<<512, 64, 0, stream>>>(zb, g1, be1, nullptr, act1);
    mlp_gemm_kernel<<<128, 256, 0, stream>>>(act1, w2, b2, zb, 256);
    bn_kernel<<<512, 64, 0, stream>>>(zb, g2, be2, act1, act2);
    mlp_gemm_kernel<<<128, 256, 0, stream>>>(act2, w3, b3, zb, 256);
    bn_kernel<<<512, 64, 0, stream>>>(zb, g3, be3, act2, act3);
    logits_kernel<<<(128 * NCLS + 63) / 64, 64, 0, stream>>>(act3, w4, b4, lg);
    softmax_kernel<<<2, 64, 0, stream>>>(lg, d_out);
    batch_kernel<<<N_NODES / 256, 256, 0, stream>>>(d_out);
}

// Round 4
// 707.578 us; speedup vs baseline: 1.5430x; 1.1149x over previous
//
#include <hip/hip_runtime.h>
#include <hip/hip_bf16.h>

// ---- problem constants ----
#define N_NODES 32768
#define NGRAPH  64
#define NPG     512
#define TOPK    256
#define HID     256
#define FDIM    768
#define NEDGE   262144
#define NCLS    10
#define BN_EPS  1e-5f

// inputs/outputs fp32 (verified round 2); MFMA internals bf16
#define IN_BF16 0
#define OUT_BF16 0

typedef __attribute__((ext_vector_type(8))) short short8;
typedef __attribute__((ext_vector_type(4))) float f32x4;

__device__ __forceinline__ float bf2f(unsigned short u) {
    return __uint_as_float(((unsigned)u) << 16);
}
__device__ __forceinline__ unsigned short f2bf(float f) {
    unsigned x = __float_as_uint(f);
    unsigned r = (x + 0x7fffu + ((x >> 16) & 1u)) >> 16;
    return (unsigned short)r;
}
__device__ __forceinline__ float in_ld(const void* p, size_t i) {
#if IN_BF16
    return bf2f(((const unsigned short*)p)[i]);
#else
    return ((const float*)p)[i];
#endif
}
__device__ __forceinline__ void st_out(void* o, size_t i, float v) {
#if OUT_BF16
    ((unsigned short*)o)[i] = f2bf(v);
#else
    ((float*)o)[i] = v;
#endif
}

// async global->LDS, 16 bytes/lane; LDS dst = wave-uniform base + lane*16
__device__ __forceinline__ void async_cp16(const unsigned short* g, unsigned short* l) {
    __builtin_amdgcn_global_load_lds(
        (const __attribute__((address_space(1))) unsigned int*)g,
        (__attribute__((address_space(3))) unsigned int*)l, 16, 0, 0);
}

// ---------------- fp32 -> bf16 conversion ----------------
__global__ __launch_bounds__(256) void cvt_kernel(const float* __restrict__ in,
                                                  unsigned short* __restrict__ out, int n) {
    int i = blockIdx.x * 256 + threadIdx.x;
    if (i < n) out[i] = f2bf(in[i]);
}

// fp32 [K][N] -> bf16 transposed [N][K]; tiled for coalescing. grid (K/32, N/32), 256 thr.
__global__ __launch_bounds__(256) void cvt_t_kernel(const float* __restrict__ in,
                                                    unsigned short* __restrict__ out, int K, int N) {
    __shared__ unsigned short tile[32][33];
    int bk = blockIdx.x * 32, bn = blockIdx.y * 32;
    int tx = threadIdx.x & 31, ty = threadIdx.x >> 5;     // ty 0..7
#pragma unroll
    for (int i = 0; i < 32; i += 8)
        tile[ty + i][tx] = f2bf(in[(size_t)(bk + ty + i) * N + bn + tx]);
    __syncthreads();
#pragma unroll
    for (int i = 0; i < 32; i += 8)
        out[(size_t)(bn + ty + i) * K + bk + tx] = tile[tx][ty + i];
}

// ---------------- edge dtype detection + CSR build ----------------
__global__ __launch_bounds__(256) void detect_kernel(const int* __restrict__ eb, int* __restrict__ flag) {
    int i = blockIdx.x * 256 + threadIdx.x;
    int v = eb[2 * (size_t)i + 1];
    unsigned long long b = __ballot(v != 0);
    if ((threadIdx.x & 63) == 0 && b)
        atomicAdd(flag, (int)__popcll(b));
}

__global__ __launch_bounds__(256) void hist_kernel(const int* __restrict__ eb, const int* __restrict__ flag,
                                                   int* __restrict__ deg) {
    int e = blockIdx.x * 256 + threadIdx.x;
    int st = (*flag == 0) ? 2 : 1;
    unsigned d = ((const unsigned*)eb)[(size_t)(NEDGE + e) * st] & (N_NODES - 1);
    atomicAdd(&deg[d], 1);
}

__global__ __launch_bounds__(256) void dinv_kernel(const int* __restrict__ deg, float* __restrict__ dinv) {
    int i = blockIdx.x * 256 + threadIdx.x;
    dinv[i] = rsqrtf((float)deg[i] + 1.0f);
}

__global__ __launch_bounds__(1024) void scan_kernel(const int* __restrict__ cnt, int* __restrict__ rowptr,
                                                    int* __restrict__ cursor) {
    __shared__ int part[1024];
    int t = threadIdx.x;
    int base = t * 32;
    int loc[32];
    int s = 0;
#pragma unroll
    for (int i = 0; i < 32; i++) { loc[i] = cnt[base + i]; s += loc[i]; }
    part[t] = s;
    __syncthreads();
    for (int off = 1; off < 1024; off <<= 1) {
        int v = (t >= off) ? part[t - off] : 0;
        __syncthreads();
        part[t] += v;
        __syncthreads();
    }
    int run = (t == 0) ? 0 : part[t - 1];
#pragma unroll
    for (int i = 0; i < 32; i++) {
        rowptr[base + i] = run;
        cursor[base + i] = run;
        run += loc[i];
    }
    if (t == 1023) rowptr[N_NODES] = run;
}

__global__ __launch_bounds__(256) void scatter_kernel(const int* __restrict__ eb, const int* __restrict__ flag,
                                                      int* __restrict__ cursor, int* __restrict__ srcs) {
    int e = blockIdx.x * 256 + threadIdx.x;
    int st = (*flag == 0) ? 2 : 1;
    unsigned s = ((const unsigned*)eb)[(size_t)e * st] & (N_NODES - 1);
    unsigned d = ((const unsigned*)eb)[(size_t)(NEDGE + e) * st] & (N_NODES - 1);
    int p = atomicAdd(&cursor[d], 1);
    srcs[p] = (int)s;
}

// ---------------- MFMA GEMM, m97-style ----------------
// C[M x Nn] = A[M x K](bf16 row-major) @ W (given as WT[Nn x K] bf16 row-major).
// Block tile 128x128, BK=64, 4 waves 2x2, wave tile 64x64 (4x4 16x16x32 MFMAs).
// Staging via global_load_lds(16B) with XOR chunk swizzle: logical (row, chunk c)
// stored at physical chunk c ^ (row & 7); ds_read applies same swizzle -> 2-way
// bank aliasing only (free). epi: 0 none, 1 sigmoid. bias fp32 or null.
__global__ __launch_bounds__(256) void gemm_kernel(const unsigned short* __restrict__ A,
                                                   const unsigned short* __restrict__ WT,
                                                   const float* __restrict__ bias,
                                                   unsigned short* __restrict__ C,
                                                   int K, int Nn, int ldC, int colOff, int epi) {
    __shared__ unsigned short As[128 * 64];
    __shared__ unsigned short Bs[128 * 64];
    const int tid = threadIdx.x;
    const int wave = tid >> 6;
    const int lane = tid & 63;
    const int bm = blockIdx.y * 128;
    const int bn = blockIdx.x * 128;
    const int wm = (wave >> 1) * 64;
    const int wn = (wave & 1) * 64;
    const int l15 = lane & 15;
    const int q = lane >> 4;

    f32x4 acc[4][4] = {};

    // staging: per wave-instr, 64 lanes cover 8 rows x 8 chunks (16B each)
    const int srow = lane >> 3;      // 0..7
    const int schunk = lane & 7;     // 0..7

    for (int k0 = 0; k0 < K; k0 += 64) {
        __syncthreads();
#pragma unroll
        for (int t = 0; t < 4; t++) {
            int r = t * 32 + wave * 8 + srow;          // 0..127
            int gc = schunk ^ (r & 7);                  // xor swizzle at 16B granularity
            const unsigned short* ga = A + (size_t)(bm + r) * K + k0 + gc * 8;
            const unsigned short* gb = WT + (size_t)(bn + r) * K + k0 + gc * 8;
            unsigned short* la = &As[(t * 32 + wave * 8) * 64];
            unsigned short* lb = &Bs[(t * 32 + wave * 8) * 64];
            async_cp16(ga, la);
            async_cp16(gb, lb);
        }
        __syncthreads();

#pragma unroll
        for (int h = 0; h < 2; h++) {
            short8 af[4], bfv[4];
            int p = (h * 4 + q) ^ (l15 & 7);           // same for all tm/tn (row&7 == l15&7)
#pragma unroll
            for (int t = 0; t < 4; t++) {
                int m = wm + t * 16 + l15;
                int n = wn + t * 16 + l15;
                af[t] = *(const short8*)&As[m * 64 + p * 8];
                bfv[t] = *(const short8*)&Bs[n * 64 + p * 8];
            }
#pragma unroll
            for (int tm = 0; tm < 4; tm++)
#pragma unroll
                for (int tn = 0; tn < 4; tn++)
                    acc[tm][tn] = __builtin_amdgcn_mfma_f32_16x16x32_bf16(af[tm], bfv[tn], acc[tm][tn], 0, 0, 0);
        }
    }

#pragma unroll
    for (int tm = 0; tm < 4; tm++) {
        int row = bm + wm + tm * 16 + q * 4;
#pragma unroll
        for (int tn = 0; tn < 4; tn++) {
            int col = bn + wn + tn * 16 + l15;
            float bv = bias ? bias[col] : 0.0f;
#pragma unroll
            for (int r = 0; r < 4; r++) {
                float v = acc[tm][tn][r] + bv;
                if (epi == 1) v = 1.0f / (1.0f + __expf(-v));
                C[(size_t)(row + r) * ldC + colOff + col] = f2bf(v);
            }
        }
    }
}

// ---------------- GCN aggregation (256-dim), fused self-loop + bias + optional leaky-relu ----------------
__global__ __launch_bounds__(256) void agg_kernel(const unsigned short* __restrict__ h,
                                                  const int* __restrict__ rowptr, const int* __restrict__ srcs,
                                                  const float* __restrict__ dinv, const void* __restrict__ bias,
                                                  unsigned short* __restrict__ out, int ldOut, int colOff,
                                                  int do_lrelu) {
    int wave = threadIdx.x >> 6, lane = threadIdx.x & 63;
    int v = blockIdx.x * 4 + wave;
    int f0 = lane * 4;
    float a0 = 0.f, a1 = 0.f, a2 = 0.f, a3 = 0.f;
    int s = rowptr[v], e = rowptr[v + 1];
    for (int i = s; i < e; i++) {
        int u = srcs[i] & (N_NODES - 1);
        float du = dinv[u];
        uint2 hv = *(const uint2*)(h + (size_t)u * 256 + f0);
        a0 += bf2f((unsigned short)(hv.x & 0xffff)) * du;
        a1 += bf2f((unsigned short)(hv.x >> 16)) * du;
        a2 += bf2f((unsigned short)(hv.y & 0xffff)) * du;
        a3 += bf2f((unsigned short)(hv.y >> 16)) * du;
    }
    float dv = dinv[v], dv2 = dv * dv;
    uint2 sv = *(const uint2*)(h + (size_t)v * 256 + f0);
    float r0 = dv * a0 + bf2f((unsigned short)(sv.x & 0xffff)) * dv2 + in_ld(bias, f0 + 0);
    float r1 = dv * a1 + bf2f((unsigned short)(sv.x >> 16)) * dv2 + in_ld(bias, f0 + 1);
    float r2 = dv * a2 + bf2f((unsigned short)(sv.y & 0xffff)) * dv2 + in_ld(bias, f0 + 2);
    float r3 = dv * a3 + bf2f((unsigned short)(sv.y >> 16)) * dv2 + in_ld(bias, f0 + 3);
    if (do_lrelu) {
        r0 = r0 > 0.f ? r0 : 0.01f * r0;
        r1 = r1 > 0.f ? r1 : 0.01f * r1;
        r2 = r2 > 0.f ? r2 : 0.01f * r2;
        r3 = r3 > 0.f ? r3 : 0.01f * r3;
    }
    unsigned o0 = f2bf(r0), o1 = f2bf(r1), o2 = f2bf(r2), o3 = f2bf(r3);
    uint2 ov = make_uint2((o1 << 16) | o0, (o3 << 16) | o2);
    *(uint2*)(out + (size_t)v * ldOut + colOff + f0) = ov;
}

// ---------------- score matvec: sv = h_final @ w (768 -> 1), fp32 accumulate ----------------
__global__ __launch_bounds__(256) void score_mv_kernel(const unsigned short* __restrict__ hf,
                                                       const void* __restrict__ wp, const void* __restrict__ wn,
                                                       float* __restrict__ svp, float* __restrict__ svn) {
    int wave = threadIdx.x >> 6, lane = threadIdx.x & 63;
    int v = blockIdx.x * 4 + wave;
    float sp = 0.f, sn = 0.f;
#pragma unroll
    for (int i = 0; i < 3; i++) {
        int k = i * 256 + lane * 4;
        uint2 hv = *(const uint2*)(hf + (size_t)v * 768 + k);
        float x0 = bf2f((unsigned short)(hv.x & 0xffff));
        float x1 = bf2f((unsigned short)(hv.x >> 16));
        float x2 = bf2f((unsigned short)(hv.y & 0xffff));
        float x3 = bf2f((unsigned short)(hv.y >> 16));
        sp += x0 * in_ld(wp, k) + x1 * in_ld(wp, k + 1) + x2 * in_ld(wp, k + 2) + x3 * in_ld(wp, k + 3);
        sn += x0 * in_ld(wn, k) + x1 * in_ld(wn, k + 1) + x2 * in_ld(wn, k + 2) + x3 * in_ld(wn, k + 3);
    }
    for (int off = 32; off >= 1; off >>= 1) {
        sp += __shfl_down(sp, off, 64);
        sn += __shfl_down(sn, off, 64);
    }
    if (lane == 0) { svp[v] = sp; svn[v] = sn; }
}

// ---------------- scalar GCN agg on scores + sigmoid ----------------
__global__ __launch_bounds__(256) void score_agg_kernel(const float* __restrict__ svp, const float* __restrict__ svn,
                                                        const int* __restrict__ rowptr, const int* __restrict__ srcs,
                                                        const float* __restrict__ dinv,
                                                        const void* __restrict__ bp, const void* __restrict__ bn_,
                                                        float* __restrict__ scp, float* __restrict__ scn,
                                                        void* __restrict__ dout) {
    int v = blockIdx.x * 256 + threadIdx.x;
    float ap = 0.f, an = 0.f;
    int s = rowptr[v], e = rowptr[v + 1];
    for (int i = s; i < e; i++) {
        int u = srcs[i] & (N_NODES - 1);
        float du = dinv[u];
        ap += svp[u] * du;
        an += svn[u] * du;
    }
    float dv = dinv[v], dv2 = dv * dv;
    float zp = dv * ap + svp[v] * dv2 + in_ld(bp, 0);
    float zn = dv * an + svn[v] * dv2 + in_ld(bn_, 0);
    float pp = 1.0f / (1.0f + __expf(-zp));
    float pn = 1.0f / (1.0f + __expf(-zn));
    scp[v] = pp;
    scn[v] = pn;
    st_out(dout, 1920 + (size_t)v, pp);
    st_out(dout, 1920 + (size_t)N_NODES + v, pn);
}

// ---------------- top-k mask per graph ----------------
__global__ __launch_bounds__(512) void topk_kernel(const float* __restrict__ sc, unsigned char* __restrict__ mask) {
    __shared__ float s[512];
    int g = blockIdx.x, i = threadIdx.x;
    float my = sc[(size_t)g * 512 + i];
    s[i] = my;
    __syncthreads();
    int cnt = 0;
    for (int j = 0; j < 512; j++) {
        float o = s[j];
        cnt += (int)((o > my) || ((o == my) && (j < i)));
    }
    mask[(size_t)g * 512 + i] = (cnt < TOPK) ? 1 : 0;
}

// ---------------- fused dual-mask readout ----------------
__global__ __launch_bounds__(256) void readout2_kernel(const unsigned short* __restrict__ xt,
                                                       const unsigned char* __restrict__ maskp,
                                                       const unsigned char* __restrict__ maskn,
                                                       float* __restrict__ eout) {
    int g = blockIdx.x;
    int c = blockIdx.y;
    int wv = threadIdx.x >> 6, lane = threadIdx.x & 63;
    int f = c * 64 + lane;
    __shared__ unsigned char mp[512], mn[512];
    __shared__ float red[4][64][4];
    for (int i = threadIdx.x; i < 512; i += 256) {
        mp[i] = maskp[(size_t)g * 512 + i];
        mn[i] = maskn[(size_t)g * 512 + i];
    }
    __syncthreads();
    float sp = 0.f, sn = 0.f, xp = -INFINITY, xn = -INFINITY;
    const unsigned short* base = xt + ((size_t)g * 512 + wv * 128) * 768 + f;
    for (int v = 0; v < 128; v++) {
        float x = bf2f(base[(size_t)v * 768]);
        if (mp[wv * 128 + v]) { sp += x; xp = fmaxf(xp, x); }
        if (mn[wv * 128 + v]) { sn += x; xn = fmaxf(xn, x); }
    }
    red[wv][lane][0] = sp; red[wv][lane][1] = xp;
    red[wv][lane][2] = sn; red[wv][lane][3] = xn;
    __syncthreads();
    if (wv == 0) {
#pragma unroll
        for (int w = 1; w < 4; w++) {
            sp += red[w][lane][0]; xp = fmaxf(xp, red[w][lane][1]);
            sn += red[w][lane][2]; xn = fmaxf(xn, red[w][lane][3]);
        }
        float* erp = eout + (size_t)g * 1536;
        float* ern = eout + (size_t)(64 + g) * 1536;
        erp[f] = sp * (1.0f / TOPK);
        erp[768 + f] = xp;
        ern[f] = sn * (1.0f / TOPK);
        ern[768 + f] = xn;
    }
}

// ---------------- tiny MLP pieces ----------------
__global__ __launch_bounds__(256) void mlp_gemm_kernel(const float* __restrict__ in, const void* __restrict__ W,
                                                       const void* __restrict__ b, float* __restrict__ out, int K) {
    __shared__ float row[1536];
    int r = blockIdx.x, c = threadIdx.x;
    for (int k = c; k < K; k += 256) row[k] = in[(size_t)r * K + k];
    __syncthreads();
    float acc = in_ld(b, c);
    for (int k = 0; k < K; k++) acc += row[k] * in_ld(W, (size_t)k * 256 + c);
    out[(size_t)r * 256 + c] = acc;
}

__global__ __launch_bounds__(64) void bn_kernel(const float* __restrict__ z, const void* __restrict__ gamma,
                                                const void* __restrict__ beta, const float* __restrict__ res,
                                                float* __restrict__ out) {
    int f = blockIdx.x & 255, g = blockIdx.x >> 8, r = threadIdx.x;
    size_t idx = (size_t)(g * 64 + r) * 256 + f;
    float x = z[idx];
    float s = x, sq = x * x;
    for (int off = 1; off < 64; off <<= 1) {
        s += __shfl_xor(s, off, 64);
        sq += __shfl_xor(sq, off, 64);
    }
    float m = s * (1.0f / 64.0f);
    float var = sq * (1.0f / 64.0f) - m * m;
    float y = (x - m) * rsqrtf(var + BN_EPS) * in_ld(gamma, f) + in_ld(beta, f);
    y = fmaxf(y, 0.0f);
    if (res) y += res[idx];
    out[idx] = y;
}

__global__ __launch_bounds__(64) void logits_kernel(const float* __restrict__ act, const void* __restrict__ w4,
                                                    const void* __restrict__ b4, float* __restrict__ lg) {
    int idx = blockIdx.x * 64 + threadIdx.x;
    if (idx >= 128 * NCLS) return;
    int r = idx / NCLS, c = idx % NCLS;
    float acc = in_ld(b4, c);
    for (int k = 0; k < 256; k++) acc += act[(size_t)r * 256 + k] * in_ld(w4, (size_t)k * NCLS + c);
    lg[idx] = acc;
}

__global__ __launch_bounds__(64) void softmax_kernel(const float* __restrict__ lg, void* __restrict__ dout) {
    int r = blockIdx.x * 64 + threadIdx.x;
    if (r >= 128) return;
    float l[NCLS];
    float mx = -1e30f;
    for (int c = 0; c < NCLS; c++) { l[c] = lg[(size_t)r * NCLS + c]; mx = fmaxf(mx, l[c]); }
    float sum = 0.f;
    float ex[NCLS];
    for (int c = 0; c < NCLS; c++) { ex[c] = __expf(l[c] - mx); sum += ex[c]; }
    float inv = 1.0f / sum;
    int g = r >> 6, rr = r & 63;
    if (g == 0) {
        for (int c = 0; c < NCLS; c++) st_out(dout, (size_t)rr * NCLS + c, l[c]);
        for (int c = 0; c < NCLS; c++) st_out(dout, 640 + (size_t)rr * NCLS + c, ex[c] * inv);
    } else {
        for (int c = 0; c < NCLS; c++) st_out(dout, 1280 + (size_t)rr * NCLS + c, ex[c] * inv);
    }
}

__global__ __launch_bounds__(256) void batch_kernel(void* __restrict__ dout) {
    int i = blockIdx.x * 256 + threadIdx.x;
    st_out(dout, 1920 + 2 * (size_t)N_NODES + i, (float)(i >> 9));
}

// ---------------- host launcher ----------------
extern "C" void kernel_launch(void* const* d_in, const int* in_sizes, int n_in,
                              void* d_out, int out_size, void* d_ws, size_t ws_size,
                              hipStream_t stream) {
    (void)in_sizes; (void)n_in; (void)out_size; (void)ws_size;

    const float* x = (const float*)d_in[0];
    const int* eb = (const int*)d_in[1];
    const float* w_s1 = (const float*)d_in[3];
    const float* b_s1 = (const float*)d_in[4];
    const float* w_s21 = (const float*)d_in[5];
    const float* b_s21 = (const float*)d_in[6];
    const float* w_s22 = (const float*)d_in[7];
    const float* b_s22 = (const float*)d_in[8];
    const float* w_raw = (const float*)d_in[9];
    const float* b_raw = (const float*)d_in[10];
    const void* w_pos = d_in[11];
    const void* b_pos = d_in[12];
    const void* w_neg = d_in[13];
    const void* b_neg = d_in[14];
    const float* w_pool = (const float*)d_in[15];
    const float* b_pool = (const float*)d_in[16];
    const void* w1 = d_in[17];  const void* b1 = d_in[18];  const void* g1 = d_in[19];  const void* be1 = d_in[20];
    const void* w2 = d_in[21];  const void* b2 = d_in[22];  const void* g2 = d_in[23];  const void* be2 = d_in[24];
    const void* w3 = d_in[25];  const void* b3 = d_in[26];  const void* g3 = d_in[27];  const void* be3 = d_in[28];
    const void* w4 = d_in[29];  const void* b4 = d_in[30];

    char* ws = (char*)d_ws;
    size_t off = 0;
    auto alloc = [&](size_t b) -> void* {
        void* p = ws + off;
        off += (b + 255) & ~(size_t)255;
        return p;
    };
    int* flag = (int*)alloc(256);
    int* deg = (int*)alloc((size_t)N_NODES * 4);
    float* dinv = (float*)alloc((size_t)N_NODES * 4);
    int* rowptr = (int*)alloc((size_t)(N_NODES + 1) * 4);
    int* cursor = (int*)alloc((size_t)N_NODES * 4);
    int* srcs = (int*)alloc((size_t)NEDGE * 4);
    unsigned short* xbf = (unsigned short*)alloc((size_t)N_NODES * 256 * 2);
    unsigned short* wb_s1 = (unsigned short*)alloc((size_t)256 * 256 * 2);   // transposed [N][K]
    unsigned short* wb_s21 = (unsigned short*)alloc((size_t)256 * 256 * 2);
    unsigned short* wb_s22 = (unsigned short*)alloc((size_t)256 * 256 * 2);
    unsigned short* wb_raw = (unsigned short*)alloc((size_t)256 * 256 * 2);
    unsigned short* wb_pool = (unsigned short*)alloc((size_t)768 * 768 * 2);
    unsigned short* tmpA = (unsigned short*)alloc((size_t)N_NODES * 256 * 2);
    unsigned short* tmpB = (unsigned short*)alloc((size_t)N_NODES * 256 * 2);
    unsigned short* hfin = (unsigned short*)alloc((size_t)N_NODES * 768 * 2);
    unsigned short* xt = (unsigned short*)alloc((size_t)N_NODES * 768 * 2);
    float* svp = (float*)alloc((size_t)N_NODES * 4);
    float* svn = (float*)alloc((size_t)N_NODES * 4);
    float* scp = (float*)alloc((size_t)N_NODES * 4);
    float* scn = (float*)alloc((size_t)N_NODES * 4);
    unsigned char* maskp = (unsigned char*)alloc(N_NODES);
    unsigned char* maskn = (unsigned char*)alloc(N_NODES);
    float* ebuf = (float*)alloc((size_t)128 * 1536 * 4);
    float* zb = (float*)alloc((size_t)128 * 256 * 4);
    float* act1 = (float*)alloc((size_t)128 * 256 * 4);
    float* act2 = (float*)alloc((size_t)128 * 256 * 4);
    float* act3 = (float*)alloc((size_t)128 * 256 * 4);
    float* lg = (float*)alloc((size_t)128 * NCLS * 4);

    hipMemsetAsync(flag, 0, 256, stream);
    hipMemsetAsync(deg, 0, (size_t)N_NODES * 4, stream);
    detect_kernel<<<NEDGE / 256, 256, 0, stream>>>(eb, flag);
    hist_kernel<<<NEDGE / 256, 256, 0, stream>>>(eb, flag, deg);
    dinv_kernel<<<N_NODES / 256, 256, 0, stream>>>(deg, dinv);
    scan_kernel<<<1, 1024, 0, stream>>>(deg, rowptr, cursor);
    scatter_kernel<<<NEDGE / 256, 256, 0, stream>>>(eb, flag, cursor, srcs);

    // conversions: x row-major bf16; weights transposed to [N][K] bf16
    cvt_kernel<<<(N_NODES * 256 + 255) / 256, 256, 0, stream>>>(x, xbf, N_NODES * 256);
    {
        dim3 g8(8, 8), g24(24, 24);
        cvt_t_kernel<<<g8, 256, 0, stream>>>(w_s1, wb_s1, 256, 256);
        cvt_t_kernel<<<g8, 256, 0, stream>>>(w_s21, wb_s21, 256, 256);
        cvt_t_kernel<<<g8, 256, 0, stream>>>(w_s22, wb_s22, 256, 256);
        cvt_t_kernel<<<g8, 256, 0, stream>>>(w_raw, wb_raw, 256, 256);
        cvt_t_kernel<<<g24, 256, 0, stream>>>(w_pool, wb_pool, 768, 768);
    }

    dim3 gA(256 / 128, N_NODES / 128);   // (2, 256)  N-inner for A-slab L2/L3 reuse
    dim3 gP(768 / 128, N_NODES / 128);   // (6, 256)

    // h_s1 branch
    gemm_kernel<<<gA, 256, 0, stream>>>(xbf, wb_s1, nullptr, tmpA, 256, 256, 256, 0, 0);
    agg_kernel<<<N_NODES / 4, 256, 0, stream>>>(tmpA, rowptr, srcs, dinv, b_s1, hfin, 768, 0, 1);
    // h_s2 branch (two GCN layers)
    gemm_kernel<<<gA, 256, 0, stream>>>(xbf, wb_s21, nullptr, tmpA, 256, 256, 256, 0, 0);
    agg_kernel<<<N_NODES / 4, 256, 0, stream>>>(tmpA, rowptr, srcs, dinv, b_s21, tmpB, 256, 0, 1);
    gemm_kernel<<<gA, 256, 0, stream>>>(tmpB, wb_s22, nullptr, tmpA, 256, 256, 256, 0, 0);
    agg_kernel<<<N_NODES / 4, 256, 0, stream>>>(tmpA, rowptr, srcs, dinv, b_s22, hfin, 768, 256, 1);
    // h_raw
    gemm_kernel<<<gA, 256, 0, stream>>>(xbf, wb_raw, b_raw, hfin, 256, 256, 768, 512, 0);
    // xt = sigmoid(h_final @ w_pool + b_pool)
    gemm_kernel<<<gP, 256, 0, stream>>>(hfin, wb_pool, b_pool, xt, 768, 768, 768, 0, 1);
    // scores
    score_mv_kernel<<<N_NODES / 4, 256, 0, stream>>>(hfin, w_pos, w_neg, svp, svn);
    score_agg_kernel<<<N_NODES / 256, 256, 0, stream>>>(svp, svn, rowptr, srcs, dinv, b_pos, b_neg, scp, scn, d_out);
    // top-k + fused readout
    topk_kernel<<<NGRAPH, 512, 0, stream>>>(scp, maskp);
    topk_kernel<<<NGRAPH, 512, 0, stream>>>(scn, maskn);
    {
        dim3 gR(NGRAPH, FDIM / 64);
        readout2_kernel<<<gR, 256, 0, stream>>>(xt, maskp, maskn, ebuf);
    }
    // MLP
    mlp_gemm_kernel<<<128, 256, 0, stream>>>(ebuf, w1, b1, zb, 1536);
    bn_kernel<<<512, 64, 0, stream>>>(zb, g1, be1, nullptr, act1);
    mlp_gemm_kernel<<<128, 256, 0, stream>>>(act1, w2, b2, zb, 256);
    bn_kernel<<<512, 64, 0, stream>>>(zb, g2, be2, act1, act2);
    mlp_gemm_kernel<<<128, 256, 0, stream>>>(act2, w3, b3, zb, 256);
    bn_kernel<<<512, 64, 0, stream>>>(zb, g3, be3, act2, act3);
    logits_kernel<<<(128 * NCLS + 63) / 64, 64, 0, stream>>>(act3, w4, b4, lg);
    softmax_kernel<<<2, 64, 0, stream>>>(lg, d_out);
    batch_kernel<<<N_NODES / 256, 256, 0, stream>>>(d_out);
}

// Round 5
// 647.750 us; speedup vs baseline: 1.6855x; 1.0924x over previous
//
#include <hip/hip_runtime.h>
#include <hip/hip_bf16.h>

// ---- problem constants ----
#define N_NODES 32768
#define NGRAPH  64
#define NPG     512
#define TOPK    256
#define HID     256
#define FDIM    768
#define NEDGE   262144
#define NCLS    10
#define BN_EPS  1e-5f

// inputs/outputs fp32 (verified round 2); MFMA internals bf16
#define IN_BF16 0
#define OUT_BF16 0

typedef __attribute__((ext_vector_type(8))) short short8;
typedef __attribute__((ext_vector_type(4))) float f32x4;

__device__ __forceinline__ float bf2f(unsigned short u) {
    return __uint_as_float(((unsigned)u) << 16);
}
__device__ __forceinline__ unsigned short f2bf(float f) {
    unsigned x = __float_as_uint(f);
    unsigned r = (x + 0x7fffu + ((x >> 16) & 1u)) >> 16;
    return (unsigned short)r;
}
__device__ __forceinline__ float in_ld(const void* p, size_t i) {
#if IN_BF16
    return bf2f(((const unsigned short*)p)[i]);
#else
    return ((const float*)p)[i];
#endif
}
__device__ __forceinline__ void st_out(void* o, size_t i, float v) {
#if OUT_BF16
    ((unsigned short*)o)[i] = f2bf(v);
#else
    ((float*)o)[i] = v;
#endif
}

// async global->LDS, 16 bytes/lane; LDS dst = wave-uniform base + lane*16
__device__ __forceinline__ void async_cp16(const unsigned short* g, unsigned short* l) {
    __builtin_amdgcn_global_load_lds(
        (const __attribute__((address_space(1))) unsigned int*)g,
        (__attribute__((address_space(3))) unsigned int*)l, 16, 0, 0);
}

// ---------------- fp32 -> bf16 conversion ----------------
__global__ __launch_bounds__(256) void cvt_kernel(const float* __restrict__ in,
                                                  unsigned short* __restrict__ out, int n) {
    int i = blockIdx.x * 256 + threadIdx.x;
    if (i < n) out[i] = f2bf(in[i]);
}

// fp32 [K][N] -> bf16 transposed [N][K]; tiled for coalescing. grid (K/32, N/32), 256 thr.
__global__ __launch_bounds__(256) void cvt_t_kernel(const float* __restrict__ in,
                                                    unsigned short* __restrict__ out, int K, int N) {
    __shared__ unsigned short tile[32][33];
    int bk = blockIdx.x * 32, bn = blockIdx.y * 32;
    int tx = threadIdx.x & 31, ty = threadIdx.x >> 5;     // ty 0..7
#pragma unroll
    for (int i = 0; i < 32; i += 8)
        tile[ty + i][tx] = f2bf(in[(size_t)(bk + ty + i) * N + bn + tx]);
    __syncthreads();
#pragma unroll
    for (int i = 0; i < 32; i += 8)
        out[(size_t)(bn + ty + i) * K + bk + tx] = tile[tx][ty + i];
}

// ---------------- edge dtype detection + CSR build ----------------
__global__ __launch_bounds__(256) void detect_kernel(const int* __restrict__ eb, int* __restrict__ flag) {
    int i = blockIdx.x * 256 + threadIdx.x;
    int v = eb[2 * (size_t)i + 1];
    unsigned long long b = __ballot(v != 0);
    if ((threadIdx.x & 63) == 0 && b)
        atomicAdd(flag, (int)__popcll(b));
}

__global__ __launch_bounds__(256) void hist_kernel(const int* __restrict__ eb, const int* __restrict__ flag,
                                                   int* __restrict__ deg) {
    int e = blockIdx.x * 256 + threadIdx.x;
    int st = (*flag == 0) ? 2 : 1;
    unsigned d = ((const unsigned*)eb)[(size_t)(NEDGE + e) * st] & (N_NODES - 1);
    atomicAdd(&deg[d], 1);
}

__global__ __launch_bounds__(256) void dinv_kernel(const int* __restrict__ deg, float* __restrict__ dinv) {
    int i = blockIdx.x * 256 + threadIdx.x;
    dinv[i] = rsqrtf((float)deg[i] + 1.0f);
}

__global__ __launch_bounds__(1024) void scan_kernel(const int* __restrict__ cnt, int* __restrict__ rowptr,
                                                    int* __restrict__ cursor) {
    __shared__ int part[1024];
    int t = threadIdx.x;
    int base = t * 32;
    int loc[32];
    int s = 0;
#pragma unroll
    for (int i = 0; i < 32; i++) { loc[i] = cnt[base + i]; s += loc[i]; }
    part[t] = s;
    __syncthreads();
    for (int off = 1; off < 1024; off <<= 1) {
        int v = (t >= off) ? part[t - off] : 0;
        __syncthreads();
        part[t] += v;
        __syncthreads();
    }
    int run = (t == 0) ? 0 : part[t - 1];
#pragma unroll
    for (int i = 0; i < 32; i++) {
        rowptr[base + i] = run;
        cursor[base + i] = run;
        run += loc[i];
    }
    if (t == 1023) rowptr[N_NODES] = run;
}

__global__ __launch_bounds__(256) void scatter_kernel(const int* __restrict__ eb, const int* __restrict__ flag,
                                                      int* __restrict__ cursor, int* __restrict__ srcs) {
    int e = blockIdx.x * 256 + threadIdx.x;
    int st = (*flag == 0) ? 2 : 1;
    unsigned s = ((const unsigned*)eb)[(size_t)e * st] & (N_NODES - 1);
    unsigned d = ((const unsigned*)eb)[(size_t)(NEDGE + e) * st] & (N_NODES - 1);
    int p = atomicAdd(&cursor[d], 1);
    srcs[p] = (int)s;
}

// ---------------- MFMA GEMM, m97-style ----------------
// C[M x Nn] = A[M x K](bf16 row-major) @ W (given as WT[Nn x K] bf16 row-major).
// Block tile 128x128, BK=64, 4 waves 2x2, wave tile 64x64 (4x4 16x16x32 MFMAs).
__global__ __launch_bounds__(256) void gemm_kernel(const unsigned short* __restrict__ A,
                                                   const unsigned short* __restrict__ WT,
                                                   const float* __restrict__ bias,
                                                   unsigned short* __restrict__ C,
                                                   int K, int Nn, int ldC, int colOff, int epi) {
    __shared__ unsigned short As[128 * 64];
    __shared__ unsigned short Bs[128 * 64];
    const int tid = threadIdx.x;
    const int wave = tid >> 6;
    const int lane = tid & 63;
    const int bm = blockIdx.y * 128;
    const int bn = blockIdx.x * 128;
    const int wm = (wave >> 1) * 64;
    const int wn = (wave & 1) * 64;
    const int l15 = lane & 15;
    const int q = lane >> 4;

    f32x4 acc[4][4] = {};

    const int srow = lane >> 3;      // 0..7
    const int schunk = lane & 7;     // 0..7

    for (int k0 = 0; k0 < K; k0 += 64) {
        __syncthreads();
#pragma unroll
        for (int t = 0; t < 4; t++) {
            int r = t * 32 + wave * 8 + srow;          // 0..127
            int gc = schunk ^ (r & 7);                  // xor swizzle at 16B granularity
            const unsigned short* ga = A + (size_t)(bm + r) * K + k0 + gc * 8;
            const unsigned short* gb = WT + (size_t)(bn + r) * K + k0 + gc * 8;
            unsigned short* la = &As[(t * 32 + wave * 8) * 64];
            unsigned short* lb = &Bs[(t * 32 + wave * 8) * 64];
            async_cp16(ga, la);
            async_cp16(gb, lb);
        }
        __syncthreads();

#pragma unroll
        for (int h = 0; h < 2; h++) {
            short8 af[4], bfv[4];
            int p = (h * 4 + q) ^ (l15 & 7);
#pragma unroll
            for (int t = 0; t < 4; t++) {
                int m = wm + t * 16 + l15;
                int n = wn + t * 16 + l15;
                af[t] = *(const short8*)&As[m * 64 + p * 8];
                bfv[t] = *(const short8*)&Bs[n * 64 + p * 8];
            }
#pragma unroll
            for (int tm = 0; tm < 4; tm++)
#pragma unroll
                for (int tn = 0; tn < 4; tn++)
                    acc[tm][tn] = __builtin_amdgcn_mfma_f32_16x16x32_bf16(af[tm], bfv[tn], acc[tm][tn], 0, 0, 0);
        }
    }

#pragma unroll
    for (int tm = 0; tm < 4; tm++) {
        int row = bm + wm + tm * 16 + q * 4;
#pragma unroll
        for (int tn = 0; tn < 4; tn++) {
            int col = bn + wn + tn * 16 + l15;
            float bv = bias ? bias[col] : 0.0f;
#pragma unroll
            for (int r = 0; r < 4; r++) {
                float v = acc[tm][tn][r] + bv;
                if (epi == 1) v = 1.0f / (1.0f + __expf(-v));
                C[(size_t)(row + r) * ldC + colOff + col] = f2bf(v);
            }
        }
    }
}

// ---------------- GCN aggregation (256-dim) ----------------
__global__ __launch_bounds__(256) void agg_kernel(const unsigned short* __restrict__ h,
                                                  const int* __restrict__ rowptr, const int* __restrict__ srcs,
                                                  const float* __restrict__ dinv, const void* __restrict__ bias,
                                                  unsigned short* __restrict__ out, int ldOut, int colOff,
                                                  int do_lrelu) {
    int wave = threadIdx.x >> 6, lane = threadIdx.x & 63;
    int v = blockIdx.x * 4 + wave;
    int f0 = lane * 4;
    float a0 = 0.f, a1 = 0.f, a2 = 0.f, a3 = 0.f;
    int s = rowptr[v], e = rowptr[v + 1];
    for (int i = s; i < e; i++) {
        int u = srcs[i] & (N_NODES - 1);
        float du = dinv[u];
        uint2 hv = *(const uint2*)(h + (size_t)u * 256 + f0);
        a0 += bf2f((unsigned short)(hv.x & 0xffff)) * du;
        a1 += bf2f((unsigned short)(hv.x >> 16)) * du;
        a2 += bf2f((unsigned short)(hv.y & 0xffff)) * du;
        a3 += bf2f((unsigned short)(hv.y >> 16)) * du;
    }
    float dv = dinv[v], dv2 = dv * dv;
    uint2 sv = *(const uint2*)(h + (size_t)v * 256 + f0);
    float r0 = dv * a0 + bf2f((unsigned short)(sv.x & 0xffff)) * dv2 + in_ld(bias, f0 + 0);
    float r1 = dv * a1 + bf2f((unsigned short)(sv.x >> 16)) * dv2 + in_ld(bias, f0 + 1);
    float r2 = dv * a2 + bf2f((unsigned short)(sv.y & 0xffff)) * dv2 + in_ld(bias, f0 + 2);
    float r3 = dv * a3 + bf2f((unsigned short)(sv.y >> 16)) * dv2 + in_ld(bias, f0 + 3);
    if (do_lrelu) {
        r0 = r0 > 0.f ? r0 : 0.01f * r0;
        r1 = r1 > 0.f ? r1 : 0.01f * r1;
        r2 = r2 > 0.f ? r2 : 0.01f * r2;
        r3 = r3 > 0.f ? r3 : 0.01f * r3;
    }
    unsigned o0 = f2bf(r0), o1 = f2bf(r1), o2 = f2bf(r2), o3 = f2bf(r3);
    uint2 ov = make_uint2((o1 << 16) | o0, (o3 << 16) | o2);
    *(uint2*)(out + (size_t)v * ldOut + colOff + f0) = ov;
}

// ---------------- score matvec ----------------
__global__ __launch_bounds__(256) void score_mv_kernel(const unsigned short* __restrict__ hf,
                                                       const void* __restrict__ wp, const void* __restrict__ wn,
                                                       float* __restrict__ svp, float* __restrict__ svn) {
    int wave = threadIdx.x >> 6, lane = threadIdx.x & 63;
    int v = blockIdx.x * 4 + wave;
    float sp = 0.f, sn = 0.f;
#pragma unroll
    for (int i = 0; i < 3; i++) {
        int k = i * 256 + lane * 4;
        uint2 hv = *(const uint2*)(hf + (size_t)v * 768 + k);
        float x0 = bf2f((unsigned short)(hv.x & 0xffff));
        float x1 = bf2f((unsigned short)(hv.x >> 16));
        float x2 = bf2f((unsigned short)(hv.y & 0xffff));
        float x3 = bf2f((unsigned short)(hv.y >> 16));
        sp += x0 * in_ld(wp, k) + x1 * in_ld(wp, k + 1) + x2 * in_ld(wp, k + 2) + x3 * in_ld(wp, k + 3);
        sn += x0 * in_ld(wn, k) + x1 * in_ld(wn, k + 1) + x2 * in_ld(wn, k + 2) + x3 * in_ld(wn, k + 3);
    }
    for (int off = 32; off >= 1; off >>= 1) {
        sp += __shfl_down(sp, off, 64);
        sn += __shfl_down(sn, off, 64);
    }
    if (lane == 0) { svp[v] = sp; svn[v] = sn; }
}

// ---------------- scalar GCN agg on scores + sigmoid ----------------
__global__ __launch_bounds__(256) void score_agg_kernel(const float* __restrict__ svp, const float* __restrict__ svn,
                                                        const int* __restrict__ rowptr, const int* __restrict__ srcs,
                                                        const float* __restrict__ dinv,
                                                        const void* __restrict__ bp, const void* __restrict__ bn_,
                                                        float* __restrict__ scp, float* __restrict__ scn,
                                                        void* __restrict__ dout) {
    int v = blockIdx.x * 256 + threadIdx.x;
    float ap = 0.f, an = 0.f;
    int s = rowptr[v], e = rowptr[v + 1];
    for (int i = s; i < e; i++) {
        int u = srcs[i] & (N_NODES - 1);
        float du = dinv[u];
        ap += svp[u] * du;
        an += svn[u] * du;
    }
    float dv = dinv[v], dv2 = dv * dv;
    float zp = dv * ap + svp[v] * dv2 + in_ld(bp, 0);
    float zn = dv * an + svn[v] * dv2 + in_ld(bn_, 0);
    float pp = 1.0f / (1.0f + __expf(-zp));
    float pn = 1.0f / (1.0f + __expf(-zn));
    scp[v] = pp;
    scn[v] = pn;
    st_out(dout, 1920 + (size_t)v, pp);
    st_out(dout, 1920 + (size_t)N_NODES + v, pn);
}

// ---------------- top-k mask per graph ----------------
__global__ __launch_bounds__(512) void topk_kernel(const float* __restrict__ sc, unsigned char* __restrict__ mask) {
    __shared__ float s[512];
    int g = blockIdx.x, i = threadIdx.x;
    float my = sc[(size_t)g * 512 + i];
    s[i] = my;
    __syncthreads();
    int cnt = 0;
    for (int j = 0; j < 512; j++) {
        float o = s[j];
        cnt += (int)((o > my) || ((o == my) && (j < i)));
    }
    mask[(size_t)g * 512 + i] = (cnt < TOPK) ? 1 : 0;
}

// ---------------- fused dual-mask readout ----------------
__global__ __launch_bounds__(256) void readout2_kernel(const unsigned short* __restrict__ xt,
                                                       const unsigned char* __restrict__ maskp,
                                                       const unsigned char* __restrict__ maskn,
                                                       float* __restrict__ eout) {
    int g = blockIdx.x;
    int c = blockIdx.y;
    int wv = threadIdx.x >> 6, lane = threadIdx.x & 63;
    int f = c * 64 + lane;
    __shared__ unsigned char mp[512], mn[512];
    __shared__ float red[4][64][4];
    for (int i = threadIdx.x; i < 512; i += 256) {
        mp[i] = maskp[(size_t)g * 512 + i];
        mn[i] = maskn[(size_t)g * 512 + i];
    }
    __syncthreads();
    float sp = 0.f, sn = 0.f, xp = -INFINITY, xn = -INFINITY;
    const unsigned short* base = xt + ((size_t)g * 512 + wv * 128) * 768 + f;
    for (int v = 0; v < 128; v++) {
        float x = bf2f(base[(size_t)v * 768]);
        if (mp[wv * 128 + v]) { sp += x; xp = fmaxf(xp, x); }
        if (mn[wv * 128 + v]) { sn += x; xn = fmaxf(xn, x); }
    }
    red[wv][lane][0] = sp; red[wv][lane][1] = xp;
    red[wv][lane][2] = sn; red[wv][lane][3] = xn;
    __syncthreads();
    if (wv == 0) {
#pragma unroll
        for (int w = 1; w < 4; w++) {
            sp += red[w][lane][0]; xp = fmaxf(xp, red[w][lane][1]);
            sn += red[w][lane][2]; xn = fmaxf(xn, red[w][lane][3]);
        }
        float* erp = eout + (size_t)g * 1536;
        float* ern = eout + (size_t)(64 + g) * 1536;
        erp[f] = sp * (1.0f / TOPK);
        erp[768 + f] = xp;
        ern[f] = sn * (1.0f / TOPK);
        ern[768 + f] = xn;
    }
}

// ---------------- MLP GEMM, k-split + n-split (fp32 exact path) ----------------
// grid (M=128, N/64=4); block 256 = 4 waves (k-slices) x 64 cols.
// Serial chain per thread = K/4 (384 for layer 1, 64 for layers 2/3).
__global__ __launch_bounds__(256) void mlp_gemm2_kernel(const float* __restrict__ in,
                                                        const float* __restrict__ W,
                                                        const float* __restrict__ b,
                                                        float* __restrict__ out, int K) {
    __shared__ float row[1536];
    __shared__ float red[4][64];
    int r = blockIdx.x, cg = blockIdx.y;
    int wv = threadIdx.x >> 6, lane = threadIdx.x & 63;
    int c = cg * 64 + lane;
    for (int k = threadIdx.x; k < K; k += 256) row[k] = in[(size_t)r * K + k];
    __syncthreads();
    int kpw = K >> 2;
    const float* wp = W + (size_t)(wv * kpw) * 256 + c;
    const float* rp = row + wv * kpw;
    float acc = 0.f;
#pragma unroll 4
    for (int k = 0; k < kpw; k++)
        acc += rp[k] * wp[(size_t)k * 256];
    red[wv][lane] = acc;
    __syncthreads();
    if (wv == 0) {
        float v = red[0][lane] + red[1][lane] + red[2][lane] + red[3][lane] + b[c];
        out[(size_t)r * 256 + c] = v;
    }
}

__global__ __launch_bounds__(64) void bn_kernel(const float* __restrict__ z, const void* __restrict__ gamma,
                                                const void* __restrict__ beta, const float* __restrict__ res,
                                                float* __restrict__ out) {
    int f = blockIdx.x & 255, g = blockIdx.x >> 8, r = threadIdx.x;
    size_t idx = (size_t)(g * 64 + r) * 256 + f;
    float x = z[idx];
    float s = x, sq = x * x;
    for (int off = 1; off < 64; off <<= 1) {
        s += __shfl_xor(s, off, 64);
        sq += __shfl_xor(sq, off, 64);
    }
    float m = s * (1.0f / 64.0f);
    float var = sq * (1.0f / 64.0f) - m * m;
    float y = (x - m) * rsqrtf(var + BN_EPS) * in_ld(gamma, f) + in_ld(beta, f);
    y = fmaxf(y, 0.0f);
    if (res) y += res[idx];
    out[idx] = y;
}

__global__ __launch_bounds__(64) void logits_kernel(const float* __restrict__ act, const void* __restrict__ w4,
                                                    const void* __restrict__ b4, float* __restrict__ lg) {
    int idx = blockIdx.x * 64 + threadIdx.x;
    if (idx >= 128 * NCLS) return;
    int r = idx / NCLS, c = idx % NCLS;
    float acc = in_ld(b4, c);
    for (int k = 0; k < 256; k++) acc += act[(size_t)r * 256 + k] * in_ld(w4, (size_t)k * NCLS + c);
    lg[idx] = acc;
}

__global__ __launch_bounds__(64) void softmax_kernel(const float* __restrict__ lg, void* __restrict__ dout) {
    int r = blockIdx.x * 64 + threadIdx.x;
    if (r >= 128) return;
    float l[NCLS];
    float mx = -1e30f;
    for (int c = 0; c < NCLS; c++) { l[c] = lg[(size_t)r * NCLS + c]; mx = fmaxf(mx, l[c]); }
    float sum = 0.f;
    float ex[NCLS];
    for (int c = 0; c < NCLS; c++) { ex[c] = __expf(l[c] - mx); sum += ex[c]; }
    float inv = 1.0f / sum;
    int g = r >> 6, rr = r & 63;
    if (g == 0) {
        for (int c = 0; c < NCLS; c++) st_out(dout, (size_t)rr * NCLS + c, l[c]);
        for (int c = 0; c < NCLS; c++) st_out(dout, 640 + (size_t)rr * NCLS + c, ex[c] * inv);
    } else {
        for (int c = 0; c < NCLS; c++) st_out(dout, 1280 + (size_t)rr * NCLS + c, ex[c] * inv);
    }
}

__global__ __launch_bounds__(256) void batch_kernel(void* __restrict__ dout) {
    int i = blockIdx.x * 256 + threadIdx.x;
    st_out(dout, 1920 + 2 * (size_t)N_NODES + i, (float)(i >> 9));
}

// ---------------- host launcher ----------------
extern "C" void kernel_launch(void* const* d_in, const int* in_sizes, int n_in,
                              void* d_out, int out_size, void* d_ws, size_t ws_size,
                              hipStream_t stream) {
    (void)in_sizes; (void)n_in; (void)out_size; (void)ws_size;

    const float* x = (const float*)d_in[0];
    const int* eb = (const int*)d_in[1];
    const float* w_s1 = (const float*)d_in[3];
    const float* b_s1 = (const float*)d_in[4];
    const float* w_s21 = (const float*)d_in[5];
    const float* b_s21 = (const float*)d_in[6];
    const float* w_s22 = (const float*)d_in[7];
    const float* b_s22 = (const float*)d_in[8];
    const float* w_raw = (const float*)d_in[9];
    const float* b_raw = (const float*)d_in[10];
    const void* w_pos = d_in[11];
    const void* b_pos = d_in[12];
    const void* w_neg = d_in[13];
    const void* b_neg = d_in[14];
    const float* w_pool = (const float*)d_in[15];
    const float* b_pool = (const float*)d_in[16];
    const float* w1 = (const float*)d_in[17];  const float* b1 = (const float*)d_in[18];
    const void* g1 = d_in[19];  const void* be1 = d_in[20];
    const float* w2 = (const float*)d_in[21];  const float* b2 = (const float*)d_in[22];
    const void* g2 = d_in[23];  const void* be2 = d_in[24];
    const float* w3 = (const float*)d_in[25];  const float* b3 = (const float*)d_in[26];
    const void* g3 = d_in[27];  const void* be3 = d_in[28];
    const void* w4 = d_in[29];  const void* b4 = d_in[30];

    char* ws = (char*)d_ws;
    size_t off = 0;
    auto alloc = [&](size_t b) -> void* {
        void* p = ws + off;
        off += (b + 255) & ~(size_t)255;
        return p;
    };
    int* flag = (int*)alloc(256);
    int* deg = (int*)alloc((size_t)N_NODES * 4);
    float* dinv = (float*)alloc((size_t)N_NODES * 4);
    int* rowptr = (int*)alloc((size_t)(N_NODES + 1) * 4);
    int* cursor = (int*)alloc((size_t)N_NODES * 4);
    int* srcs = (int*)alloc((size_t)NEDGE * 4);
    unsigned short* xbf = (unsigned short*)alloc((size_t)N_NODES * 256 * 2);
    unsigned short* wb_s1 = (unsigned short*)alloc((size_t)256 * 256 * 2);   // transposed [N][K]
    unsigned short* wb_s21 = (unsigned short*)alloc((size_t)256 * 256 * 2);
    unsigned short* wb_s22 = (unsigned short*)alloc((size_t)256 * 256 * 2);
    unsigned short* wb_raw = (unsigned short*)alloc((size_t)256 * 256 * 2);
    unsigned short* wb_pool = (unsigned short*)alloc((size_t)768 * 768 * 2);
    unsigned short* tmpA = (unsigned short*)alloc((size_t)N_NODES * 256 * 2);
    unsigned short* tmpB = (unsigned short*)alloc((size_t)N_NODES * 256 * 2);
    unsigned short* hfin = (unsigned short*)alloc((size_t)N_NODES * 768 * 2);
    unsigned short* xt = (unsigned short*)alloc((size_t)N_NODES * 768 * 2);
    float* svp = (float*)alloc((size_t)N_NODES * 4);
    float* svn = (float*)alloc((size_t)N_NODES * 4);
    float* scp = (float*)alloc((size_t)N_NODES * 4);
    float* scn = (float*)alloc((size_t)N_NODES * 4);
    unsigned char* maskp = (unsigned char*)alloc(N_NODES);
    unsigned char* maskn = (unsigned char*)alloc(N_NODES);
    float* ebuf = (float*)alloc((size_t)128 * 1536 * 4);
    float* zb = (float*)alloc((size_t)128 * 256 * 4);
    float* act1 = (float*)alloc((size_t)128 * 256 * 4);
    float* act2 = (float*)alloc((size_t)128 * 256 * 4);
    float* act3 = (float*)alloc((size_t)128 * 256 * 4);
    float* lg = (float*)alloc((size_t)128 * NCLS * 4);

    hipMemsetAsync(flag, 0, 256, stream);
    hipMemsetAsync(deg, 0, (size_t)N_NODES * 4, stream);
    detect_kernel<<<NEDGE / 256, 256, 0, stream>>>(eb, flag);
    hist_kernel<<<NEDGE / 256, 256, 0, stream>>>(eb, flag, deg);
    dinv_kernel<<<N_NODES / 256, 256, 0, stream>>>(deg, dinv);
    scan_kernel<<<1, 1024, 0, stream>>>(deg, rowptr, cursor);
    scatter_kernel<<<NEDGE / 256, 256, 0, stream>>>(eb, flag, cursor, srcs);

    // conversions: x row-major bf16; weights transposed to [N][K] bf16
    cvt_kernel<<<(N_NODES * 256 + 255) / 256, 256, 0, stream>>>(x, xbf, N_NODES * 256);
    {
        dim3 g8(8, 8), g24(24, 24);
        cvt_t_kernel<<<g8, 256, 0, stream>>>(w_s1, wb_s1, 256, 256);
        cvt_t_kernel<<<g8, 256, 0, stream>>>(w_s21, wb_s21, 256, 256);
        cvt_t_kernel<<<g8, 256, 0, stream>>>(w_s22, wb_s22, 256, 256);
        cvt_t_kernel<<<g8, 256, 0, stream>>>(w_raw, wb_raw, 256, 256);
        cvt_t_kernel<<<g24, 256, 0, stream>>>(w_pool, wb_pool, 768, 768);
    }

    dim3 gA(256 / 128, N_NODES / 128);   // (2, 256)
    dim3 gP(768 / 128, N_NODES / 128);   // (6, 256)

    // h_s1 branch
    gemm_kernel<<<gA, 256, 0, stream>>>(xbf, wb_s1, nullptr, tmpA, 256, 256, 256, 0, 0);
    agg_kernel<<<N_NODES / 4, 256, 0, stream>>>(tmpA, rowptr, srcs, dinv, b_s1, hfin, 768, 0, 1);
    // h_s2 branch (two GCN layers)
    gemm_kernel<<<gA, 256, 0, stream>>>(xbf, wb_s21, nullptr, tmpA, 256, 256, 256, 0, 0);
    agg_kernel<<<N_NODES / 4, 256, 0, stream>>>(tmpA, rowptr, srcs, dinv, b_s21, tmpB, 256, 0, 1);
    gemm_kernel<<<gA, 256, 0, stream>>>(tmpB, wb_s22, nullptr, tmpA, 256, 256, 256, 0, 0);
    agg_kernel<<<N_NODES / 4, 256, 0, stream>>>(tmpA, rowptr, srcs, dinv, b_s22, hfin, 768, 256, 1);
    // h_raw
    gemm_kernel<<<gA, 256, 0, stream>>>(xbf, wb_raw, b_raw, hfin, 256, 256, 768, 512, 0);
    // xt = sigmoid(h_final @ w_pool + b_pool)
    gemm_kernel<<<gP, 256, 0, stream>>>(hfin, wb_pool, b_pool, xt, 768, 768, 768, 0, 1);
    // scores
    score_mv_kernel<<<N_NODES / 4, 256, 0, stream>>>(hfin, w_pos, w_neg, svp, svn);
    score_agg_kernel<<<N_NODES / 256, 256, 0, stream>>>(svp, svn, rowptr, srcs, dinv, b_pos, b_neg, scp, scn, d_out);
    // top-k + fused readout
    topk_kernel<<<NGRAPH, 512, 0, stream>>>(scp, maskp);
    topk_kernel<<<NGRAPH, 512, 0, stream>>>(scn, maskn);
    {
        dim3 gR(NGRAPH, FDIM / 64);
        readout2_kernel<<<gR, 256, 0, stream>>>(xt, maskp, maskn, ebuf);
    }
    // MLP (k-split fp32 GEMMs: grid (row, colgroup))
    {
        dim3 gM(128, 4);
        mlp_gemm2_kernel<<<gM, 256, 0, stream>>>(ebuf, w1, b1, zb, 1536);
        bn_kernel<<<512, 64, 0, stream>>>(zb, g1, be1, nullptr, act1);
        mlp_gemm2_kernel<<<gM, 256, 0, stream>>>(act1, w2, b2, zb, 256);
        bn_kernel<<<512, 64, 0, stream>>>(zb, g2, be2, act1, act2);
        mlp_gemm2_kernel<<<gM, 256, 0, stream>>>(act2, w3, b3, zb, 256);
        bn_kernel<<<512, 64, 0, stream>>>(zb, g3, be3, act2, act3);
    }
    logits_kernel<<<(128 * NCLS + 63) / 64, 64, 0, stream>>>(act3, w4, b4, lg);
    softmax_kernel<<<2, 64, 0, stream>>>(lg, d_out);
    batch_kernel<<<N_NODES / 256, 256, 0, stream>>>(d_out);
}

// Round 6
// 627.352 us; speedup vs baseline: 1.7403x; 1.0325x over previous
//
#include <hip/hip_runtime.h>
#include <hip/hip_bf16.h>

// ---- problem constants ----
#define N_NODES 32768
#define NGRAPH  64
#define NPG     512
#define TOPK    256
#define HID     256
#define FDIM    768
#define NEDGE   262144
#define NCLS    10
#define BN_EPS  1e-5f

#define IN_BF16 0
#define OUT_BF16 0

typedef __attribute__((ext_vector_type(8))) short short8;
typedef __attribute__((ext_vector_type(4))) float f32x4;

__device__ __forceinline__ float bf2f(unsigned short u) {
    return __uint_as_float(((unsigned)u) << 16);
}
__device__ __forceinline__ unsigned short f2bf(float f) {
    unsigned x = __float_as_uint(f);
    unsigned r = (x + 0x7fffu + ((x >> 16) & 1u)) >> 16;
    return (unsigned short)r;
}
__device__ __forceinline__ float in_ld(const void* p, size_t i) {
#if IN_BF16
    return bf2f(((const unsigned short*)p)[i]);
#else
    return ((const float*)p)[i];
#endif
}
__device__ __forceinline__ void st_out(void* o, size_t i, float v) {
#if OUT_BF16
    ((unsigned short*)o)[i] = f2bf(v);
#else
    ((float*)o)[i] = v;
#endif
}

__device__ __forceinline__ void async_cp16(const unsigned short* g, unsigned short* l) {
    __builtin_amdgcn_global_load_lds(
        (const __attribute__((address_space(1))) unsigned int*)g,
        (__attribute__((address_space(3))) unsigned int*)l, 16, 0, 0);
}

// XCD-aware tile swizzle: all nx N-tiles of an M-slab map to one XCD (L%8).
// Requires gridDim.y % 8 == 0; bijective, so correctness never depends on it.
__device__ __forceinline__ void tile_swizzle(int& bm, int& bn) {
    int nx = gridDim.x;
    int L = blockIdx.y * nx + blockIdx.x;     // HW dispatch order (x fastest)
    int xcd = L & 7;
    int j = L >> 3;
    bm = ((j / nx) * 8 + xcd) * 128;
    bn = (j % nx) * 128;
}

// ---------------- fp32 -> bf16 conversion ----------------
__global__ __launch_bounds__(256) void cvt_kernel(const float* __restrict__ in,
                                                  unsigned short* __restrict__ out, int n) {
    int i = blockIdx.x * 256 + threadIdx.x;
    if (i < n) out[i] = f2bf(in[i]);
}

// fp32 [K][N] -> bf16 transposed [N][K]
__global__ __launch_bounds__(256) void cvt_t_kernel(const float* __restrict__ in,
                                                    unsigned short* __restrict__ out, int K, int N) {
    __shared__ unsigned short tile[32][33];
    int bk = blockIdx.x * 32, bn = blockIdx.y * 32;
    int tx = threadIdx.x & 31, ty = threadIdx.x >> 5;
#pragma unroll
    for (int i = 0; i < 32; i += 8)
        tile[ty + i][tx] = f2bf(in[(size_t)(bk + ty + i) * N + bn + tx]);
    __syncthreads();
#pragma unroll
    for (int i = 0; i < 32; i += 8)
        out[(size_t)(bn + ty + i) * K + bk + tx] = tile[tx][ty + i];
}

// ---------------- edge dtype detection + CSR build ----------------
__global__ __launch_bounds__(256) void detect_kernel(const int* __restrict__ eb, int* __restrict__ flag) {
    int i = blockIdx.x * 256 + threadIdx.x;
    int v = eb[2 * (size_t)i + 1];
    unsigned long long b = __ballot(v != 0);
    if ((threadIdx.x & 63) == 0 && b)
        atomicAdd(flag, (int)__popcll(b));
}

__global__ __launch_bounds__(256) void hist_kernel(const int* __restrict__ eb, const int* __restrict__ flag,
                                                   int* __restrict__ deg) {
    int e = blockIdx.x * 256 + threadIdx.x;
    int st = (*flag == 0) ? 2 : 1;
    unsigned d = ((const unsigned*)eb)[(size_t)(NEDGE + e) * st] & (N_NODES - 1);
    atomicAdd(&deg[d], 1);
}

__global__ __launch_bounds__(256) void dinv_kernel(const int* __restrict__ deg, float* __restrict__ dinv) {
    int i = blockIdx.x * 256 + threadIdx.x;
    dinv[i] = rsqrtf((float)deg[i] + 1.0f);
}

__global__ __launch_bounds__(1024) void scan_kernel(const int* __restrict__ cnt, int* __restrict__ rowptr,
                                                    int* __restrict__ cursor) {
    __shared__ int part[1024];
    int t = threadIdx.x;
    int base = t * 32;
    int loc[32];
    int s = 0;
#pragma unroll
    for (int i = 0; i < 32; i++) { loc[i] = cnt[base + i]; s += loc[i]; }
    part[t] = s;
    __syncthreads();
    for (int off = 1; off < 1024; off <<= 1) {
        int v = (t >= off) ? part[t - off] : 0;
        __syncthreads();
        part[t] += v;
        __syncthreads();
    }
    int run = (t == 0) ? 0 : part[t - 1];
#pragma unroll
    for (int i = 0; i < 32; i++) {
        rowptr[base + i] = run;
        cursor[base + i] = run;
        run += loc[i];
    }
    if (t == 1023) rowptr[N_NODES] = run;
}

__global__ __launch_bounds__(256) void scatter_kernel(const int* __restrict__ eb, const int* __restrict__ flag,
                                                      int* __restrict__ cursor, int* __restrict__ srcs) {
    int e = blockIdx.x * 256 + threadIdx.x;
    int st = (*flag == 0) ? 2 : 1;
    unsigned s = ((const unsigned*)eb)[(size_t)e * st] & (N_NODES - 1);
    unsigned d = ((const unsigned*)eb)[(size_t)(NEDGE + e) * st] & (N_NODES - 1);
    int p = atomicAdd(&cursor[d], 1);
    srcs[p] = (int)s;
}

// ---------------- GEMM core macro body (128x128 tile, BK=64) ----------------
#define GEMM_CORE(K_)                                                           \
    __shared__ unsigned short As[128 * 64];                                     \
    __shared__ unsigned short Bs[128 * 64];                                     \
    const int tid = threadIdx.x;                                                \
    const int wave = tid >> 6;                                                  \
    const int lane = tid & 63;                                                  \
    int bm, bn;                                                                 \
    tile_swizzle(bm, bn);                                                       \
    const int wm = (wave >> 1) * 64;                                            \
    const int wn = (wave & 1) * 64;                                             \
    const int l15 = lane & 15;                                                  \
    const int q = lane >> 4;                                                    \
    f32x4 acc[4][4] = {};                                                       \
    const int srow = lane >> 3;                                                 \
    const int schunk = lane & 7;                                                \
    for (int k0 = 0; k0 < (K_); k0 += 64) {                                     \
        __syncthreads();                                                        \
        _Pragma("unroll")                                                       \
        for (int t = 0; t < 4; t++) {                                           \
            int r = t * 32 + wave * 8 + srow;                                   \
            int gc = schunk ^ (r & 7);                                          \
            const unsigned short* ga = A + (size_t)(bm + r) * (K_) + k0 + gc * 8;\
            const unsigned short* gb = WT + (size_t)(bn + r) * (K_) + k0 + gc * 8;\
            unsigned short* la = &As[(t * 32 + wave * 8) * 64];                 \
            unsigned short* lb = &Bs[(t * 32 + wave * 8) * 64];                 \
            async_cp16(ga, la);                                                 \
            async_cp16(gb, lb);                                                 \
        }                                                                       \
        __syncthreads();                                                        \
        _Pragma("unroll")                                                       \
        for (int h = 0; h < 2; h++) {                                           \
            short8 af[4], bfv[4];                                               \
            int p = (h * 4 + q) ^ (l15 & 7);                                    \
            _Pragma("unroll")                                                   \
            for (int t = 0; t < 4; t++) {                                       \
                int m = wm + t * 16 + l15;                                      \
                int n = wn + t * 16 + l15;                                      \
                af[t] = *(const short8*)&As[m * 64 + p * 8];                    \
                bfv[t] = *(const short8*)&Bs[n * 64 + p * 8];                   \
            }                                                                   \
            _Pragma("unroll")                                                   \
            for (int tm = 0; tm < 4; tm++)                                      \
                _Pragma("unroll")                                               \
                for (int tn = 0; tn < 4; tn++)                                  \
                    acc[tm][tn] = __builtin_amdgcn_mfma_f32_16x16x32_bf16(af[tm], bfv[tn], acc[tm][tn], 0, 0, 0); \
        }                                                                       \
    }

// generic GEMM
__global__ __launch_bounds__(256) void gemm_kernel(const unsigned short* __restrict__ A,
                                                   const unsigned short* __restrict__ WT,
                                                   const float* __restrict__ bias,
                                                   unsigned short* __restrict__ C,
                                                   int K, int ldC, int colOff, int epi) {
    GEMM_CORE(K)
#pragma unroll
    for (int tm = 0; tm < 4; tm++) {
        int row = bm + wm + tm * 16 + q * 4;
#pragma unroll
        for (int tn = 0; tn < 4; tn++) {
            int col = bn + wn + tn * 16 + l15;
            float bv = bias ? bias[col] : 0.0f;
#pragma unroll
            for (int r = 0; r < 4; r++) {
                float v = acc[tm][tn][r] + bv;
                if (epi == 1) v = 1.0f / (1.0f + __expf(-v));
                C[(size_t)(row + r) * ldC + colOff + col] = f2bf(v);
            }
        }
    }
}

// merged 3-branch GEMM from xbf
__global__ __launch_bounds__(256) void gemm3_kernel(const unsigned short* __restrict__ A,
                                                    const unsigned short* __restrict__ WT,
                                                    const float* __restrict__ b_raw,
                                                    unsigned short* __restrict__ tA,
                                                    unsigned short* __restrict__ tB,
                                                    unsigned short* __restrict__ hfin) {
    GEMM_CORE(256)
#pragma unroll
    for (int tm = 0; tm < 4; tm++) {
        int row = bm + wm + tm * 16 + q * 4;
#pragma unroll
        for (int tn = 0; tn < 4; tn++) {
            int col = bn + wn + tn * 16 + l15;      // 16-aligned group: branch wave-uniform
            if (col < 256) {
#pragma unroll
                for (int r = 0; r < 4; r++)
                    tA[(size_t)(row + r) * 256 + col] = f2bf(acc[tm][tn][r]);
            } else if (col < 512) {
#pragma unroll
                for (int r = 0; r < 4; r++)
                    tB[(size_t)(row + r) * 256 + (col - 256)] = f2bf(acc[tm][tn][r]);
            } else {
                float bv = b_raw[col - 512];
#pragma unroll
                for (int r = 0; r < 4; r++)
                    hfin[(size_t)(row + r) * 768 + col] = f2bf(acc[tm][tn][r] + bv);
            }
        }
    }
}

// ---------------- GCN aggregation (256-dim) ----------------
__global__ __launch_bounds__(256) void agg_kernel(const unsigned short* __restrict__ h,
                                                  const int* __restrict__ rowptr, const int* __restrict__ srcs,
                                                  const float* __restrict__ dinv, const void* __restrict__ bias,
                                                  unsigned short* __restrict__ out, int ldOut, int colOff,
                                                  int do_lrelu) {
    int wave = threadIdx.x >> 6, lane = threadIdx.x & 63;
    int v = blockIdx.x * 4 + wave;
    int f0 = lane * 4;
    float a0 = 0.f, a1 = 0.f, a2 = 0.f, a3 = 0.f;
    int s = rowptr[v], e = rowptr[v + 1];
    for (int i = s; i < e; i++) {
        int u = srcs[i] & (N_NODES - 1);
        float du = dinv[u];
        uint2 hv = *(const uint2*)(h + (size_t)u * 256 + f0);
        a0 += bf2f((unsigned short)(hv.x & 0xffff)) * du;
        a1 += bf2f((unsigned short)(hv.x >> 16)) * du;
        a2 += bf2f((unsigned short)(hv.y & 0xffff)) * du;
        a3 += bf2f((unsigned short)(hv.y >> 16)) * du;
    }
    float dv = dinv[v], dv2 = dv * dv;
    uint2 sv = *(const uint2*)(h + (size_t)v * 256 + f0);
    float r0 = dv * a0 + bf2f((unsigned short)(sv.x & 0xffff)) * dv2 + in_ld(bias, f0 + 0);
    float r1 = dv * a1 + bf2f((unsigned short)(sv.x >> 16)) * dv2 + in_ld(bias, f0 + 1);
    float r2 = dv * a2 + bf2f((unsigned short)(sv.y & 0xffff)) * dv2 + in_ld(bias, f0 + 2);
    float r3 = dv * a3 + bf2f((unsigned short)(sv.y >> 16)) * dv2 + in_ld(bias, f0 + 3);
    if (do_lrelu) {
        r0 = r0 > 0.f ? r0 : 0.01f * r0;
        r1 = r1 > 0.f ? r1 : 0.01f * r1;
        r2 = r2 > 0.f ? r2 : 0.01f * r2;
        r3 = r3 > 0.f ? r3 : 0.01f * r3;
    }
    unsigned o0 = f2bf(r0), o1 = f2bf(r1), o2 = f2bf(r2), o3 = f2bf(r3);
    uint2 ov = make_uint2((o1 << 16) | o0, (o3 << 16) | o2);
    *(uint2*)(out + (size_t)v * ldOut + colOff + f0) = ov;
}

// ---------------- score matvec ----------------
__global__ __launch_bounds__(256) void score_mv_kernel(const unsigned short* __restrict__ hf,
                                                       const void* __restrict__ wp, const void* __restrict__ wn,
                                                       float* __restrict__ svp, float* __restrict__ svn) {
    int wave = threadIdx.x >> 6, lane = threadIdx.x & 63;
    int v = blockIdx.x * 4 + wave;
    float sp = 0.f, sn = 0.f;
#pragma unroll
    for (int i = 0; i < 3; i++) {
        int k = i * 256 + lane * 4;
        uint2 hv = *(const uint2*)(hf + (size_t)v * 768 + k);
        float x0 = bf2f((unsigned short)(hv.x & 0xffff));
        float x1 = bf2f((unsigned short)(hv.x >> 16));
        float x2 = bf2f((unsigned short)(hv.y & 0xffff));
        float x3 = bf2f((unsigned short)(hv.y >> 16));
        sp += x0 * in_ld(wp, k) + x1 * in_ld(wp, k + 1) + x2 * in_ld(wp, k + 2) + x3 * in_ld(wp, k + 3);
        sn += x0 * in_ld(wn, k) + x1 * in_ld(wn, k + 1) + x2 * in_ld(wn, k + 2) + x3 * in_ld(wn, k + 3);
    }
    for (int off = 32; off >= 1; off >>= 1) {
        sp += __shfl_down(sp, off, 64);
        sn += __shfl_down(sn, off, 64);
    }
    if (lane == 0) { svp[v] = sp; svn[v] = sn; }
}

// ---------------- scalar GCN agg on scores + sigmoid ----------------
__global__ __launch_bounds__(256) void score_agg_kernel(const float* __restrict__ svp, const float* __restrict__ svn,
                                                        const int* __restrict__ rowptr, const int* __restrict__ srcs,
                                                        const float* __restrict__ dinv,
                                                        const void* __restrict__ bp, const void* __restrict__ bn_,
                                                        float* __restrict__ scp, float* __restrict__ scn,
                                                        void* __restrict__ dout) {
    int v = blockIdx.x * 256 + threadIdx.x;
    float ap = 0.f, an = 0.f;
    int s = rowptr[v], e = rowptr[v + 1];
    for (int i = s; i < e; i++) {
        int u = srcs[i] & (N_NODES - 1);
        float du = dinv[u];
        ap += svp[u] * du;
        an += svn[u] * du;
    }
    float dv = dinv[v], dv2 = dv * dv;
    float zp = dv * ap + svp[v] * dv2 + in_ld(bp, 0);
    float zn = dv * an + svn[v] * dv2 + in_ld(bn_, 0);
    float pp = 1.0f / (1.0f + __expf(-zp));
    float pn = 1.0f / (1.0f + __expf(-zn));
    scp[v] = pp;
    scn[v] = pn;
    st_out(dout, 1920 + (size_t)v, pp);
    st_out(dout, 1920 + (size_t)N_NODES + v, pn);
}

// ---------------- top-k mask per graph ----------------
__global__ __launch_bounds__(512) void topk_kernel(const float* __restrict__ sc, unsigned char* __restrict__ mask) {
    __shared__ float s[512];
    int g = blockIdx.x, i = threadIdx.x;
    float my = sc[(size_t)g * 512 + i];
    s[i] = my;
    __syncthreads();
    int cnt = 0;
    for (int j = 0; j < 512; j++) {
        float o = s[j];
        cnt += (int)((o > my) || ((o == my) && (j < i)));
    }
    mask[(size_t)g * 512 + i] = (cnt < TOPK) ? 1 : 0;
}

// ---------------- fused dual-mask readout ----------------
__global__ __launch_bounds__(256) void readout2_kernel(const unsigned short* __restrict__ xt,
                                                       const unsigned char* __restrict__ maskp,
                                                       const unsigned char* __restrict__ maskn,
                                                       float* __restrict__ eout) {
    int g = blockIdx.x;
    int c = blockIdx.y;
    int wv = threadIdx.x >> 6, lane = threadIdx.x & 63;
    int f = c * 64 + lane;
    __shared__ unsigned char mp[512], mn[512];
    __shared__ float red[4][64][4];
    for (int i = threadIdx.x; i < 512; i += 256) {
        mp[i] = maskp[(size_t)g * 512 + i];
        mn[i] = maskn[(size_t)g * 512 + i];
    }
    __syncthreads();
    float sp = 0.f, sn = 0.f, xp = -INFINITY, xn = -INFINITY;
    const unsigned short* base = xt + ((size_t)g * 512 + wv * 128) * 768 + f;
    for (int v = 0; v < 128; v++) {
        float x = bf2f(base[(size_t)v * 768]);
        if (mp[wv * 128 + v]) { sp += x; xp = fmaxf(xp, x); }
        if (mn[wv * 128 + v]) { sn += x; xn = fmaxf(xn, x); }
    }
    red[wv][lane][0] = sp; red[wv][lane][1] = xp;
    red[wv][lane][2] = sn; red[wv][lane][3] = xn;
    __syncthreads();
    if (wv == 0) {
#pragma unroll
        for (int w = 1; w < 4; w++) {
            sp += red[w][lane][0]; xp = fmaxf(xp, red[w][lane][1]);
            sn += red[w][lane][2]; xn = fmaxf(xn, red[w][lane][3]);
        }
        float* erp = eout + (size_t)g * 1536;
        float* ern = eout + (size_t)(64 + g) * 1536;
        erp[f] = sp * (1.0f / TOPK);
        erp[768 + f] = xp;
        ern[f] = sn * (1.0f / TOPK);
        ern[768 + f] = xn;
    }
}

// ---------------- MLP GEMM, k-split + n-split ----------------
__global__ __launch_bounds__(256) void mlp_gemm2_kernel(const float* __restrict__ in,
                                                        const float* __restrict__ W,
                                                        const float* __restrict__ b,
                                                        float* __restrict__ out, int K) {
    __shared__ float row[1536];
    __shared__ float red[4][64];
    int r = blockIdx.x, cg = blockIdx.y;
    int wv = threadIdx.x >> 6, lane = threadIdx.x & 63;
    int c = cg * 64 + lane;
    for (int k = threadIdx.x; k < K; k += 256) row[k] = in[(size_t)r * K + k];
    __syncthreads();
    int kpw = K >> 2;
    const float* wp = W + (size_t)(wv * kpw) * 256 + c;
    const float* rp = row + wv * kpw;
    float acc = 0.f;
#pragma unroll 4
    for (int k = 0; k < kpw; k++)
        acc += rp[k] * wp[(size_t)k * 256];
    red[wv][lane] = acc;
    __syncthreads();
    if (wv == 0) {
        float v = red[0][lane] + red[1][lane] + red[2][lane] + red[3][lane] + b[c];
        out[(size_t)r * 256 + c] = v;
    }
}

__global__ __launch_bounds__(64) void bn_kernel(const float* __restrict__ z, const void* __restrict__ gamma,
                                                const void* __restrict__ beta, const float* __restrict__ res,
                                                float* __restrict__ out) {
    int f = blockIdx.x & 255, g = blockIdx.x >> 8, r = threadIdx.x;
    size_t idx = (size_t)(g * 64 + r) * 256 + f;
    float x = z[idx];
    float s = x, sq = x * x;
    for (int off = 1; off < 64; off <<= 1) {
        s += __shfl_xor(s, off, 64);
        sq += __shfl_xor(sq, off, 64);
    }
    float m = s * (1.0f / 64.0f);
    float var = sq * (1.0f / 64.0f) - m * m;
    float y = (x - m) * rsqrtf(var + BN_EPS) * in_ld(gamma, f) + in_ld(beta, f);
    y = fmaxf(y, 0.0f);
    if (res) y += res[idx];
    out[idx] = y;
}

__global__ __launch_bounds__(64) void logits_kernel(const float* __restrict__ act, const void* __restrict__ w4,
                                                    const void* __restrict__ b4, float* __restrict__ lg) {
    int idx = blockIdx.x * 64 + threadIdx.x;
    if (idx >= 128 * NCLS) return;
    int r = idx / NCLS, c = idx % NCLS;
    float acc = in_ld(b4, c);
    for (int k = 0; k < 256; k++) acc += act[(size_t)r * 256 + k] * in_ld(w4, (size_t)k * NCLS + c);
    lg[idx] = acc;
}

__global__ __launch_bounds__(64) void softmax_kernel(const float* __restrict__ lg, void* __restrict__ dout) {
    int r = blockIdx.x * 64 + threadIdx.x;
    if (r >= 128) return;
    float l[NCLS];
    float mx = -1e30f;
    for (int c = 0; c < NCLS; c++) { l[c] = lg[(size_t)r * NCLS + c]; mx = fmaxf(mx, l[c]); }
    float sum = 0.f;
    float ex[NCLS];
    for (int c = 0; c < NCLS; c++) { ex[c] = __expf(l[c] - mx); sum += ex[c]; }
    float inv = 1.0f / sum;
    int g = r >> 6, rr = r & 63;
    if (g == 0) {
        for (int c = 0; c < NCLS; c++) st_out(dout, (size_t)rr * NCLS + c, l[c]);
        for (int c = 0; c < NCLS; c++) st_out(dout, 640 + (size_t)rr * NCLS + c, ex[c] * inv);
    } else {
        for (int c = 0; c < NCLS; c++) st_out(dout, 1280 + (size_t)rr * NCLS + c, ex[c] * inv);
    }
}

__global__ __launch_bounds__(256) void batch_kernel(void* __restrict__ dout) {
    int i = blockIdx.x * 256 + threadIdx.x;
    st_out(dout, 1920 + 2 * (size_t)N_NODES + i, (float)(i >> 9));
}

// ---------------- host launcher ----------------
extern "C" void kernel_launch(void* const* d_in, const int* in_sizes, int n_in,
                              void* d_out, int out_size, void* d_ws, size_t ws_size,
                              hipStream_t stream) {
    (void)in_sizes; (void)n_in; (void)out_size; (void)ws_size;

    const float* x = (const float*)d_in[0];
    const int* eb = (const int*)d_in[1];
    const float* w_s1 = (const float*)d_in[3];
    const float* b_s1 = (const float*)d_in[4];
    const float* w_s21 = (const float*)d_in[5];
    const float* b_s21 = (const float*)d_in[6];
    const float* w_s22 = (const float*)d_in[7];
    const float* b_s22 = (const float*)d_in[8];
    const float* w_raw = (const float*)d_in[9];
    const float* b_raw = (const float*)d_in[10];
    const void* w_pos = d_in[11];
    const void* b_pos = d_in[12];
    const void* w_neg = d_in[13];
    const void* b_neg = d_in[14];
    const float* w_pool = (const float*)d_in[15];
    const float* b_pool = (const float*)d_in[16];
    const float* w1 = (const float*)d_in[17];  const float* b1 = (const float*)d_in[18];
    const void* g1 = d_in[19];  const void* be1 = d_in[20];
    const float* w2 = (const float*)d_in[21];  const float* b2 = (const float*)d_in[22];
    const void* g2 = d_in[23];  const void* be2 = d_in[24];
    const float* w3 = (const float*)d_in[25];  const float* b3 = (const float*)d_in[26];
    const void* g3 = d_in[27];  const void* be3 = d_in[28];
    const void* w4 = d_in[29];  const void* b4 = d_in[30];

    char* ws = (char*)d_ws;
    size_t off = 0;
    auto alloc = [&](size_t b) -> void* {
        void* p = ws + off;
        off += (b + 255) & ~(size_t)255;
        return p;
    };
    int* flag = (int*)alloc(256);
    int* deg = (int*)alloc((size_t)N_NODES * 4);
    float* dinv = (float*)alloc((size_t)N_NODES * 4);
    int* rowptr = (int*)alloc((size_t)(N_NODES + 1) * 4);
    int* cursor = (int*)alloc((size_t)N_NODES * 4);
    int* srcs = (int*)alloc((size_t)NEDGE * 4);
    unsigned short* xbf = (unsigned short*)alloc((size_t)N_NODES * 256 * 2);
    unsigned short* wcat = (unsigned short*)alloc((size_t)768 * 256 * 2);
    unsigned short* wb_s22 = (unsigned short*)alloc((size_t)256 * 256 * 2);
    unsigned short* wb_pool = (unsigned short*)alloc((size_t)768 * 768 * 2);
    unsigned short* tA = (unsigned short*)alloc((size_t)N_NODES * 256 * 2);
    unsigned short* tB = (unsigned short*)alloc((size_t)N_NODES * 256 * 2);
    unsigned short* tmpB = (unsigned short*)alloc((size_t)N_NODES * 256 * 2);
    unsigned short* hfin = (unsigned short*)alloc((size_t)N_NODES * 768 * 2);
    unsigned short* xt = (unsigned short*)alloc((size_t)N_NODES * 768 * 2);
    float* svp = (float*)alloc((size_t)N_NODES * 4);
    float* svn = (float*)alloc((size_t)N_NODES * 4);
    float* scp = (float*)alloc((size_t)N_NODES * 4);
    float* scn = (float*)alloc((size_t)N_NODES * 4);
    unsigned char* maskp = (unsigned char*)alloc(N_NODES);
    unsigned char* maskn = (unsigned char*)alloc(N_NODES);
    float* ebuf = (float*)alloc((size_t)128 * 1536 * 4);
    float* zb = (float*)alloc((size_t)128 * 256 * 4);
    float* act1 = (float*)alloc((size_t)128 * 256 * 4);
    float* act2 = (float*)alloc((size_t)128 * 256 * 4);
    float* act3 = (float*)alloc((size_t)128 * 256 * 4);
    float* lg = (float*)alloc((size_t)128 * NCLS * 4);

    hipMemsetAsync(flag, 0, 256, stream);
    hipMemsetAsync(deg, 0, (size_t)N_NODES * 4, stream);
    detect_kernel<<<NEDGE / 256, 256, 0, stream>>>(eb, flag);
    hist_kernel<<<NEDGE / 256, 256, 0, stream>>>(eb, flag, deg);
    dinv_kernel<<<N_NODES / 256, 256, 0, stream>>>(deg, dinv);
    scan_kernel<<<1, 1024, 0, stream>>>(deg, rowptr, cursor);
    scatter_kernel<<<NEDGE / 256, 256, 0, stream>>>(eb, flag, cursor, srcs);

    // conversions
    cvt_kernel<<<(N_NODES * 256 + 255) / 256, 256, 0, stream>>>(x, xbf, N_NODES * 256);
    {
        dim3 g8(8, 8), g24(24, 24);
        cvt_t_kernel<<<g8, 256, 0, stream>>>(w_s1, wcat, 256, 256);
        cvt_t_kernel<<<g8, 256, 0, stream>>>(w_s21, wcat + (size_t)256 * 256, 256, 256);
        cvt_t_kernel<<<g8, 256, 0, stream>>>(w_raw, wcat + (size_t)512 * 256, 256, 256);
        cvt_t_kernel<<<g8, 256, 0, stream>>>(w_s22, wb_s22, 256, 256);
        cvt_t_kernel<<<g24, 256, 0, stream>>>(w_pool, wb_pool, 768, 768);
    }

    dim3 gG3(768 / 128, N_NODES / 128);  // (6, 256)
    dim3 gA(256 / 128, N_NODES / 128);   // (2, 256)
    dim3 gP(768 / 128, N_NODES / 128);   // (6, 256)

    // merged s1/s21/raw GEMM (xbf fetched once)
    gemm3_kernel<<<gG3, 256, 0, stream>>>(xbf, wcat, b_raw, tA, tB, hfin);
    // aggregations
    agg_kernel<<<N_NODES / 4, 256, 0, stream>>>(tA, rowptr, srcs, dinv, b_s1, hfin, 768, 0, 1);
    agg_kernel<<<N_NODES / 4, 256, 0, stream>>>(tB, rowptr, srcs, dinv, b_s21, tmpB, 256, 0, 1);
    gemm_kernel<<<gA, 256, 0, stream>>>(tmpB, wb_s22, nullptr, tA, 256, 256, 0, 0);
    agg_kernel<<<N_NODES / 4, 256, 0, stream>>>(tA, rowptr, srcs, dinv, b_s22, hfin, 768, 256, 1);
    // xt = sigmoid(h_final @ w_pool + b_pool)
    gemm_kernel<<<gP, 256, 0, stream>>>(hfin, wb_pool, b_pool, xt, 768, 768, 0, 1);
    // scores
    score_mv_kernel<<<N_NODES / 4, 256, 0, stream>>>(hfin, w_pos, w_neg, svp, svn);
    score_agg_kernel<<<N_NODES / 256, 256, 0, stream>>>(svp, svn, rowptr, srcs, dinv, b_pos, b_neg, scp, scn, d_out);
    // top-k + fused readout
    topk_kernel<<<NGRAPH, 512, 0, stream>>>(scp, maskp);
    topk_kernel<<<NGRAPH, 512, 0, stream>>>(scn, maskn);
    {
        dim3 gR(NGRAPH, FDIM / 64);
        readout2_kernel<<<gR, 256, 0, stream>>>(xt, maskp, maskn, ebuf);
    }
    // MLP
    {
        dim3 gM(128, 4);
        mlp_gemm2_kernel<<<gM, 256, 0, stream>>>(ebuf, w1, b1, zb, 1536);
        bn_kernel<<<512, 64, 0, stream>>>(zb, g1, be1, nullptr, act1);
        mlp_gemm2_kernel<<<gM, 256, 0, stream>>>(act1, w2, b2, zb, 256);
        bn_kernel<<<512, 64, 0, stream>>>(zb, g2, be2, act1, act2);
        mlp_gemm2_kernel<<<gM, 256, 0, stream>>>(act2, w3, b3, zb, 256);
        bn_kernel<<<512, 64, 0, stream>>>(zb, g3, be3, act2, act3);
    }
    logits_kernel<<<(128 * NCLS + 63) / 64, 64, 0, stream>>>(act3, w4, b4, lg);
    softmax_kernel<<<2, 64, 0, stream>>>(lg, d_out);
    batch_kernel<<<N_NODES / 256, 256, 0, stream>>>(d_out);
}

// Round 7
// 603.495 us; speedup vs baseline: 1.8091x; 1.0395x over previous
//
#include <hip/hip_runtime.h>
#include <hip/hip_bf16.h>

// ---- problem constants ----
#define N_NODES 32768
#define NGRAPH  64
#define NPG     512
#define TOPK    256
#define HID     256
#define FDIM    768
#define NEDGE   262144
#define NCLS    10
#define BN_EPS  1e-5f

#define IN_BF16 0
#define OUT_BF16 0

typedef __attribute__((ext_vector_type(8))) short short8;
typedef __attribute__((ext_vector_type(4))) float f32x4;

__device__ __forceinline__ float bf2f(unsigned short u) {
    return __uint_as_float(((unsigned)u) << 16);
}
__device__ __forceinline__ unsigned short f2bf(float f) {
    unsigned x = __float_as_uint(f);
    unsigned r = (x + 0x7fffu + ((x >> 16) & 1u)) >> 16;
    return (unsigned short)r;
}
__device__ __forceinline__ float in_ld(const void* p, size_t i) {
#if IN_BF16
    return bf2f(((const unsigned short*)p)[i]);
#else
    return ((const float*)p)[i];
#endif
}
__device__ __forceinline__ void st_out(void* o, size_t i, float v) {
#if OUT_BF16
    ((unsigned short*)o)[i] = f2bf(v);
#else
    ((float*)o)[i] = v;
#endif
}

__device__ __forceinline__ void async_cp16(const unsigned short* g, unsigned short* l) {
    __builtin_amdgcn_global_load_lds(
        (const __attribute__((address_space(1))) unsigned int*)g,
        (__attribute__((address_space(3))) unsigned int*)l, 16, 0, 0);
}

// XCD-aware tile swizzle: all nx N-tiles of an M-slab map to one XCD (L%8).
__device__ __forceinline__ void tile_swizzle(int& bm, int& bn) {
    int nx = gridDim.x;
    int L = blockIdx.y * nx + blockIdx.x;
    int xcd = L & 7;
    int j = L >> 3;
    bm = ((j / nx) * 8 + xcd) * 128;
    bn = (j % nx) * 128;
}

// ---------------- fp32 -> bf16 conversion ----------------
__global__ __launch_bounds__(256) void cvt_kernel(const float* __restrict__ in,
                                                  unsigned short* __restrict__ out, int n) {
    int i = blockIdx.x * 256 + threadIdx.x;
    if (i < n) out[i] = f2bf(in[i]);
}

// all 5 weight transposes (fp32 [K][N] -> bf16 [N][K]) in ONE launch.
// flat tile ids: 0-63 w_s1, 64-127 w_s21, 128-191 w_raw, 192-255 w_s22, 256-831 w_pool.
__global__ __launch_bounds__(256) void cvt_t_all_kernel(const float* __restrict__ w_s1,
                                                        const float* __restrict__ w_s21,
                                                        const float* __restrict__ w_raw,
                                                        const float* __restrict__ w_s22,
                                                        const float* __restrict__ w_pool,
                                                        unsigned short* __restrict__ wcat,
                                                        unsigned short* __restrict__ wb_s22,
                                                        unsigned short* __restrict__ wb_pool) {
    __shared__ unsigned short tile[32][33];
    int id = blockIdx.x;
    const float* src;
    unsigned short* dst;
    int K, N, t;
    if (id < 64)       { src = w_s1;  dst = wcat;                       K = 256; N = 256; t = id; }
    else if (id < 128) { src = w_s21; dst = wcat + (size_t)256 * 256;   K = 256; N = 256; t = id - 64; }
    else if (id < 192) { src = w_raw; dst = wcat + (size_t)512 * 256;   K = 256; N = 256; t = id - 128; }
    else if (id < 256) { src = w_s22; dst = wb_s22;                     K = 256; N = 256; t = id - 192; }
    else               { src = w_pool; dst = wb_pool;                   K = 768; N = 768; t = id - 256; }
    int tiles_x = K >> 5;
    int bk = (t % tiles_x) * 32, bn = (t / tiles_x) * 32;
    int tx = threadIdx.x & 31, ty = threadIdx.x >> 5;
#pragma unroll
    for (int i = 0; i < 32; i += 8)
        tile[ty + i][tx] = f2bf(src[(size_t)(bk + ty + i) * N + bn + tx]);
    __syncthreads();
#pragma unroll
    for (int i = 0; i < 32; i += 8)
        dst[(size_t)(bn + ty + i) * K + bk + tx] = tile[tx][ty + i];
}

// ---------------- edge dtype detection + CSR build ----------------
__global__ __launch_bounds__(256) void detect_kernel(const int* __restrict__ eb, int* __restrict__ flag) {
    int i = blockIdx.x * 256 + threadIdx.x;
    int v = eb[2 * (size_t)i + 1];
    unsigned long long b = __ballot(v != 0);
    if ((threadIdx.x & 63) == 0 && b)
        atomicAdd(flag, (int)__popcll(b));
}

__global__ __launch_bounds__(256) void hist_kernel(const int* __restrict__ eb, const int* __restrict__ flag,
                                                   int* __restrict__ deg) {
    int e = blockIdx.x * 256 + threadIdx.x;
    int st = (*flag == 0) ? 2 : 1;
    unsigned d = ((const unsigned*)eb)[(size_t)(NEDGE + e) * st] & (N_NODES - 1);
    atomicAdd(&deg[d], 1);
}

// scan + dinv fused
__global__ __launch_bounds__(1024) void scan_kernel(const int* __restrict__ cnt, int* __restrict__ rowptr,
                                                    int* __restrict__ cursor, float* __restrict__ dinv) {
    __shared__ int part[1024];
    int t = threadIdx.x;
    int base = t * 32;
    int loc[32];
    int s = 0;
#pragma unroll
    for (int i = 0; i < 32; i++) { loc[i] = cnt[base + i]; s += loc[i]; }
    part[t] = s;
    __syncthreads();
    for (int off = 1; off < 1024; off <<= 1) {
        int v = (t >= off) ? part[t - off] : 0;
        __syncthreads();
        part[t] += v;
        __syncthreads();
    }
    int run = (t == 0) ? 0 : part[t - 1];
#pragma unroll
    for (int i = 0; i < 32; i++) {
        rowptr[base + i] = run;
        cursor[base + i] = run;
        dinv[base + i] = rsqrtf((float)loc[i] + 1.0f);
        run += loc[i];
    }
    if (t == 1023) rowptr[N_NODES] = run;
}

__global__ __launch_bounds__(256) void scatter_kernel(const int* __restrict__ eb, const int* __restrict__ flag,
                                                      int* __restrict__ cursor, int* __restrict__ srcs) {
    int e = blockIdx.x * 256 + threadIdx.x;
    int st = (*flag == 0) ? 2 : 1;
    unsigned s = ((const unsigned*)eb)[(size_t)e * st] & (N_NODES - 1);
    unsigned d = ((const unsigned*)eb)[(size_t)(NEDGE + e) * st] & (N_NODES - 1);
    int p = atomicAdd(&cursor[d], 1);
    srcs[p] = (int)s;
}

// ---------------- GEMM core macro body (128x128 tile, BK=64) ----------------
// K_ is a compile-time constant in every instantiation -> compiler can unroll,
// fold k0 into load offsets, and hoist LDS fragment addresses (VALU relief).
#define GEMM_CORE(K_)                                                           \
    __shared__ unsigned short As[128 * 64];                                     \
    __shared__ unsigned short Bs[128 * 64];                                     \
    const int tid = threadIdx.x;                                                \
    const int wave = tid >> 6;                                                  \
    const int lane = tid & 63;                                                  \
    int bm, bn;                                                                 \
    tile_swizzle(bm, bn);                                                       \
    const int wm = (wave >> 1) * 64;                                            \
    const int wn = (wave & 1) * 64;                                             \
    const int l15 = lane & 15;                                                  \
    const int q = lane >> 4;                                                    \
    f32x4 acc[4][4] = {};                                                       \
    const int srow = lane >> 3;                                                 \
    const int schunk = lane & 7;                                                \
    for (int k0 = 0; k0 < (K_); k0 += 64) {                                     \
        __syncthreads();                                                        \
        _Pragma("unroll")                                                       \
        for (int t = 0; t < 4; t++) {                                           \
            int r = t * 32 + wave * 8 + srow;                                   \
            int gc = schunk ^ (r & 7);                                          \
            const unsigned short* ga = A + (size_t)(bm + r) * (K_) + k0 + gc * 8;\
            const unsigned short* gb = WT + (size_t)(bn + r) * (K_) + k0 + gc * 8;\
            unsigned short* la = &As[(t * 32 + wave * 8) * 64];                 \
            unsigned short* lb = &Bs[(t * 32 + wave * 8) * 64];                 \
            async_cp16(ga, la);                                                 \
            async_cp16(gb, lb);                                                 \
        }                                                                       \
        __syncthreads();                                                        \
        _Pragma("unroll")                                                       \
        for (int h = 0; h < 2; h++) {                                           \
            short8 af[4], bfv[4];                                               \
            int p = (h * 4 + q) ^ (l15 & 7);                                    \
            _Pragma("unroll")                                                   \
            for (int t = 0; t < 4; t++) {                                       \
                int m = wm + t * 16 + l15;                                      \
                int n = wn + t * 16 + l15;                                      \
                af[t] = *(const short8*)&As[m * 64 + p * 8];                    \
                bfv[t] = *(const short8*)&Bs[n * 64 + p * 8];                   \
            }                                                                   \
            _Pragma("unroll")                                                   \
            for (int tm = 0; tm < 4; tm++)                                      \
                _Pragma("unroll")                                               \
                for (int tn = 0; tn < 4; tn++)                                  \
                    acc[tm][tn] = __builtin_amdgcn_mfma_f32_16x16x32_bf16(af[tm], bfv[tn], acc[tm][tn], 0, 0, 0); \
        }                                                                       \
    }

// generic GEMM, compile-time K
template <int K_>
__global__ __launch_bounds__(256) void gemm_kernel(const unsigned short* __restrict__ A,
                                                   const unsigned short* __restrict__ WT,
                                                   const float* __restrict__ bias,
                                                   unsigned short* __restrict__ C,
                                                   int ldC, int colOff, int epi) {
    GEMM_CORE(K_)
#pragma unroll
    for (int tm = 0; tm < 4; tm++) {
        int row = bm + wm + tm * 16 + q * 4;
#pragma unroll
        for (int tn = 0; tn < 4; tn++) {
            int col = bn + wn + tn * 16 + l15;
            float bv = bias ? bias[col] : 0.0f;
#pragma unroll
            for (int r = 0; r < 4; r++) {
                float v = acc[tm][tn][r] + bv;
                if (epi == 1) v = 1.0f / (1.0f + __expf(-v));
                C[(size_t)(row + r) * ldC + colOff + col] = f2bf(v);
            }
        }
    }
}

// merged 3-branch GEMM from xbf
__global__ __launch_bounds__(256) void gemm3_kernel(const unsigned short* __restrict__ A,
                                                    const unsigned short* __restrict__ WT,
                                                    const float* __restrict__ b_raw,
                                                    unsigned short* __restrict__ tA,
                                                    unsigned short* __restrict__ tB,
                                                    unsigned short* __restrict__ hfin) {
    GEMM_CORE(256)
#pragma unroll
    for (int tm = 0; tm < 4; tm++) {
        int row = bm + wm + tm * 16 + q * 4;
#pragma unroll
        for (int tn = 0; tn < 4; tn++) {
            int col = bn + wn + tn * 16 + l15;      // 16-aligned group: branch wave-uniform
            if (col < 256) {
#pragma unroll
                for (int r = 0; r < 4; r++)
                    tA[(size_t)(row + r) * 256 + col] = f2bf(acc[tm][tn][r]);
            } else if (col < 512) {
#pragma unroll
                for (int r = 0; r < 4; r++)
                    tB[(size_t)(row + r) * 256 + (col - 256)] = f2bf(acc[tm][tn][r]);
            } else {
                float bv = b_raw[col - 512];
#pragma unroll
                for (int r = 0; r < 4; r++)
                    hfin[(size_t)(row + r) * 768 + col] = f2bf(acc[tm][tn][r] + bv);
            }
        }
    }
}

// ---------------- dual GCN aggregation: s1 and s21 share the CSR walk ----------------
__global__ __launch_bounds__(256) void agg2_kernel(const unsigned short* __restrict__ hA,
                                                   const unsigned short* __restrict__ hB,
                                                   const int* __restrict__ rowptr, const int* __restrict__ srcs,
                                                   const float* __restrict__ dinv,
                                                   const float* __restrict__ biasA, const float* __restrict__ biasB,
                                                   unsigned short* __restrict__ outA,   // hfin, ld 768, col 0
                                                   unsigned short* __restrict__ outB) { // tmpB, ld 256
    int wave = threadIdx.x >> 6, lane = threadIdx.x & 63;
    int v = blockIdx.x * 4 + wave;
    int f0 = lane * 4;
    float a0 = 0.f, a1 = 0.f, a2 = 0.f, a3 = 0.f;
    float c0 = 0.f, c1 = 0.f, c2 = 0.f, c3 = 0.f;
    int s = rowptr[v], e = rowptr[v + 1];
    for (int i = s; i < e; i++) {
        int u = srcs[i] & (N_NODES - 1);
        float du = dinv[u];
        uint2 ha = *(const uint2*)(hA + (size_t)u * 256 + f0);
        uint2 hb = *(const uint2*)(hB + (size_t)u * 256 + f0);
        a0 += bf2f((unsigned short)(ha.x & 0xffff)) * du;
        a1 += bf2f((unsigned short)(ha.x >> 16)) * du;
        a2 += bf2f((unsigned short)(ha.y & 0xffff)) * du;
        a3 += bf2f((unsigned short)(ha.y >> 16)) * du;
        c0 += bf2f((unsigned short)(hb.x & 0xffff)) * du;
        c1 += bf2f((unsigned short)(hb.x >> 16)) * du;
        c2 += bf2f((unsigned short)(hb.y & 0xffff)) * du;
        c3 += bf2f((unsigned short)(hb.y >> 16)) * du;
    }
    float dv = dinv[v], dv2 = dv * dv;
    uint2 sa = *(const uint2*)(hA + (size_t)v * 256 + f0);
    uint2 sb = *(const uint2*)(hB + (size_t)v * 256 + f0);
    float r0 = dv * a0 + bf2f((unsigned short)(sa.x & 0xffff)) * dv2 + biasA[f0 + 0];
    float r1 = dv * a1 + bf2f((unsigned short)(sa.x >> 16)) * dv2 + biasA[f0 + 1];
    float r2 = dv * a2 + bf2f((unsigned short)(sa.y & 0xffff)) * dv2 + biasA[f0 + 2];
    float r3 = dv * a3 + bf2f((unsigned short)(sa.y >> 16)) * dv2 + biasA[f0 + 3];
    float t0 = dv * c0 + bf2f((unsigned short)(sb.x & 0xffff)) * dv2 + biasB[f0 + 0];
    float t1 = dv * c1 + bf2f((unsigned short)(sb.x >> 16)) * dv2 + biasB[f0 + 1];
    float t2 = dv * c2 + bf2f((unsigned short)(sb.y & 0xffff)) * dv2 + biasB[f0 + 2];
    float t3 = dv * c3 + bf2f((unsigned short)(sb.y >> 16)) * dv2 + biasB[f0 + 3];
    r0 = r0 > 0.f ? r0 : 0.01f * r0;  r1 = r1 > 0.f ? r1 : 0.01f * r1;
    r2 = r2 > 0.f ? r2 : 0.01f * r2;  r3 = r3 > 0.f ? r3 : 0.01f * r3;
    t0 = t0 > 0.f ? t0 : 0.01f * t0;  t1 = t1 > 0.f ? t1 : 0.01f * t1;
    t2 = t2 > 0.f ? t2 : 0.01f * t2;  t3 = t3 > 0.f ? t3 : 0.01f * t3;
    uint2 ov = make_uint2(((unsigned)f2bf(r1) << 16) | f2bf(r0), ((unsigned)f2bf(r3) << 16) | f2bf(r2));
    uint2 ow = make_uint2(((unsigned)f2bf(t1) << 16) | f2bf(t0), ((unsigned)f2bf(t3) << 16) | f2bf(t2));
    *(uint2*)(outA + (size_t)v * 768 + f0) = ov;
    *(uint2*)(outB + (size_t)v * 256 + f0) = ow;
}

// ---------------- single GCN aggregation (s22 path) ----------------
__global__ __launch_bounds__(256) void agg_kernel(const unsigned short* __restrict__ h,
                                                  const int* __restrict__ rowptr, const int* __restrict__ srcs,
                                                  const float* __restrict__ dinv, const float* __restrict__ bias,
                                                  unsigned short* __restrict__ out, int ldOut, int colOff,
                                                  int do_lrelu) {
    int wave = threadIdx.x >> 6, lane = threadIdx.x & 63;
    int v = blockIdx.x * 4 + wave;
    int f0 = lane * 4;
    float a0 = 0.f, a1 = 0.f, a2 = 0.f, a3 = 0.f;
    int s = rowptr[v], e = rowptr[v + 1];
    for (int i = s; i < e; i++) {
        int u = srcs[i] & (N_NODES - 1);
        float du = dinv[u];
        uint2 hv = *(const uint2*)(h + (size_t)u * 256 + f0);
        a0 += bf2f((unsigned short)(hv.x & 0xffff)) * du;
        a1 += bf2f((unsigned short)(hv.x >> 16)) * du;
        a2 += bf2f((unsigned short)(hv.y & 0xffff)) * du;
        a3 += bf2f((unsigned short)(hv.y >> 16)) * du;
    }
    float dv = dinv[v], dv2 = dv * dv;
    uint2 sv = *(const uint2*)(h + (size_t)v * 256 + f0);
    float r0 = dv * a0 + bf2f((unsigned short)(sv.x & 0xffff)) * dv2 + bias[f0 + 0];
    float r1 = dv * a1 + bf2f((unsigned short)(sv.x >> 16)) * dv2 + bias[f0 + 1];
    float r2 = dv * a2 + bf2f((unsigned short)(sv.y & 0xffff)) * dv2 + bias[f0 + 2];
    float r3 = dv * a3 + bf2f((unsigned short)(sv.y >> 16)) * dv2 + bias[f0 + 3];
    if (do_lrelu) {
        r0 = r0 > 0.f ? r0 : 0.01f * r0;
        r1 = r1 > 0.f ? r1 : 0.01f * r1;
        r2 = r2 > 0.f ? r2 : 0.01f * r2;
        r3 = r3 > 0.f ? r3 : 0.01f * r3;
    }
    uint2 ov = make_uint2(((unsigned)f2bf(r1) << 16) | f2bf(r0), ((unsigned)f2bf(r3) << 16) | f2bf(r2));
    *(uint2*)(out + (size_t)v * ldOut + colOff + f0) = ov;
}

// ---------------- score matvec ----------------
__global__ __launch_bounds__(256) void score_mv_kernel(const unsigned short* __restrict__ hf,
                                                       const void* __restrict__ wp, const void* __restrict__ wn,
                                                       float* __restrict__ svp, float* __restrict__ svn) {
    int wave = threadIdx.x >> 6, lane = threadIdx.x & 63;
    int v = blockIdx.x * 4 + wave;
    float sp = 0.f, sn = 0.f;
#pragma unroll
    for (int i = 0; i < 3; i++) {
        int k = i * 256 + lane * 4;
        uint2 hv = *(const uint2*)(hf + (size_t)v * 768 + k);
        float x0 = bf2f((unsigned short)(hv.x & 0xffff));
        float x1 = bf2f((unsigned short)(hv.x >> 16));
        float x2 = bf2f((unsigned short)(hv.y & 0xffff));
        float x3 = bf2f((unsigned short)(hv.y >> 16));
        sp += x0 * in_ld(wp, k) + x1 * in_ld(wp, k + 1) + x2 * in_ld(wp, k + 2) + x3 * in_ld(wp, k + 3);
        sn += x0 * in_ld(wn, k) + x1 * in_ld(wn, k + 1) + x2 * in_ld(wn, k + 2) + x3 * in_ld(wn, k + 3);
    }
    for (int off = 32; off >= 1; off >>= 1) {
        sp += __shfl_down(sp, off, 64);
        sn += __shfl_down(sn, off, 64);
    }
    if (lane == 0) { svp[v] = sp; svn[v] = sn; }
}

// ---------------- scalar GCN agg on scores + sigmoid (+ batch output fused) ----------------
__global__ __launch_bounds__(256) void score_agg_kernel(const float* __restrict__ svp, const float* __restrict__ svn,
                                                        const int* __restrict__ rowptr, const int* __restrict__ srcs,
                                                        const float* __restrict__ dinv,
                                                        const void* __restrict__ bp, const void* __restrict__ bn_,
                                                        float* __restrict__ scp, float* __restrict__ scn,
                                                        void* __restrict__ dout) {
    int v = blockIdx.x * 256 + threadIdx.x;
    float ap = 0.f, an = 0.f;
    int s = rowptr[v], e = rowptr[v + 1];
    for (int i = s; i < e; i++) {
        int u = srcs[i] & (N_NODES - 1);
        float du = dinv[u];
        ap += svp[u] * du;
        an += svn[u] * du;
    }
    float dv = dinv[v], dv2 = dv * dv;
    float zp = dv * ap + svp[v] * dv2 + in_ld(bp, 0);
    float zn = dv * an + svn[v] * dv2 + in_ld(bn_, 0);
    float pp = 1.0f / (1.0f + __expf(-zp));
    float pn = 1.0f / (1.0f + __expf(-zn));
    scp[v] = pp;
    scn[v] = pn;
    st_out(dout, 1920 + (size_t)v, pp);
    st_out(dout, 1920 + (size_t)N_NODES + v, pn);
    st_out(dout, 1920 + 2 * (size_t)N_NODES + v, (float)(v >> 9));   // batch output
}

// ---------------- top-k masks, pos+neg in one launch (grid 128) ----------------
__global__ __launch_bounds__(512) void topk2_kernel(const float* __restrict__ scp, const float* __restrict__ scn,
                                                    unsigned char* __restrict__ maskp,
                                                    unsigned char* __restrict__ maskn) {
    __shared__ float s[512];
    const float* sc = (blockIdx.x & 1) ? scn : scp;
    unsigned char* mask = (blockIdx.x & 1) ? maskn : maskp;
    int g = blockIdx.x >> 1, i = threadIdx.x;
    float my = sc[(size_t)g * 512 + i];
    s[i] = my;
    __syncthreads();
    int cnt = 0;
    for (int j = 0; j < 512; j++) {
        float o = s[j];
        cnt += (int)((o > my) || ((o == my) && (j < i)));
    }
    mask[(size_t)g * 512 + i] = (cnt < TOPK) ? 1 : 0;
}

// ---------------- fused dual-mask readout (skips rows masked out of both) ----------------
__global__ __launch_bounds__(256) void readout2_kernel(const unsigned short* __restrict__ xt,
                                                       const unsigned char* __restrict__ maskp,
                                                       const unsigned char* __restrict__ maskn,
                                                       float* __restrict__ eout) {
    int g = blockIdx.x;
    int c = blockIdx.y;
    int wv = threadIdx.x >> 6, lane = threadIdx.x & 63;
    int f = c * 64 + lane;
    __shared__ unsigned char mp[512], mn[512];
    __shared__ float red[4][64][4];
    for (int i = threadIdx.x; i < 512; i += 256) {
        mp[i] = maskp[(size_t)g * 512 + i];
        mn[i] = maskn[(size_t)g * 512 + i];
    }
    __syncthreads();
    float sp = 0.f, sn = 0.f, xp = -INFINITY, xn = -INFINITY;
    const unsigned short* base = xt + ((size_t)g * 512 + wv * 128) * 768 + f;
    for (int v = 0; v < 128; v++) {
        unsigned char bp = mp[wv * 128 + v], bn_ = mn[wv * 128 + v];
        if (!(bp | bn_)) continue;                 // wave-uniform skip
        float x = bf2f(base[(size_t)v * 768]);
        if (bp) { sp += x; xp = fmaxf(xp, x); }
        if (bn_) { sn += x; xn = fmaxf(xn, x); }
    }
    red[wv][lane][0] = sp; red[wv][lane][1] = xp;
    red[wv][lane][2] = sn; red[wv][lane][3] = xn;
    __syncthreads();
    if (wv == 0) {
#pragma unroll
        for (int w = 1; w < 4; w++) {
            sp += red[w][lane][0]; xp = fmaxf(xp, red[w][lane][1]);
            sn += red[w][lane][2]; xn = fmaxf(xn, red[w][lane][3]);
        }
        float* erp = eout + (size_t)g * 1536;
        float* ern = eout + (size_t)(64 + g) * 1536;
        erp[f] = sp * (1.0f / TOPK);
        erp[768 + f] = xp;
        ern[f] = sn * (1.0f / TOPK);
        ern[768 + f] = xn;
    }
}

// ---------------- MLP GEMM, k-split + n-split ----------------
__global__ __launch_bounds__(256) void mlp_gemm2_kernel(const float* __restrict__ in,
                                                        const float* __restrict__ W,
                                                        const float* __restrict__ b,
                                                        float* __restrict__ out, int K) {
    __shared__ float row[1536];
    __shared__ float red[4][64];
    int r = blockIdx.x, cg = blockIdx.y;
    int wv = threadIdx.x >> 6, lane = threadIdx.x & 63;
    int c = cg * 64 + lane;
    for (int k = threadIdx.x; k < K; k += 256) row[k] = in[(size_t)r * K + k];
    __syncthreads();
    int kpw = K >> 2;
    const float* wp = W + (size_t)(wv * kpw) * 256 + c;
    const float* rp = row + wv * kpw;
    float acc = 0.f;
#pragma unroll 4
    for (int k = 0; k < kpw; k++)
        acc += rp[k] * wp[(size_t)k * 256];
    red[wv][lane] = acc;
    __syncthreads();
    if (wv == 0) {
        float v = red[0][lane] + red[1][lane] + red[2][lane] + red[3][lane] + b[c];
        out[(size_t)r * 256 + c] = v;
    }
}

__global__ __launch_bounds__(64) void bn_kernel(const float* __restrict__ z, const void* __restrict__ gamma,
                                                const void* __restrict__ beta, const float* __restrict__ res,
                                                float* __restrict__ out) {
    int f = blockIdx.x & 255, g = blockIdx.x >> 8, r = threadIdx.x;
    size_t idx = (size_t)(g * 64 + r) * 256 + f;
    float x = z[idx];
    float s = x, sq = x * x;
    for (int off = 1; off < 64; off <<= 1) {
        s += __shfl_xor(s, off, 64);
        sq += __shfl_xor(sq, off, 64);
    }
    float m = s * (1.0f / 64.0f);
    float var = sq * (1.0f / 64.0f) - m * m;
    float y = (x - m) * rsqrtf(var + BN_EPS) * in_ld(gamma, f) + in_ld(beta, f);
    y = fmaxf(y, 0.0f);
    if (res) y += res[idx];
    out[idx] = y;
}

__global__ __launch_bounds__(64) void logits_kernel(const float* __restrict__ act, const void* __restrict__ w4,
                                                    const void* __restrict__ b4, float* __restrict__ lg) {
    int idx = blockIdx.x * 64 + threadIdx.x;
    if (idx >= 128 * NCLS) return;
    int r = idx / NCLS, c = idx % NCLS;
    float acc = in_ld(b4, c);
    for (int k = 0; k < 256; k++) acc += act[(size_t)r * 256 + k] * in_ld(w4, (size_t)k * NCLS + c);
    lg[idx] = acc;
}

__global__ __launch_bounds__(64) void softmax_kernel(const float* __restrict__ lg, void* __restrict__ dout) {
    int r = blockIdx.x * 64 + threadIdx.x;
    if (r >= 128) return;
    float l[NCLS];
    float mx = -1e30f;
    for (int c = 0; c < NCLS; c++) { l[c] = lg[(size_t)r * NCLS + c]; mx = fmaxf(mx, l[c]); }
    float sum = 0.f;
    float ex[NCLS];
    for (int c = 0; c < NCLS; c++) { ex[c] = __expf(l[c] - mx); sum += ex[c]; }
    float inv = 1.0f / sum;
    int g = r >> 6, rr = r & 63;
    if (g == 0) {
        for (int c = 0; c < NCLS; c++) st_out(dout, (size_t)rr * NCLS + c, l[c]);
        for (int c = 0; c < NCLS; c++) st_out(dout, 640 + (size_t)rr * NCLS + c, ex[c] * inv);
    } else {
        for (int c = 0; c < NCLS; c++) st_out(dout, 1280 + (size_t)rr * NCLS + c, ex[c] * inv);
    }
}

// ---------------- host launcher ----------------
extern "C" void kernel_launch(void* const* d_in, const int* in_sizes, int n_in,
                              void* d_out, int out_size, void* d_ws, size_t ws_size,
                              hipStream_t stream) {
    (void)in_sizes; (void)n_in; (void)out_size; (void)ws_size;

    const float* x = (const float*)d_in[0];
    const int* eb = (const int*)d_in[1];
    const float* w_s1 = (const float*)d_in[3];
    const float* b_s1 = (const float*)d_in[4];
    const float* w_s21 = (const float*)d_in[5];
    const float* b_s21 = (const float*)d_in[6];
    const float* w_s22 = (const float*)d_in[7];
    const float* b_s22 = (const float*)d_in[8];
    const float* w_raw = (const float*)d_in[9];
    const float* b_raw = (const float*)d_in[10];
    const void* w_pos = d_in[11];
    const void* b_pos = d_in[12];
    const void* w_neg = d_in[13];
    const void* b_neg = d_in[14];
    const float* w_pool = (const float*)d_in[15];
    const float* b_pool = (const float*)d_in[16];
    const float* w1 = (const float*)d_in[17];  const float* b1 = (const float*)d_in[18];
    const void* g1 = d_in[19];  const void* be1 = d_in[20];
    const float* w2 = (const float*)d_in[21];  const float* b2 = (const float*)d_in[22];
    const void* g2 = d_in[23];  const void* be2 = d_in[24];
    const float* w3 = (const float*)d_in[25];  const float* b3 = (const float*)d_in[26];
    const void* g3 = d_in[27];  const void* be3 = d_in[28];
    const void* w4 = d_in[29];  const void* b4 = d_in[30];

    char* ws = (char*)d_ws;
    size_t off = 0;
    auto alloc = [&](size_t b) -> void* {
        void* p = ws + off;
        off += (b + 255) & ~(size_t)255;
        return p;
    };
    int* flag = (int*)alloc(256);
    int* deg = (int*)alloc((size_t)N_NODES * 4);
    float* dinv = (float*)alloc((size_t)N_NODES * 4);
    int* rowptr = (int*)alloc((size_t)(N_NODES + 1) * 4);
    int* cursor = (int*)alloc((size_t)N_NODES * 4);
    int* srcs = (int*)alloc((size_t)NEDGE * 4);
    unsigned short* xbf = (unsigned short*)alloc((size_t)N_NODES * 256 * 2);
    unsigned short* wcat = (unsigned short*)alloc((size_t)768 * 256 * 2);
    unsigned short* wb_s22 = (unsigned short*)alloc((size_t)256 * 256 * 2);
    unsigned short* wb_pool = (unsigned short*)alloc((size_t)768 * 768 * 2);
    unsigned short* tA = (unsigned short*)alloc((size_t)N_NODES * 256 * 2);
    unsigned short* tB = (unsigned short*)alloc((size_t)N_NODES * 256 * 2);
    unsigned short* tmpB = (unsigned short*)alloc((size_t)N_NODES * 256 * 2);
    unsigned short* hfin = (unsigned short*)alloc((size_t)N_NODES * 768 * 2);
    unsigned short* xt = (unsigned short*)alloc((size_t)N_NODES * 768 * 2);
    float* svp = (float*)alloc((size_t)N_NODES * 4);
    float* svn = (float*)alloc((size_t)N_NODES * 4);
    float* scp = (float*)alloc((size_t)N_NODES * 4);
    float* scn = (float*)alloc((size_t)N_NODES * 4);
    unsigned char* maskp = (unsigned char*)alloc(N_NODES);
    unsigned char* maskn = (unsigned char*)alloc(N_NODES);
    float* ebuf = (float*)alloc((size_t)128 * 1536 * 4);
    float* zb = (float*)alloc((size_t)128 * 256 * 4);
    float* act1 = (float*)alloc((size_t)128 * 256 * 4);
    float* act2 = (float*)alloc((size_t)128 * 256 * 4);
    float* act3 = (float*)alloc((size_t)128 * 256 * 4);
    float* lg = (float*)alloc((size_t)128 * NCLS * 4);

    hipMemsetAsync(flag, 0, 256, stream);
    hipMemsetAsync(deg, 0, (size_t)N_NODES * 4, stream);
    detect_kernel<<<NEDGE / 256, 256, 0, stream>>>(eb, flag);
    hist_kernel<<<NEDGE / 256, 256, 0, stream>>>(eb, flag, deg);
    scan_kernel<<<1, 1024, 0, stream>>>(deg, rowptr, cursor, dinv);
    scatter_kernel<<<NEDGE / 256, 256, 0, stream>>>(eb, flag, cursor, srcs);

    // conversions
    cvt_kernel<<<(N_NODES * 256 + 255) / 256, 256, 0, stream>>>(x, xbf, N_NODES * 256);
    cvt_t_all_kernel<<<832, 256, 0, stream>>>(w_s1, w_s21, w_raw, w_s22, w_pool, wcat, wb_s22, wb_pool);

    dim3 gG3(768 / 128, N_NODES / 128);  // (6, 256)
    dim3 gA(256 / 128, N_NODES / 128);   // (2, 256)
    dim3 gP(768 / 128, N_NODES / 128);   // (6, 256)

    // merged s1/s21/raw GEMM (xbf fetched once)
    gemm3_kernel<<<gG3, 256, 0, stream>>>(xbf, wcat, b_raw, tA, tB, hfin);
    // dual aggregation (s1 -> hfin[0:256], s21 -> tmpB) sharing the CSR walk
    agg2_kernel<<<N_NODES / 4, 256, 0, stream>>>(tA, tB, rowptr, srcs, dinv, b_s1, b_s21, hfin, tmpB);
    gemm_kernel<256><<<gA, 256, 0, stream>>>(tmpB, wb_s22, nullptr, tA, 256, 0, 0);
    agg_kernel<<<N_NODES / 4, 256, 0, stream>>>(tA, rowptr, srcs, dinv, b_s22, hfin, 768, 256, 1);
    // xt = sigmoid(h_final @ w_pool + b_pool)
    gemm_kernel<768><<<gP, 256, 0, stream>>>(hfin, wb_pool, b_pool, xt, 768, 0, 1);
    // scores
    score_mv_kernel<<<N_NODES / 4, 256, 0, stream>>>(hfin, w_pos, w_neg, svp, svn);
    score_agg_kernel<<<N_NODES / 256, 256, 0, stream>>>(svp, svn, rowptr, srcs, dinv, b_pos, b_neg, scp, scn, d_out);
    // top-k (both polarities) + fused readout
    topk2_kernel<<<2 * NGRAPH, 512, 0, stream>>>(scp, scn, maskp, maskn);
    {
        dim3 gR(NGRAPH, FDIM / 64);
        readout2_kernel<<<gR, 256, 0, stream>>>(xt, maskp, maskn, ebuf);
    }
    // MLP
    {
        dim3 gM(128, 4);
        mlp_gemm2_kernel<<<gM, 256, 0, stream>>>(ebuf, w1, b1, zb, 1536);
        bn_kernel<<<512, 64, 0, stream>>>(zb, g1, be1, nullptr, act1);
        mlp_gemm2_kernel<<<gM, 256, 0, stream>>>(act1, w2, b2, zb, 256);
        bn_kernel<<<512, 64, 0, stream>>>(zb, g2, be2, act1, act2);
        mlp_gemm2_kernel<<<gM, 256, 0, stream>>>(act2, w3, b3, zb, 256);
        bn_kernel<<<512, 64, 0, stream>>>(zb, g3, be3, act2, act3);
    }
    logits_kernel<<<(128 * NCLS + 63) / 64, 64, 0, stream>>>(act3, w4, b4, lg);
    softmax_kernel<<<2, 64, 0, stream>>>(lg, d_out);
}

// Round 8
// 601.820 us; speedup vs baseline: 1.8141x; 1.0028x over previous
//
#include <hip/hip_runtime.h>
#include <hip/hip_bf16.h>

// ---- problem constants ----
#define N_NODES 32768
#define NGRAPH  64
#define NPG     512
#define TOPK    256
#define HID     256
#define FDIM    768
#define NEDGE   262144
#define NCLS    10
#define BN_EPS  1e-5f

#define IN_BF16 0
#define OUT_BF16 0

typedef __attribute__((ext_vector_type(8))) short short8;
typedef __attribute__((ext_vector_type(4))) float f32x4;

__device__ __forceinline__ float bf2f(unsigned short u) {
    return __uint_as_float(((unsigned)u) << 16);
}
__device__ __forceinline__ unsigned short f2bf(float f) {
    unsigned x = __float_as_uint(f);
    unsigned r = (x + 0x7fffu + ((x >> 16) & 1u)) >> 16;
    return (unsigned short)r;
}
__device__ __forceinline__ float in_ld(const void* p, size_t i) {
#if IN_BF16
    return bf2f(((const unsigned short*)p)[i]);
#else
    return ((const float*)p)[i];
#endif
}
__device__ __forceinline__ void st_out(void* o, size_t i, float v) {
#if OUT_BF16
    ((unsigned short*)o)[i] = f2bf(v);
#else
    ((float*)o)[i] = v;
#endif
}

__device__ __forceinline__ void async_cp16(const unsigned short* g, unsigned short* l) {
    __builtin_amdgcn_global_load_lds(
        (const __attribute__((address_space(1))) unsigned int*)g,
        (__attribute__((address_space(3))) unsigned int*)l, 16, 0, 0);
}

// XCD-aware tile swizzle: all nx N-tiles of an M-slab map to one XCD (L%8).
__device__ __forceinline__ void tile_swizzle(int& bm, int& bn) {
    int nx = gridDim.x;
    int L = blockIdx.y * nx + blockIdx.x;
    int xcd = L & 7;
    int j = L >> 3;
    bm = ((j / nx) * 8 + xcd) * 128;
    bn = (j % nx) * 128;
}

// ---------------- fp32 -> bf16 conversion ----------------
__global__ __launch_bounds__(256) void cvt_kernel(const float* __restrict__ in,
                                                  unsigned short* __restrict__ out, int n) {
    int i = blockIdx.x * 256 + threadIdx.x;
    if (i < n) out[i] = f2bf(in[i]);
}

// all 5 weight transposes (fp32 [K][N] -> bf16 [N][K]) in ONE launch.
__global__ __launch_bounds__(256) void cvt_t_all_kernel(const float* __restrict__ w_s1,
                                                        const float* __restrict__ w_s21,
                                                        const float* __restrict__ w_raw,
                                                        const float* __restrict__ w_s22,
                                                        const float* __restrict__ w_pool,
                                                        unsigned short* __restrict__ wcat,
                                                        unsigned short* __restrict__ wb_s22,
                                                        unsigned short* __restrict__ wb_pool) {
    __shared__ unsigned short tile[32][33];
    int id = blockIdx.x;
    const float* src;
    unsigned short* dst;
    int K, N, t;
    if (id < 64)       { src = w_s1;  dst = wcat;                       K = 256; N = 256; t = id; }
    else if (id < 128) { src = w_s21; dst = wcat + (size_t)256 * 256;   K = 256; N = 256; t = id - 64; }
    else if (id < 192) { src = w_raw; dst = wcat + (size_t)512 * 256;   K = 256; N = 256; t = id - 128; }
    else if (id < 256) { src = w_s22; dst = wb_s22;                     K = 256; N = 256; t = id - 192; }
    else               { src = w_pool; dst = wb_pool;                   K = 768; N = 768; t = id - 256; }
    int tiles_x = K >> 5;
    int bk = (t % tiles_x) * 32, bn = (t / tiles_x) * 32;
    int tx = threadIdx.x & 31, ty = threadIdx.x >> 5;
#pragma unroll
    for (int i = 0; i < 32; i += 8)
        tile[ty + i][tx] = f2bf(src[(size_t)(bk + ty + i) * N + bn + tx]);
    __syncthreads();
#pragma unroll
    for (int i = 0; i < 32; i += 8)
        dst[(size_t)(bn + ty + i) * K + bk + tx] = tile[tx][ty + i];
}

// ---------------- edge dtype detection + CSR build ----------------
__global__ __launch_bounds__(256) void detect_kernel(const int* __restrict__ eb, int* __restrict__ flag) {
    int i = blockIdx.x * 256 + threadIdx.x;
    int v = eb[2 * (size_t)i + 1];
    unsigned long long b = __ballot(v != 0);
    if ((threadIdx.x & 63) == 0 && b)
        atomicAdd(flag, (int)__popcll(b));
}

__global__ __launch_bounds__(256) void hist_kernel(const int* __restrict__ eb, const int* __restrict__ flag,
                                                   int* __restrict__ deg) {
    int e = blockIdx.x * 256 + threadIdx.x;
    int st = (*flag == 0) ? 2 : 1;
    unsigned d = ((const unsigned*)eb)[(size_t)(NEDGE + e) * st] & (N_NODES - 1);
    atomicAdd(&deg[d], 1);
}

// scan + dinv fused
__global__ __launch_bounds__(1024) void scan_kernel(const int* __restrict__ cnt, int* __restrict__ rowptr,
                                                    int* __restrict__ cursor, float* __restrict__ dinv) {
    __shared__ int part[1024];
    int t = threadIdx.x;
    int base = t * 32;
    int loc[32];
    int s = 0;
#pragma unroll
    for (int i = 0; i < 32; i++) { loc[i] = cnt[base + i]; s += loc[i]; }
    part[t] = s;
    __syncthreads();
    for (int off = 1; off < 1024; off <<= 1) {
        int v = (t >= off) ? part[t - off] : 0;
        __syncthreads();
        part[t] += v;
        __syncthreads();
    }
    int run = (t == 0) ? 0 : part[t - 1];
#pragma unroll
    for (int i = 0; i < 32; i++) {
        rowptr[base + i] = run;
        cursor[base + i] = run;
        dinv[base + i] = rsqrtf((float)loc[i] + 1.0f);
        run += loc[i];
    }
    if (t == 1023) rowptr[N_NODES] = run;
}

__global__ __launch_bounds__(256) void scatter_kernel(const int* __restrict__ eb, const int* __restrict__ flag,
                                                      int* __restrict__ cursor, int* __restrict__ srcs) {
    int e = blockIdx.x * 256 + threadIdx.x;
    int st = (*flag == 0) ? 2 : 1;
    unsigned s = ((const unsigned*)eb)[(size_t)e * st] & (N_NODES - 1);
    unsigned d = ((const unsigned*)eb)[(size_t)(NEDGE + e) * st] & (N_NODES - 1);
    int p = atomicAdd(&cursor[d], 1);
    srcs[p] = (int)s;
}

// ---------------- GEMM core (128x128 tile, BK=64), runtime K ----------------
// Staging algebra: r = t*32 + wave*8 + srow  =>  r&7 == srow, so the XOR chunk
// swizzle gc = schunk ^ srow is loop/t-invariant. Per-iter staging cost is
// 8 global_load_lds + pointer adds only (no mul/xor in the loop).
#define GEMM_CORE(K_)                                                           \
    __shared__ unsigned short As[128 * 64];                                     \
    __shared__ unsigned short Bs[128 * 64];                                     \
    const int tid = threadIdx.x;                                                \
    const int wave = tid >> 6;                                                  \
    const int lane = tid & 63;                                                  \
    int bm, bn;                                                                 \
    tile_swizzle(bm, bn);                                                       \
    const int wm = (wave >> 1) * 64;                                            \
    const int wn = (wave & 1) * 64;                                             \
    const int l15 = lane & 15;                                                  \
    const int q = lane >> 4;                                                    \
    f32x4 acc[4][4] = {};                                                       \
    const int srow = lane >> 3;                                                 \
    const int schunk = lane & 7;                                                \
    const int gc = schunk ^ srow;                                               \
    const unsigned short* gaA = A + (size_t)(bm + wave * 8 + srow) * (K_) + gc * 8;  \
    const unsigned short* gbB = WT + (size_t)(bn + wave * 8 + srow) * (K_) + gc * 8; \
    const size_t K32 = (size_t)(K_) * 32;                                       \
    unsigned short* const la0 = &As[(wave * 8) * 64];                           \
    unsigned short* const lb0 = &Bs[(wave * 8) * 64];                           \
    for (int k0 = 0; k0 < (K_); k0 += 64) {                                     \
        __syncthreads();                                                        \
        _Pragma("unroll")                                                       \
        for (int t = 0; t < 4; t++) {                                           \
            async_cp16(gaA + t * K32 + k0, la0 + t * 32 * 64);                  \
            async_cp16(gbB + t * K32 + k0, lb0 + t * 32 * 64);                  \
        }                                                                       \
        __syncthreads();                                                        \
        _Pragma("unroll")                                                       \
        for (int h = 0; h < 2; h++) {                                           \
            short8 af[4], bfv[4];                                               \
            int p = (h * 4 + q) ^ (l15 & 7);                                    \
            _Pragma("unroll")                                                   \
            for (int t = 0; t < 4; t++) {                                       \
                int m = wm + t * 16 + l15;                                      \
                int n = wn + t * 16 + l15;                                      \
                af[t] = *(const short8*)&As[m * 64 + p * 8];                    \
                bfv[t] = *(const short8*)&Bs[n * 64 + p * 8];                   \
            }                                                                   \
            _Pragma("unroll")                                                   \
            for (int tm = 0; tm < 4; tm++)                                      \
                _Pragma("unroll")                                               \
                for (int tn = 0; tn < 4; tn++)                                  \
                    acc[tm][tn] = __builtin_amdgcn_mfma_f32_16x16x32_bf16(af[tm], bfv[tn], acc[tm][tn], 0, 0, 0); \
        }                                                                       \
    }

// generic GEMM, runtime K (no full unroll -> keeps VGPR/occupancy)
__global__ __launch_bounds__(256) void gemm_kernel(const unsigned short* __restrict__ A,
                                                   const unsigned short* __restrict__ WT,
                                                   const float* __restrict__ bias,
                                                   unsigned short* __restrict__ C,
                                                   int K, int ldC, int colOff, int epi) {
    GEMM_CORE(K)
#pragma unroll
    for (int tm = 0; tm < 4; tm++) {
        int row = bm + wm + tm * 16 + q * 4;
#pragma unroll
        for (int tn = 0; tn < 4; tn++) {
            int col = bn + wn + tn * 16 + l15;
            float bv = bias ? bias[col] : 0.0f;
#pragma unroll
            for (int r = 0; r < 4; r++) {
                float v = acc[tm][tn][r] + bv;
                if (epi == 1) v = 1.0f / (1.0f + __expf(-v));
                C[(size_t)(row + r) * ldC + colOff + col] = f2bf(v);
            }
        }
    }
}

// merged 3-branch GEMM from xbf
__global__ __launch_bounds__(256) void gemm3_kernel(const unsigned short* __restrict__ A,
                                                    const unsigned short* __restrict__ WT,
                                                    const float* __restrict__ b_raw,
                                                    unsigned short* __restrict__ tA,
                                                    unsigned short* __restrict__ tB,
                                                    unsigned short* __restrict__ hfin) {
    GEMM_CORE(256)
#pragma unroll
    for (int tm = 0; tm < 4; tm++) {
        int row = bm + wm + tm * 16 + q * 4;
#pragma unroll
        for (int tn = 0; tn < 4; tn++) {
            int col = bn + wn + tn * 16 + l15;      // 16-aligned group: branch wave-uniform
            if (col < 256) {
#pragma unroll
                for (int r = 0; r < 4; r++)
                    tA[(size_t)(row + r) * 256 + col] = f2bf(acc[tm][tn][r]);
            } else if (col < 512) {
#pragma unroll
                for (int r = 0; r < 4; r++)
                    tB[(size_t)(row + r) * 256 + (col - 256)] = f2bf(acc[tm][tn][r]);
            } else {
                float bv = b_raw[col - 512];
#pragma unroll
                for (int r = 0; r < 4; r++)
                    hfin[(size_t)(row + r) * 768 + col] = f2bf(acc[tm][tn][r] + bv);
            }
        }
    }
}

// ---------------- dual GCN aggregation: s1 and s21 share the CSR walk ----------------
__global__ __launch_bounds__(256) void agg2_kernel(const unsigned short* __restrict__ hA,
                                                   const unsigned short* __restrict__ hB,
                                                   const int* __restrict__ rowptr, const int* __restrict__ srcs,
                                                   const float* __restrict__ dinv,
                                                   const float* __restrict__ biasA, const float* __restrict__ biasB,
                                                   unsigned short* __restrict__ outA,
                                                   unsigned short* __restrict__ outB) {
    int wave = threadIdx.x >> 6, lane = threadIdx.x & 63;
    int v = blockIdx.x * 4 + wave;
    int f0 = lane * 4;
    float a0 = 0.f, a1 = 0.f, a2 = 0.f, a3 = 0.f;
    float c0 = 0.f, c1 = 0.f, c2 = 0.f, c3 = 0.f;
    int s = rowptr[v], e = rowptr[v + 1];
    for (int i = s; i < e; i++) {
        int u = srcs[i] & (N_NODES - 1);
        float du = dinv[u];
        uint2 ha = *(const uint2*)(hA + (size_t)u * 256 + f0);
        uint2 hb = *(const uint2*)(hB + (size_t)u * 256 + f0);
        a0 += bf2f((unsigned short)(ha.x & 0xffff)) * du;
        a1 += bf2f((unsigned short)(ha.x >> 16)) * du;
        a2 += bf2f((unsigned short)(ha.y & 0xffff)) * du;
        a3 += bf2f((unsigned short)(ha.y >> 16)) * du;
        c0 += bf2f((unsigned short)(hb.x & 0xffff)) * du;
        c1 += bf2f((unsigned short)(hb.x >> 16)) * du;
        c2 += bf2f((unsigned short)(hb.y & 0xffff)) * du;
        c3 += bf2f((unsigned short)(hb.y >> 16)) * du;
    }
    float dv = dinv[v], dv2 = dv * dv;
    uint2 sa = *(const uint2*)(hA + (size_t)v * 256 + f0);
    uint2 sb = *(const uint2*)(hB + (size_t)v * 256 + f0);
    float r0 = dv * a0 + bf2f((unsigned short)(sa.x & 0xffff)) * dv2 + biasA[f0 + 0];
    float r1 = dv * a1 + bf2f((unsigned short)(sa.x >> 16)) * dv2 + biasA[f0 + 1];
    float r2 = dv * a2 + bf2f((unsigned short)(sa.y & 0xffff)) * dv2 + biasA[f0 + 2];
    float r3 = dv * a3 + bf2f((unsigned short)(sa.y >> 16)) * dv2 + biasA[f0 + 3];
    float t0 = dv * c0 + bf2f((unsigned short)(sb.x & 0xffff)) * dv2 + biasB[f0 + 0];
    float t1 = dv * c1 + bf2f((unsigned short)(sb.x >> 16)) * dv2 + biasB[f0 + 1];
    float t2 = dv * c2 + bf2f((unsigned short)(sb.y & 0xffff)) * dv2 + biasB[f0 + 2];
    float t3 = dv * c3 + bf2f((unsigned short)(sb.y >> 16)) * dv2 + biasB[f0 + 3];
    r0 = r0 > 0.f ? r0 : 0.01f * r0;  r1 = r1 > 0.f ? r1 : 0.01f * r1;
    r2 = r2 > 0.f ? r2 : 0.01f * r2;  r3 = r3 > 0.f ? r3 : 0.01f * r3;
    t0 = t0 > 0.f ? t0 : 0.01f * t0;  t1 = t1 > 0.f ? t1 : 0.01f * t1;
    t2 = t2 > 0.f ? t2 : 0.01f * t2;  t3 = t3 > 0.f ? t3 : 0.01f * t3;
    uint2 ov = make_uint2(((unsigned)f2bf(r1) << 16) | f2bf(r0), ((unsigned)f2bf(r3) << 16) | f2bf(r2));
    uint2 ow = make_uint2(((unsigned)f2bf(t1) << 16) | f2bf(t0), ((unsigned)f2bf(t3) << 16) | f2bf(t2));
    *(uint2*)(outA + (size_t)v * 768 + f0) = ov;
    *(uint2*)(outB + (size_t)v * 256 + f0) = ow;
}

// ---------------- single GCN aggregation (s22 path) ----------------
__global__ __launch_bounds__(256) void agg_kernel(const unsigned short* __restrict__ h,
                                                  const int* __restrict__ rowptr, const int* __restrict__ srcs,
                                                  const float* __restrict__ dinv, const float* __restrict__ bias,
                                                  unsigned short* __restrict__ out, int ldOut, int colOff,
                                                  int do_lrelu) {
    int wave = threadIdx.x >> 6, lane = threadIdx.x & 63;
    int v = blockIdx.x * 4 + wave;
    int f0 = lane * 4;
    float a0 = 0.f, a1 = 0.f, a2 = 0.f, a3 = 0.f;
    int s = rowptr[v], e = rowptr[v + 1];
    for (int i = s; i < e; i++) {
        int u = srcs[i] & (N_NODES - 1);
        float du = dinv[u];
        uint2 hv = *(const uint2*)(h + (size_t)u * 256 + f0);
        a0 += bf2f((unsigned short)(hv.x & 0xffff)) * du;
        a1 += bf2f((unsigned short)(hv.x >> 16)) * du;
        a2 += bf2f((unsigned short)(hv.y & 0xffff)) * du;
        a3 += bf2f((unsigned short)(hv.y >> 16)) * du;
    }
    float dv = dinv[v], dv2 = dv * dv;
    uint2 sv = *(const uint2*)(h + (size_t)v * 256 + f0);
    float r0 = dv * a0 + bf2f((unsigned short)(sv.x & 0xffff)) * dv2 + bias[f0 + 0];
    float r1 = dv * a1 + bf2f((unsigned short)(sv.x >> 16)) * dv2 + bias[f0 + 1];
    float r2 = dv * a2 + bf2f((unsigned short)(sv.y & 0xffff)) * dv2 + bias[f0 + 2];
    float r3 = dv * a3 + bf2f((unsigned short)(sv.y >> 16)) * dv2 + bias[f0 + 3];
    if (do_lrelu) {
        r0 = r0 > 0.f ? r0 : 0.01f * r0;
        r1 = r1 > 0.f ? r1 : 0.01f * r1;
        r2 = r2 > 0.f ? r2 : 0.01f * r2;
        r3 = r3 > 0.f ? r3 : 0.01f * r3;
    }
    uint2 ov = make_uint2(((unsigned)f2bf(r1) << 16) | f2bf(r0), ((unsigned)f2bf(r3) << 16) | f2bf(r2));
    *(uint2*)(out + (size_t)v * ldOut + colOff + f0) = ov;
}

// ---------------- score matvec ----------------
__global__ __launch_bounds__(256) void score_mv_kernel(const unsigned short* __restrict__ hf,
                                                       const void* __restrict__ wp, const void* __restrict__ wn,
                                                       float* __restrict__ svp, float* __restrict__ svn) {
    int wave = threadIdx.x >> 6, lane = threadIdx.x & 63;
    int v = blockIdx.x * 4 + wave;
    float sp = 0.f, sn = 0.f;
#pragma unroll
    for (int i = 0; i < 3; i++) {
        int k = i * 256 + lane * 4;
        uint2 hv = *(const uint2*)(hf + (size_t)v * 768 + k);
        float x0 = bf2f((unsigned short)(hv.x & 0xffff));
        float x1 = bf2f((unsigned short)(hv.x >> 16));
        float x2 = bf2f((unsigned short)(hv.y & 0xffff));
        float x3 = bf2f((unsigned short)(hv.y >> 16));
        sp += x0 * in_ld(wp, k) + x1 * in_ld(wp, k + 1) + x2 * in_ld(wp, k + 2) + x3 * in_ld(wp, k + 3);
        sn += x0 * in_ld(wn, k) + x1 * in_ld(wn, k + 1) + x2 * in_ld(wn, k + 2) + x3 * in_ld(wn, k + 3);
    }
    for (int off = 32; off >= 1; off >>= 1) {
        sp += __shfl_down(sp, off, 64);
        sn += __shfl_down(sn, off, 64);
    }
    if (lane == 0) { svp[v] = sp; svn[v] = sn; }
}

// ---------------- scalar GCN agg on scores + sigmoid (+ batch output fused) ----------------
__global__ __launch_bounds__(256) void score_agg_kernel(const float* __restrict__ svp, const float* __restrict__ svn,
                                                        const int* __restrict__ rowptr, const int* __restrict__ srcs,
                                                        const float* __restrict__ dinv,
                                                        const void* __restrict__ bp, const void* __restrict__ bn_,
                                                        float* __restrict__ scp, float* __restrict__ scn,
                                                        void* __restrict__ dout) {
    int v = blockIdx.x * 256 + threadIdx.x;
    float ap = 0.f, an = 0.f;
    int s = rowptr[v], e = rowptr[v + 1];
    for (int i = s; i < e; i++) {
        int u = srcs[i] & (N_NODES - 1);
        float du = dinv[u];
        ap += svp[u] * du;
        an += svn[u] * du;
    }
    float dv = dinv[v], dv2 = dv * dv;
    float zp = dv * ap + svp[v] * dv2 + in_ld(bp, 0);
    float zn = dv * an + svn[v] * dv2 + in_ld(bn_, 0);
    float pp = 1.0f / (1.0f + __expf(-zp));
    float pn = 1.0f / (1.0f + __expf(-zn));
    scp[v] = pp;
    scn[v] = pn;
    st_out(dout, 1920 + (size_t)v, pp);
    st_out(dout, 1920 + (size_t)N_NODES + v, pn);
    st_out(dout, 1920 + 2 * (size_t)N_NODES + v, (float)(v >> 9));
}

// ---------------- top-k masks, pos+neg in one launch ----------------
__global__ __launch_bounds__(512) void topk2_kernel(const float* __restrict__ scp, const float* __restrict__ scn,
                                                    unsigned char* __restrict__ maskp,
                                                    unsigned char* __restrict__ maskn) {
    __shared__ float s[512];
    const float* sc = (blockIdx.x & 1) ? scn : scp;
    unsigned char* mask = (blockIdx.x & 1) ? maskn : maskp;
    int g = blockIdx.x >> 1, i = threadIdx.x;
    float my = sc[(size_t)g * 512 + i];
    s[i] = my;
    __syncthreads();
    int cnt = 0;
    for (int j = 0; j < 512; j++) {
        float o = s[j];
        cnt += (int)((o > my) || ((o == my) && (j < i)));
    }
    mask[(size_t)g * 512 + i] = (cnt < TOPK) ? 1 : 0;
}

// ---------------- fused dual-mask readout ----------------
__global__ __launch_bounds__(256) void readout2_kernel(const unsigned short* __restrict__ xt,
                                                       const unsigned char* __restrict__ maskp,
                                                       const unsigned char* __restrict__ maskn,
                                                       float* __restrict__ eout) {
    int g = blockIdx.x;
    int c = blockIdx.y;
    int wv = threadIdx.x >> 6, lane = threadIdx.x & 63;
    int f = c * 64 + lane;
    __shared__ unsigned char mp[512], mn[512];
    __shared__ float red[4][64][4];
    for (int i = threadIdx.x; i < 512; i += 256) {
        mp[i] = maskp[(size_t)g * 512 + i];
        mn[i] = maskn[(size_t)g * 512 + i];
    }
    __syncthreads();
    float sp = 0.f, sn = 0.f, xp = -INFINITY, xn = -INFINITY;
    const unsigned short* base = xt + ((size_t)g * 512 + wv * 128) * 768 + f;
    for (int v = 0; v < 128; v++) {
        unsigned char bp = mp[wv * 128 + v], bn_ = mn[wv * 128 + v];
        if (!(bp | bn_)) continue;                 // wave-uniform skip
        float x = bf2f(base[(size_t)v * 768]);
        if (bp) { sp += x; xp = fmaxf(xp, x); }
        if (bn_) { sn += x; xn = fmaxf(xn, x); }
    }
    red[wv][lane][0] = sp; red[wv][lane][1] = xp;
    red[wv][lane][2] = sn; red[wv][lane][3] = xn;
    __syncthreads();
    if (wv == 0) {
#pragma unroll
        for (int w = 1; w < 4; w++) {
            sp += red[w][lane][0]; xp = fmaxf(xp, red[w][lane][1]);
            sn += red[w][lane][2]; xn = fmaxf(xn, red[w][lane][3]);
        }
        float* erp = eout + (size_t)g * 1536;
        float* ern = eout + (size_t)(64 + g) * 1536;
        erp[f] = sp * (1.0f / TOPK);
        erp[768 + f] = xp;
        ern[f] = sn * (1.0f / TOPK);
        ern[768 + f] = xn;
    }
}

// ---------------- MLP GEMM, k-split + n-split ----------------
__global__ __launch_bounds__(256) void mlp_gemm2_kernel(const float* __restrict__ in,
                                                        const float* __restrict__ W,
                                                        const float* __restrict__ b,
                                                        float* __restrict__ out, int K) {
    __shared__ float row[1536];
    __shared__ float red[4][64];
    int r = blockIdx.x, cg = blockIdx.y;
    int wv = threadIdx.x >> 6, lane = threadIdx.x & 63;
    int c = cg * 64 + lane;
    for (int k = threadIdx.x; k < K; k += 256) row[k] = in[(size_t)r * K + k];
    __syncthreads();
    int kpw = K >> 2;
    const float* wp = W + (size_t)(wv * kpw) * 256 + c;
    const float* rp = row + wv * kpw;
    float acc = 0.f;
#pragma unroll 4
    for (int k = 0; k < kpw; k++)
        acc += rp[k] * wp[(size_t)k * 256];
    red[wv][lane] = acc;
    __syncthreads();
    if (wv == 0) {
        float v = red[0][lane] + red[1][lane] + red[2][lane] + red[3][lane] + b[c];
        out[(size_t)r * 256 + c] = v;
    }
}

__global__ __launch_bounds__(64) void bn_kernel(const float* __restrict__ z, const void* __restrict__ gamma,
                                                const void* __restrict__ beta, const float* __restrict__ res,
                                                float* __restrict__ out) {
    int f = blockIdx.x & 255, g = blockIdx.x >> 8, r = threadIdx.x;
    size_t idx = (size_t)(g * 64 + r) * 256 + f;
    float x = z[idx];
    float s = x, sq = x * x;
    for (int off = 1; off < 64; off <<= 1) {
        s += __shfl_xor(s, off, 64);
        sq += __shfl_xor(sq, off, 64);
    }
    float m = s * (1.0f / 64.0f);
    float var = sq * (1.0f / 64.0f) - m * m;
    float y = (x - m) * rsqrtf(var + BN_EPS) * in_ld(gamma, f) + in_ld(beta, f);
    y = fmaxf(y, 0.0f);
    if (res) y += res[idx];
    out[idx] = y;
}

__global__ __launch_bounds__(64) void logits_kernel(const float* __restrict__ act, const void* __restrict__ w4,
                                                    const void* __restrict__ b4, float* __restrict__ lg) {
    int idx = blockIdx.x * 64 + threadIdx.x;
    if (idx >= 128 * NCLS) return;
    int r = idx / NCLS, c = idx % NCLS;
    float acc = in_ld(b4, c);
    for (int k = 0; k < 256; k++) acc += act[(size_t)r * 256 + k] * in_ld(w4, (size_t)k * NCLS + c);
    lg[idx] = acc;
}

__global__ __launch_bounds__(64) void softmax_kernel(const float* __restrict__ lg, void* __restrict__ dout) {
    int r = blockIdx.x * 64 + threadIdx.x;
    if (r >= 128) return;
    float l[NCLS];
    float mx = -1e30f;
    for (int c = 0; c < NCLS; c++) { l[c] = lg[(size_t)r * NCLS + c]; mx = fmaxf(mx, l[c]); }
    float sum = 0.f;
    float ex[NCLS];
    for (int c = 0; c < NCLS; c++) { ex[c] = __expf(l[c] - mx); sum += ex[c]; }
    float inv = 1.0f / sum;
    int g = r >> 6, rr = r & 63;
    if (g == 0) {
        for (int c = 0; c < NCLS; c++) st_out(dout, (size_t)rr * NCLS + c, l[c]);
        for (int c = 0; c < NCLS; c++) st_out(dout, 640 + (size_t)rr * NCLS + c, ex[c] * inv);
    } else {
        for (int c = 0; c < NCLS; c++) st_out(dout, 1280 + (size_t)rr * NCLS + c, ex[c] * inv);
    }
}

// ---------------- host launcher ----------------
extern "C" void kernel_launch(void* const* d_in, const int* in_sizes, int n_in,
                              void* d_out, int out_size, void* d_ws, size_t ws_size,
                              hipStream_t stream) {
    (void)in_sizes; (void)n_in; (void)out_size; (void)ws_size;

    const float* x = (const float*)d_in[0];
    const int* eb = (const int*)d_in[1];
    const float* w_s1 = (const float*)d_in[3];
    const float* b_s1 = (const float*)d_in[4];
    const float* w_s21 = (const float*)d_in[5];
    const float* b_s21 = (const float*)d_in[6];
    const float* w_s22 = (const float*)d_in[7];
    const float* b_s22 = (const float*)d_in[8];
    const float* w_raw = (const float*)d_in[9];
    const float* b_raw = (const float*)d_in[10];
    const void* w_pos = d_in[11];
    const void* b_pos = d_in[12];
    const void* w_neg = d_in[13];
    const void* b_neg = d_in[14];
    const float* w_pool = (const float*)d_in[15];
    const float* b_pool = (const float*)d_in[16];
    const float* w1 = (const float*)d_in[17];  const float* b1 = (const float*)d_in[18];
    const void* g1 = d_in[19];  const void* be1 = d_in[20];
    const float* w2 = (const float*)d_in[21];  const float* b2 = (const float*)d_in[22];
    const void* g2 = d_in[23];  const void* be2 = d_in[24];
    const float* w3 = (const float*)d_in[25];  const float* b3 = (const float*)d_in[26];
    const void* g3 = d_in[27];  const void* be3 = d_in[28];
    const void* w4 = d_in[29];  const void* b4 = d_in[30];

    char* ws = (char*)d_ws;
    size_t off = 0;
    auto alloc = [&](size_t b) -> void* {
        void* p = ws + off;
        off += (b + 255) & ~(size_t)255;
        return p;
    };
    int* flag = (int*)alloc(256);
    int* deg = (int*)alloc((size_t)N_NODES * 4);
    float* dinv = (float*)alloc((size_t)N_NODES * 4);
    int* rowptr = (int*)alloc((size_t)(N_NODES + 1) * 4);
    int* cursor = (int*)alloc((size_t)N_NODES * 4);
    int* srcs = (int*)alloc((size_t)NEDGE * 4);
    unsigned short* xbf = (unsigned short*)alloc((size_t)N_NODES * 256 * 2);
    unsigned short* wcat = (unsigned short*)alloc((size_t)768 * 256 * 2);
    unsigned short* wb_s22 = (unsigned short*)alloc((size_t)256 * 256 * 2);
    unsigned short* wb_pool = (unsigned short*)alloc((size_t)768 * 768 * 2);
    unsigned short* tA = (unsigned short*)alloc((size_t)N_NODES * 256 * 2);
    unsigned short* tB = (unsigned short*)alloc((size_t)N_NODES * 256 * 2);
    unsigned short* tmpB = (unsigned short*)alloc((size_t)N_NODES * 256 * 2);
    unsigned short* hfin = (unsigned short*)alloc((size_t)N_NODES * 768 * 2);
    unsigned short* xt = (unsigned short*)alloc((size_t)N_NODES * 768 * 2);
    float* svp = (float*)alloc((size_t)N_NODES * 4);
    float* svn = (float*)alloc((size_t)N_NODES * 4);
    float* scp = (float*)alloc((size_t)N_NODES * 4);
    float* scn = (float*)alloc((size_t)N_NODES * 4);
    unsigned char* maskp = (unsigned char*)alloc(N_NODES);
    unsigned char* maskn = (unsigned char*)alloc(N_NODES);
    float* ebuf = (float*)alloc((size_t)128 * 1536 * 4);
    float* zb = (float*)alloc((size_t)128 * 256 * 4);
    float* act1 = (float*)alloc((size_t)128 * 256 * 4);
    float* act2 = (float*)alloc((size_t)128 * 256 * 4);
    float* act3 = (float*)alloc((size_t)128 * 256 * 4);
    float* lg = (float*)alloc((size_t)128 * NCLS * 4);

    hipMemsetAsync(flag, 0, 256, stream);
    hipMemsetAsync(deg, 0, (size_t)N_NODES * 4, stream);
    detect_kernel<<<NEDGE / 256, 256, 0, stream>>>(eb, flag);
    hist_kernel<<<NEDGE / 256, 256, 0, stream>>>(eb, flag, deg);
    scan_kernel<<<1, 1024, 0, stream>>>(deg, rowptr, cursor, dinv);
    scatter_kernel<<<NEDGE / 256, 256, 0, stream>>>(eb, flag, cursor, srcs);

    // conversions
    cvt_kernel<<<(N_NODES * 256 + 255) / 256, 256, 0, stream>>>(x, xbf, N_NODES * 256);
    cvt_t_all_kernel<<<832, 256, 0, stream>>>(w_s1, w_s21, w_raw, w_s22, w_pool, wcat, wb_s22, wb_pool);

    dim3 gG3(768 / 128, N_NODES / 128);  // (6, 256)
    dim3 gA(256 / 128, N_NODES / 128);   // (2, 256)
    dim3 gP(768 / 128, N_NODES / 128);   // (6, 256)

    // merged s1/s21/raw GEMM (xbf fetched once)
    gemm3_kernel<<<gG3, 256, 0, stream>>>(xbf, wcat, b_raw, tA, tB, hfin);
    // dual aggregation (s1 -> hfin[0:256], s21 -> tmpB)
    agg2_kernel<<<N_NODES / 4, 256, 0, stream>>>(tA, tB, rowptr, srcs, dinv, b_s1, b_s21, hfin, tmpB);
    gemm_kernel<<<gA, 256, 0, stream>>>(tmpB, wb_s22, nullptr, tA, 256, 256, 0, 0);
    agg_kernel<<<N_NODES / 4, 256, 0, stream>>>(tA, rowptr, srcs, dinv, b_s22, hfin, 768, 256, 1);
    // xt = sigmoid(h_final @ w_pool + b_pool)
    gemm_kernel<<<gP, 256, 0, stream>>>(hfin, wb_pool, b_pool, xt, 768, 768, 0, 1);
    // scores
    score_mv_kernel<<<N_NODES / 4, 256, 0, stream>>>(hfin, w_pos, w_neg, svp, svn);
    score_agg_kernel<<<N_NODES / 256, 256, 0, stream>>>(svp, svn, rowptr, srcs, dinv, b_pos, b_neg, scp, scn, d_out);
    // top-k (both polarities) + fused readout
    topk2_kernel<<<2 * NGRAPH, 512, 0, stream>>>(scp, scn, maskp, maskn);
    {
        dim3 gR(NGRAPH, FDIM / 64);
        readout2_kernel<<<gR, 256, 0, stream>>>(xt, maskp, maskn, ebuf);
    }
    // MLP
    {
        dim3 gM(128, 4);
        mlp_gemm2_kernel<<<gM, 256, 0, stream>>>(ebuf, w1, b1, zb, 1536);
        bn_kernel<<<512, 64, 0, stream>>>(zb, g1, be1, nullptr, act1);
        mlp_gemm2_kernel<<<gM, 256, 0, stream>>>(act1, w2, b2, zb, 256);
        bn_kernel<<<512, 64, 0, stream>>>(zb, g2, be2, act1, act2);
        mlp_gemm2_kernel<<<gM, 256, 0, stream>>>(act2, w3, b3, zb, 256);
        bn_kernel<<<512, 64, 0, stream>>>(zb, g3, be3, act2, act3);
    }
    logits_kernel<<<(128 * NCLS + 63) / 64, 64, 0, stream>>>(act3, w4, b4, lg);
    softmax_kernel<<<2, 64, 0, stream>>>(lg, d_out);
}

// Round 9
// 589.625 us; speedup vs baseline: 1.8517x; 1.0207x over previous
//
#include <hip/hip_runtime.h>
#include <hip/hip_bf16.h>

// ---- problem constants ----
#define N_NODES 32768
#define NGRAPH  64
#define NPG     512
#define TOPK    256
#define HID     256
#define FDIM    768
#define NEDGE   262144
#define NCLS    10
#define BN_EPS  1e-5f

#define IN_BF16 0
#define OUT_BF16 0

typedef __attribute__((ext_vector_type(8))) short short8;
typedef __attribute__((ext_vector_type(4))) float f32x4;

__device__ __forceinline__ float bf2f(unsigned short u) {
    return __uint_as_float(((unsigned)u) << 16);
}
__device__ __forceinline__ unsigned short f2bf(float f) {
    unsigned x = __float_as_uint(f);
    unsigned r = (x + 0x7fffu + ((x >> 16) & 1u)) >> 16;
    return (unsigned short)r;
}
__device__ __forceinline__ float in_ld(const void* p, size_t i) {
#if IN_BF16
    return bf2f(((const unsigned short*)p)[i]);
#else
    return ((const float*)p)[i];
#endif
}
__device__ __forceinline__ void st_out(void* o, size_t i, float v) {
#if OUT_BF16
    ((unsigned short*)o)[i] = f2bf(v);
#else
    ((float*)o)[i] = v;
#endif
}

__device__ __forceinline__ void async_cp16(const unsigned short* g, unsigned short* l) {
    __builtin_amdgcn_global_load_lds(
        (const __attribute__((address_space(1))) unsigned int*)g,
        (__attribute__((address_space(3))) unsigned int*)l, 16, 0, 0);
}

// XCD-aware tile swizzle: all nx N-tiles of an M-slab map to one XCD (L%8).
__device__ __forceinline__ void tile_swizzle(int& bm, int& bn) {
    int nx = gridDim.x;
    int L = blockIdx.y * nx + blockIdx.x;
    int xcd = L & 7;
    int j = L >> 3;
    bm = ((j / nx) * 8 + xcd) * 128;
    bn = (j % nx) * 128;
}

// ---------------- all conversions in ONE dispatch ----------------
// ids [0,4096): x fp32 -> bf16 (2048 elems/block, float4-vectorized)
// ids [4096,4160): w_s1 T -> wcat2 rows 0-255
// ids [4160,4224): w_s21 T -> wcat2 rows 256-511
// ids [4224,4288): w_s22 T -> wb_s22
// ids [4288,4352): w_raw T -> wb_raw
// ids [4352,4928): w_pool T -> wpool896 rows 0-767 (ld 768)
// ids [4928,4934): w_pos -> wpool896 row 768; w_neg -> row 769
__global__ __launch_bounds__(256) void cvt_all_kernel(const float* __restrict__ x,
                                                      const float* __restrict__ w_s1,
                                                      const float* __restrict__ w_s21,
                                                      const float* __restrict__ w_s22,
                                                      const float* __restrict__ w_raw,
                                                      const float* __restrict__ w_pool,
                                                      const float* __restrict__ w_pos,
                                                      const float* __restrict__ w_neg,
                                                      unsigned short* __restrict__ xbf,
                                                      unsigned short* __restrict__ wcat2,
                                                      unsigned short* __restrict__ wb_s22,
                                                      unsigned short* __restrict__ wb_raw,
                                                      unsigned short* __restrict__ wpool896) {
    int id = blockIdx.x;
    if (id < 4096) {
        size_t base = (size_t)id * 2048 + threadIdx.x * 8;
        float4 a = *(const float4*)(x + base);
        float4 b = *(const float4*)(x + base + 4);
        unsigned short o[8] = { f2bf(a.x), f2bf(a.y), f2bf(a.z), f2bf(a.w),
                                f2bf(b.x), f2bf(b.y), f2bf(b.z), f2bf(b.w) };
        *(uint4*)(xbf + base) = *(uint4*)o;
        return;
    }
    if (id >= 4928) {
        int j = id - 4928;                       // 0..5
        const float* src = (j < 3) ? w_pos : w_neg;
        int seg = (j < 3) ? j : j - 3;
        size_t row = (j < 3) ? 768 : 769;
        wpool896[row * 768 + seg * 256 + threadIdx.x] = f2bf(src[seg * 256 + threadIdx.x]);
        return;
    }
    __shared__ unsigned short tile[32][33];
    const float* src;
    unsigned short* dst;
    int K, N, t;
    if (id < 4160)      { src = w_s1;  dst = wcat2;                     K = 256; N = 256; t = id - 4096; }
    else if (id < 4224) { src = w_s21; dst = wcat2 + (size_t)256 * 256; K = 256; N = 256; t = id - 4160; }
    else if (id < 4288) { src = w_s22; dst = wb_s22;                    K = 256; N = 256; t = id - 4224; }
    else if (id < 4352) { src = w_raw; dst = wb_raw;                    K = 256; N = 256; t = id - 4288; }
    else                { src = w_pool; dst = wpool896;                 K = 768; N = 768; t = id - 4352; }
    int tiles_x = K >> 5;
    int bk = (t % tiles_x) * 32, bn = (t / tiles_x) * 32;
    int tx = threadIdx.x & 31, ty = threadIdx.x >> 5;
#pragma unroll
    for (int i = 0; i < 32; i += 8)
        tile[ty + i][tx] = f2bf(src[(size_t)(bk + ty + i) * N + bn + tx]);
    __syncthreads();
#pragma unroll
    for (int i = 0; i < 32; i += 8)
        dst[(size_t)(bn + ty + i) * K + bk + tx] = tile[tx][ty + i];
}

// ---------------- edge dtype detection + CSR build ----------------
__global__ __launch_bounds__(256) void detect_kernel(const int* __restrict__ eb, int* __restrict__ flag) {
    int i = blockIdx.x * 256 + threadIdx.x;
    int v = eb[2 * (size_t)i + 1];
    unsigned long long b = __ballot(v != 0);
    if ((threadIdx.x & 63) == 0 && b)
        atomicAdd(flag, (int)__popcll(b));
}

__global__ __launch_bounds__(256) void hist_kernel(const int* __restrict__ eb, const int* __restrict__ flag,
                                                   int* __restrict__ deg) {
    int e = blockIdx.x * 256 + threadIdx.x;
    int st = (*flag == 0) ? 2 : 1;
    unsigned d = ((const unsigned*)eb)[(size_t)(NEDGE + e) * st] & (N_NODES - 1);
    atomicAdd(&deg[d], 1);
}

__global__ __launch_bounds__(1024) void scan_kernel(const int* __restrict__ cnt, int* __restrict__ rowptr,
                                                    int* __restrict__ cursor, float* __restrict__ dinv) {
    __shared__ int part[1024];
    int t = threadIdx.x;
    int base = t * 32;
    int loc[32];
    int s = 0;
#pragma unroll
    for (int i = 0; i < 32; i++) { loc[i] = cnt[base + i]; s += loc[i]; }
    part[t] = s;
    __syncthreads();
    for (int off = 1; off < 1024; off <<= 1) {
        int v = (t >= off) ? part[t - off] : 0;
        __syncthreads();
        part[t] += v;
        __syncthreads();
    }
    int run = (t == 0) ? 0 : part[t - 1];
#pragma unroll
    for (int i = 0; i < 32; i++) {
        rowptr[base + i] = run;
        cursor[base + i] = run;
        dinv[base + i] = rsqrtf((float)loc[i] + 1.0f);
        run += loc[i];
    }
    if (t == 1023) rowptr[N_NODES] = run;
}

__global__ __launch_bounds__(256) void scatter_kernel(const int* __restrict__ eb, const int* __restrict__ flag,
                                                      int* __restrict__ cursor, int* __restrict__ srcs) {
    int e = blockIdx.x * 256 + threadIdx.x;
    int st = (*flag == 0) ? 2 : 1;
    unsigned s = ((const unsigned*)eb)[(size_t)e * st] & (N_NODES - 1);
    unsigned d = ((const unsigned*)eb)[(size_t)(NEDGE + e) * st] & (N_NODES - 1);
    int p = atomicAdd(&cursor[d], 1);
    srcs[p] = (int)s;
}

// ---------------- GEMM core (128x128 tile, BK=64) ----------------
// gc = schunk ^ srow is loop-invariant (r&7 == srow). Runtime or literal K.
#define GEMM_CORE(K_)                                                           \
    __shared__ unsigned short As[128 * 64];                                     \
    __shared__ unsigned short Bs[128 * 64];                                     \
    const int tid = threadIdx.x;                                                \
    const int wave = tid >> 6;                                                  \
    const int lane = tid & 63;                                                  \
    int bm, bn;                                                                 \
    tile_swizzle(bm, bn);                                                       \
    const int wm = (wave >> 1) * 64;                                            \
    const int wn = (wave & 1) * 64;                                             \
    const int l15 = lane & 15;                                                  \
    const int q = lane >> 4;                                                    \
    f32x4 acc[4][4] = {};                                                       \
    const int srow = lane >> 3;                                                 \
    const int schunk = lane & 7;                                                \
    const int gc = schunk ^ srow;                                               \
    const unsigned short* gaA = A + (size_t)(bm + wave * 8 + srow) * (K_) + gc * 8;  \
    const unsigned short* gbB = WT + (size_t)(bn + wave * 8 + srow) * (K_) + gc * 8; \
    const size_t K32 = (size_t)(K_) * 32;                                       \
    unsigned short* const la0 = &As[(wave * 8) * 64];                           \
    unsigned short* const lb0 = &Bs[(wave * 8) * 64];                           \
    for (int k0 = 0; k0 < (K_); k0 += 64) {                                     \
        __syncthreads();                                                        \
        _Pragma("unroll")                                                       \
        for (int t = 0; t < 4; t++) {                                           \
            async_cp16(gaA + t * K32 + k0, la0 + t * 32 * 64);                  \
            async_cp16(gbB + t * K32 + k0, lb0 + t * 32 * 64);                  \
        }                                                                       \
        __syncthreads();                                                        \
        _Pragma("unroll")                                                       \
        for (int h = 0; h < 2; h++) {                                           \
            short8 af[4], bfv[4];                                               \
            int p = (h * 4 + q) ^ (l15 & 7);                                    \
            _Pragma("unroll")                                                   \
            for (int t = 0; t < 4; t++) {                                       \
                int m = wm + t * 16 + l15;                                      \
                int n = wn + t * 16 + l15;                                      \
                af[t] = *(const short8*)&As[m * 64 + p * 8];                    \
                bfv[t] = *(const short8*)&Bs[n * 64 + p * 8];                   \
            }                                                                   \
            _Pragma("unroll")                                                   \
            for (int tm = 0; tm < 4; tm++)                                      \
                _Pragma("unroll")                                               \
                for (int tn = 0; tn < 4; tn++)                                  \
                    acc[tm][tn] = __builtin_amdgcn_mfma_f32_16x16x32_bf16(af[tm], bfv[tn], acc[tm][tn], 0, 0, 0); \
        }                                                                       \
    }

// generic GEMM, runtime K. epi: 0 none, 1 sigmoid, 2 leaky-relu
__global__ __launch_bounds__(256) void gemm_kernel(const unsigned short* __restrict__ A,
                                                   const unsigned short* __restrict__ WT,
                                                   const float* __restrict__ bias,
                                                   unsigned short* __restrict__ C,
                                                   int K, int ldC, int colOff, int epi) {
    GEMM_CORE(K)
#pragma unroll
    for (int tm = 0; tm < 4; tm++) {
        int row = bm + wm + tm * 16 + q * 4;
#pragma unroll
        for (int tn = 0; tn < 4; tn++) {
            int col = bn + wn + tn * 16 + l15;
            float bv = bias ? bias[col] : 0.0f;
#pragma unroll
            for (int r = 0; r < 4; r++) {
                float v = acc[tm][tn][r] + bv;
                if (epi == 1) v = 1.0f / (1.0f + __expf(-v));
                else if (epi == 2) v = v > 0.f ? v : 0.01f * v;
                C[(size_t)(row + r) * ldC + colOff + col] = f2bf(v);
            }
        }
    }
}

// Xa @ [Ws1|Ws21]: cols 0-255 -> lrelu+b_s1 -> hfin[:,0:256]; 256-511 -> lrelu+b_s21 -> t1
__global__ __launch_bounds__(256) void gemmA_kernel(const unsigned short* __restrict__ A,
                                                    const unsigned short* __restrict__ WT,
                                                    const float* __restrict__ b_s1,
                                                    const float* __restrict__ b_s21,
                                                    unsigned short* __restrict__ hfin,
                                                    unsigned short* __restrict__ t1) {
    GEMM_CORE(256)
#pragma unroll
    for (int tm = 0; tm < 4; tm++) {
        int row = bm + wm + tm * 16 + q * 4;
#pragma unroll
        for (int tn = 0; tn < 4; tn++) {
            int col = bn + wn + tn * 16 + l15;        // subtile-uniform side of 256
            if (col < 256) {
                float bv = b_s1[col];
#pragma unroll
                for (int r = 0; r < 4; r++) {
                    float v = acc[tm][tn][r] + bv;
                    v = v > 0.f ? v : 0.01f * v;
                    hfin[(size_t)(row + r) * 768 + col] = f2bf(v);
                }
            } else {
                float bv = b_s21[col - 256];
#pragma unroll
                for (int r = 0; r < 4; r++) {
                    float v = acc[tm][tn][r] + bv;
                    v = v > 0.f ? v : 0.01f * v;
                    t1[(size_t)(row + r) * 256 + (col - 256)] = f2bf(v);
                }
            }
        }
    }
}

// pool GEMM with fused score columns: N=896 (cols 0-767 pool -> sigmoid -> xt;
// col 768 -> svp; col 769 -> svn; 770+ discard)
__global__ __launch_bounds__(256) void gemmP_kernel(const unsigned short* __restrict__ A,
                                                    const unsigned short* __restrict__ WT,
                                                    const float* __restrict__ b_pool,
                                                    unsigned short* __restrict__ xt,
                                                    float* __restrict__ svp, float* __restrict__ svn,
                                                    int K) {
    GEMM_CORE(K)
#pragma unroll
    for (int tm = 0; tm < 4; tm++) {
        int row = bm + wm + tm * 16 + q * 4;
#pragma unroll
        for (int tn = 0; tn < 4; tn++) {
            int col = bn + wn + tn * 16 + l15;
            if (col < 768) {
                float bv = b_pool[col];
#pragma unroll
                for (int r = 0; r < 4; r++) {
                    float v = acc[tm][tn][r] + bv;
                    v = 1.0f / (1.0f + __expf(-v));
                    xt[(size_t)(row + r) * 768 + col] = f2bf(v);
                }
            } else if (col == 768) {
#pragma unroll
                for (int r = 0; r < 4; r++) svp[row + r] = acc[tm][tn][r];
            } else if (col == 769) {
#pragma unroll
                for (int r = 0; r < 4; r++) svn[row + r] = acc[tm][tn][r];
            }
        }
    }
}

// ---------------- pure linear GCN aggregation (256-dim): out = D^-.5 A D^-.5 h + dinv^2 h ----------------
__global__ __launch_bounds__(256) void lin_agg_kernel(const unsigned short* __restrict__ h,
                                                      const int* __restrict__ rowptr, const int* __restrict__ srcs,
                                                      const float* __restrict__ dinv,
                                                      unsigned short* __restrict__ out) {
    int wave = threadIdx.x >> 6, lane = threadIdx.x & 63;
    int v = blockIdx.x * 4 + wave;
    int f0 = lane * 4;
    float a0 = 0.f, a1 = 0.f, a2 = 0.f, a3 = 0.f;
    int s = rowptr[v], e = rowptr[v + 1];
    for (int i = s; i < e; i++) {
        int u = srcs[i] & (N_NODES - 1);
        float du = dinv[u];
        uint2 hv = *(const uint2*)(h + (size_t)u * 256 + f0);
        a0 += bf2f((unsigned short)(hv.x & 0xffff)) * du;
        a1 += bf2f((unsigned short)(hv.x >> 16)) * du;
        a2 += bf2f((unsigned short)(hv.y & 0xffff)) * du;
        a3 += bf2f((unsigned short)(hv.y >> 16)) * du;
    }
    float dv = dinv[v], dv2 = dv * dv;
    uint2 sv = *(const uint2*)(h + (size_t)v * 256 + f0);
    float r0 = dv * a0 + bf2f((unsigned short)(sv.x & 0xffff)) * dv2;
    float r1 = dv * a1 + bf2f((unsigned short)(sv.x >> 16)) * dv2;
    float r2 = dv * a2 + bf2f((unsigned short)(sv.y & 0xffff)) * dv2;
    float r3 = dv * a3 + bf2f((unsigned short)(sv.y >> 16)) * dv2;
    uint2 ov = make_uint2(((unsigned)f2bf(r1) << 16) | f2bf(r0), ((unsigned)f2bf(r3) << 16) | f2bf(r2));
    *(uint2*)(out + (size_t)v * 256 + f0) = ov;
}

// ---------------- scalar GCN agg on scores + sigmoid (+ batch output fused) ----------------
__global__ __launch_bounds__(256) void score_agg_kernel(const float* __restrict__ svp, const float* __restrict__ svn,
                                                        const int* __restrict__ rowptr, const int* __restrict__ srcs,
                                                        const float* __restrict__ dinv,
                                                        const void* __restrict__ bp, const void* __restrict__ bn_,
                                                        float* __restrict__ scp, float* __restrict__ scn,
                                                        void* __restrict__ dout) {
    int v = blockIdx.x * 256 + threadIdx.x;
    float ap = 0.f, an = 0.f;
    int s = rowptr[v], e = rowptr[v + 1];
    for (int i = s; i < e; i++) {
        int u = srcs[i] & (N_NODES - 1);
        float du = dinv[u];
        ap += svp[u] * du;
        an += svn[u] * du;
    }
    float dv = dinv[v], dv2 = dv * dv;
    float zp = dv * ap + svp[v] * dv2 + in_ld(bp, 0);
    float zn = dv * an + svn[v] * dv2 + in_ld(bn_, 0);
    float pp = 1.0f / (1.0f + __expf(-zp));
    float pn = 1.0f / (1.0f + __expf(-zn));
    scp[v] = pp;
    scn[v] = pn;
    st_out(dout, 1920 + (size_t)v, pp);
    st_out(dout, 1920 + (size_t)N_NODES + v, pn);
    st_out(dout, 1920 + 2 * (size_t)N_NODES + v, (float)(v >> 9));
}

// ---------------- top-k masks, pos+neg in one launch ----------------
__global__ __launch_bounds__(512) void topk2_kernel(const float* __restrict__ scp, const float* __restrict__ scn,
                                                    unsigned char* __restrict__ maskp,
                                                    unsigned char* __restrict__ maskn) {
    __shared__ float s[512];
    const float* sc = (blockIdx.x & 1) ? scn : scp;
    unsigned char* mask = (blockIdx.x & 1) ? maskn : maskp;
    int g = blockIdx.x >> 1, i = threadIdx.x;
    float my = sc[(size_t)g * 512 + i];
    s[i] = my;
    __syncthreads();
    int cnt = 0;
    for (int j = 0; j < 512; j++) {
        float o = s[j];
        cnt += (int)((o > my) || ((o == my) && (j < i)));
    }
    mask[(size_t)g * 512 + i] = (cnt < TOPK) ? 1 : 0;
}

// ---------------- fused dual-mask readout ----------------
__global__ __launch_bounds__(256) void readout2_kernel(const unsigned short* __restrict__ xt,
                                                       const unsigned char* __restrict__ maskp,
                                                       const unsigned char* __restrict__ maskn,
                                                       float* __restrict__ eout) {
    int g = blockIdx.x;
    int c = blockIdx.y;
    int wv = threadIdx.x >> 6, lane = threadIdx.x & 63;
    int f = c * 64 + lane;
    __shared__ unsigned char mp[512], mn[512];
    __shared__ float red[4][64][4];
    for (int i = threadIdx.x; i < 512; i += 256) {
        mp[i] = maskp[(size_t)g * 512 + i];
        mn[i] = maskn[(size_t)g * 512 + i];
    }
    __syncthreads();
    float sp = 0.f, sn = 0.f, xp = -INFINITY, xn = -INFINITY;
    const unsigned short* base = xt + ((size_t)g * 512 + wv * 128) * 768 + f;
    for (int v = 0; v < 128; v++) {
        unsigned char bp = mp[wv * 128 + v], bn_ = mn[wv * 128 + v];
        if (!(bp | bn_)) continue;
        float x = bf2f(base[(size_t)v * 768]);
        if (bp) { sp += x; xp = fmaxf(xp, x); }
        if (bn_) { sn += x; xn = fmaxf(xn, x); }
    }
    red[wv][lane][0] = sp; red[wv][lane][1] = xp;
    red[wv][lane][2] = sn; red[wv][lane][3] = xn;
    __syncthreads();
    if (wv == 0) {
#pragma unroll
        for (int w = 1; w < 4; w++) {
            sp += red[w][lane][0]; xp = fmaxf(xp, red[w][lane][1]);
            sn += red[w][lane][2]; xn = fmaxf(xn, red[w][lane][3]);
        }
        float* erp = eout + (size_t)g * 1536;
        float* ern = eout + (size_t)(64 + g) * 1536;
        erp[f] = sp * (1.0f / TOPK);
        erp[768 + f] = xp;
        ern[f] = sn * (1.0f / TOPK);
        ern[768 + f] = xn;
    }
}

// ---------------- MLP GEMM, k-split + n-split ----------------
__global__ __launch_bounds__(256) void mlp_gemm2_kernel(const float* __restrict__ in,
                                                        const float* __restrict__ W,
                                                        const float* __restrict__ b,
                                                        float* __restrict__ out, int K) {
    __shared__ float row[1536];
    __shared__ float red[4][64];
    int r = blockIdx.x, cg = blockIdx.y;
    int wv = threadIdx.x >> 6, lane = threadIdx.x & 63;
    int c = cg * 64 + lane;
    for (int k = threadIdx.x; k < K; k += 256) row[k] = in[(size_t)r * K + k];
    __syncthreads();
    int kpw = K >> 2;
    const float* wp = W + (size_t)(wv * kpw) * 256 + c;
    const float* rp = row + wv * kpw;
    float acc = 0.f;
#pragma unroll 4
    for (int k = 0; k < kpw; k++)
        acc += rp[k] * wp[(size_t)k * 256];
    red[wv][lane] = acc;
    __syncthreads();
    if (wv == 0) {
        float v = red[0][lane] + red[1][lane] + red[2][lane] + red[3][lane] + b[c];
        out[(size_t)r * 256 + c] = v;
    }
}

__global__ __launch_bounds__(64) void bn_kernel(const float* __restrict__ z, const void* __restrict__ gamma,
                                                const void* __restrict__ beta, const float* __restrict__ res,
                                                float* __restrict__ out) {
    int f = blockIdx.x & 255, g = blockIdx.x >> 8, r = threadIdx.x;
    size_t idx = (size_t)(g * 64 + r) * 256 + f;
    float x = z[idx];
    float s = x, sq = x * x;
    for (int off = 1; off < 64; off <<= 1) {
        s += __shfl_xor(s, off, 64);
        sq += __shfl_xor(sq, off, 64);
    }
    float m = s * (1.0f / 64.0f);
    float var = sq * (1.0f / 64.0f) - m * m;
    float y = (x - m) * rsqrtf(var + BN_EPS) * in_ld(gamma, f) + in_ld(beta, f);
    y = fmaxf(y, 0.0f);
    if (res) y += res[idx];
    out[idx] = y;
}

__global__ __launch_bounds__(64) void logits_kernel(const float* __restrict__ act, const void* __restrict__ w4,
                                                    const void* __restrict__ b4, float* __restrict__ lg) {
    int idx = blockIdx.x * 64 + threadIdx.x;
    if (idx >= 128 * NCLS) return;
    int r = idx / NCLS, c = idx % NCLS;
    float acc = in_ld(b4, c);
    for (int k = 0; k < 256; k++) acc += act[(size_t)r * 256 + k] * in_ld(w4, (size_t)k * NCLS + c);
    lg[idx] = acc;
}

__global__ __launch_bounds__(64) void softmax_kernel(const float* __restrict__ lg, void* __restrict__ dout) {
    int r = blockIdx.x * 64 + threadIdx.x;
    if (r >= 128) return;
    float l[NCLS];
    float mx = -1e30f;
    for (int c = 0; c < NCLS; c++) { l[c] = lg[(size_t)r * NCLS + c]; mx = fmaxf(mx, l[c]); }
    float sum = 0.f;
    float ex[NCLS];
    for (int c = 0; c < NCLS; c++) { ex[c] = __expf(l[c] - mx); sum += ex[c]; }
    float inv = 1.0f / sum;
    int g = r >> 6, rr = r & 63;
    if (g == 0) {
        for (int c = 0; c < NCLS; c++) st_out(dout, (size_t)rr * NCLS + c, l[c]);
        for (int c = 0; c < NCLS; c++) st_out(dout, 640 + (size_t)rr * NCLS + c, ex[c] * inv);
    } else {
        for (int c = 0; c < NCLS; c++) st_out(dout, 1280 + (size_t)rr * NCLS + c, ex[c] * inv);
    }
}

// ---------------- host launcher ----------------
extern "C" void kernel_launch(void* const* d_in, const int* in_sizes, int n_in,
                              void* d_out, int out_size, void* d_ws, size_t ws_size,
                              hipStream_t stream) {
    (void)in_sizes; (void)n_in; (void)out_size; (void)ws_size;

    const float* x = (const float*)d_in[0];
    const int* eb = (const int*)d_in[1];
    const float* w_s1 = (const float*)d_in[3];
    const float* b_s1 = (const float*)d_in[4];
    const float* w_s21 = (const float*)d_in[5];
    const float* b_s21 = (const float*)d_in[6];
    const float* w_s22 = (const float*)d_in[7];
    const float* b_s22 = (const float*)d_in[8];
    const float* w_raw = (const float*)d_in[9];
    const float* b_raw = (const float*)d_in[10];
    const float* w_pos = (const float*)d_in[11];
    const void* b_pos = d_in[12];
    const float* w_neg = (const float*)d_in[13];
    const void* b_neg = d_in[14];
    const float* w_pool = (const float*)d_in[15];
    const float* b_pool = (const float*)d_in[16];
    const float* w1 = (const float*)d_in[17];  const float* b1 = (const float*)d_in[18];
    const void* g1 = d_in[19];  const void* be1 = d_in[20];
    const float* w2 = (const float*)d_in[21];  const float* b2 = (const float*)d_in[22];
    const void* g2 = d_in[23];  const void* be2 = d_in[24];
    const float* w3 = (const float*)d_in[25];  const float* b3 = (const float*)d_in[26];
    const void* g3 = d_in[27];  const void* be3 = d_in[28];
    const void* w4 = d_in[29];  const void* b4 = d_in[30];

    char* ws = (char*)d_ws;
    size_t off = 0;
    auto alloc = [&](size_t b) -> void* {
        void* p = ws + off;
        off += (b + 255) & ~(size_t)255;
        return p;
    };
    int* flag = (int*)alloc(256);
    int* deg = (int*)alloc((size_t)N_NODES * 4);
    float* dinv = (float*)alloc((size_t)N_NODES * 4);
    int* rowptr = (int*)alloc((size_t)(N_NODES + 1) * 4);
    int* cursor = (int*)alloc((size_t)N_NODES * 4);
    int* srcs = (int*)alloc((size_t)NEDGE * 4);
    unsigned short* xbf = (unsigned short*)alloc((size_t)N_NODES * 256 * 2);
    unsigned short* wcat2 = (unsigned short*)alloc((size_t)512 * 256 * 2);
    unsigned short* wb_s22 = (unsigned short*)alloc((size_t)256 * 256 * 2);
    unsigned short* wb_raw = (unsigned short*)alloc((size_t)256 * 256 * 2);
    unsigned short* wpool896 = (unsigned short*)alloc((size_t)896 * 768 * 2);
    unsigned short* Xa = (unsigned short*)alloc((size_t)N_NODES * 256 * 2);
    unsigned short* t1 = (unsigned short*)alloc((size_t)N_NODES * 256 * 2);
    unsigned short* t1a = (unsigned short*)alloc((size_t)N_NODES * 256 * 2);
    unsigned short* hfin = (unsigned short*)alloc((size_t)N_NODES * 768 * 2);
    unsigned short* xt = (unsigned short*)alloc((size_t)N_NODES * 768 * 2);
    float* svp = (float*)alloc((size_t)N_NODES * 4);
    float* svn = (float*)alloc((size_t)N_NODES * 4);
    float* scp = (float*)alloc((size_t)N_NODES * 4);
    float* scn = (float*)alloc((size_t)N_NODES * 4);
    unsigned char* maskp = (unsigned char*)alloc(N_NODES);
    unsigned char* maskn = (unsigned char*)alloc(N_NODES);
    float* ebuf = (float*)alloc((size_t)128 * 1536 * 4);
    float* zb = (float*)alloc((size_t)128 * 256 * 4);
    float* act1 = (float*)alloc((size_t)128 * 256 * 4);
    float* act2 = (float*)alloc((size_t)128 * 256 * 4);
    float* act3 = (float*)alloc((size_t)128 * 256 * 4);
    float* lg = (float*)alloc((size_t)128 * NCLS * 4);

    hipMemsetAsync(flag, 0, 256, stream);
    hipMemsetAsync(deg, 0, (size_t)N_NODES * 4, stream);
    // zero pad rows 770-895 of wpool896 (un-initialized ws is 0xAA-poisoned)
    hipMemsetAsync(wpool896 + (size_t)770 * 768, 0, (size_t)126 * 768 * 2, stream);

    detect_kernel<<<NEDGE / 256, 256, 0, stream>>>(eb, flag);
    hist_kernel<<<NEDGE / 256, 256, 0, stream>>>(eb, flag, deg);
    scan_kernel<<<1, 1024, 0, stream>>>(deg, rowptr, cursor, dinv);
    scatter_kernel<<<NEDGE / 256, 256, 0, stream>>>(eb, flag, cursor, srcs);

    cvt_all_kernel<<<4934, 256, 0, stream>>>(x, w_s1, w_s21, w_s22, w_raw, w_pool, w_pos, w_neg,
                                             xbf, wcat2, wb_s22, wb_raw, wpool896);

    dim3 gA2(512 / 128, N_NODES / 128);  // (4, 256)
    dim3 gA1(256 / 128, N_NODES / 128);  // (2, 256)
    dim3 gP(896 / 128, N_NODES / 128);   // (7, 256)

    // linearity-restructured GCN pipeline
    lin_agg_kernel<<<N_NODES / 4, 256, 0, stream>>>(xbf, rowptr, srcs, dinv, Xa);
    gemmA_kernel<<<gA2, 256, 0, stream>>>(Xa, wcat2, b_s1, b_s21, hfin, t1);
    lin_agg_kernel<<<N_NODES / 4, 256, 0, stream>>>(t1, rowptr, srcs, dinv, t1a);
    gemm_kernel<<<gA1, 256, 0, stream>>>(t1a, wb_s22, b_s22, hfin, 256, 768, 256, 2);
    gemm_kernel<<<gA1, 256, 0, stream>>>(xbf, wb_raw, b_raw, hfin, 256, 768, 512, 0);
    // pool + fused score matvecs
    gemmP_kernel<<<gP, 256, 0, stream>>>(hfin, wpool896, b_pool, xt, svp, svn, 768);
    // score aggregation + outputs
    score_agg_kernel<<<N_NODES / 256, 256, 0, stream>>>(svp, svn, rowptr, srcs, dinv, b_pos, b_neg, scp, scn, d_out);
    // top-k + readout
    topk2_kernel<<<2 * NGRAPH, 512, 0, stream>>>(scp, scn, maskp, maskn);
    {
        dim3 gR(NGRAPH, FDIM / 64);
        readout2_kernel<<<gR, 256, 0, stream>>>(xt, maskp, maskn, ebuf);
    }
    // MLP
    {
        dim3 gM(128, 4);
        mlp_gemm2_kernel<<<gM, 256, 0, stream>>>(ebuf, w1, b1, zb, 1536);
        bn_kernel<<<512, 64, 0, stream>>>(zb, g1, be1, nullptr, act1);
        mlp_gemm2_kernel<<<gM, 256, 0, stream>>>(act1, w2, b2, zb, 256);
        bn_kernel<<<512, 64, 0, stream>>>(zb, g2, be2, act1, act2);
        mlp_gemm2_kernel<<<gM, 256, 0, stream>>>(act2, w3, b3, zb, 256);
        bn_kernel<<<512, 64, 0, stream>>>(zb, g3, be3, act2, act3);
    }
    logits_kernel<<<(128 * NCLS + 63) / 64, 64, 0, stream>>>(act3, w4, b4, lg);
    softmax_kernel<<<2, 64, 0, stream>>>(lg, d_out);
}

// Round 10
// 588.224 us; speedup vs baseline: 1.8561x; 1.0024x over previous
//
#include <hip/hip_runtime.h>
#include <hip/hip_bf16.h>

// ---- problem constants ----
#define N_NODES 32768
#define NGRAPH  64
#define NPG     512
#define TOPK    256
#define HID     256
#define FDIM    768
#define NEDGE   262144
#define NCLS    10
#define BN_EPS  1e-5f

#define IN_BF16 0
#define OUT_BF16 0

typedef __attribute__((ext_vector_type(8))) short short8;
typedef __attribute__((ext_vector_type(4))) float f32x4;

__device__ __forceinline__ float bf2f(unsigned short u) {
    return __uint_as_float(((unsigned)u) << 16);
}
__device__ __forceinline__ unsigned short f2bf(float f) {
    unsigned x = __float_as_uint(f);
    unsigned r = (x + 0x7fffu + ((x >> 16) & 1u)) >> 16;
    return (unsigned short)r;
}
__device__ __forceinline__ float in_ld(const void* p, size_t i) {
#if IN_BF16
    return bf2f(((const unsigned short*)p)[i]);
#else
    return ((const float*)p)[i];
#endif
}
__device__ __forceinline__ void st_out(void* o, size_t i, float v) {
#if OUT_BF16
    ((unsigned short*)o)[i] = f2bf(v);
#else
    ((float*)o)[i] = v;
#endif
}

__device__ __forceinline__ void async_cp16(const unsigned short* g, unsigned short* l) {
    __builtin_amdgcn_global_load_lds(
        (const __attribute__((address_space(1))) unsigned int*)g,
        (__attribute__((address_space(3))) unsigned int*)l, 16, 0, 0);
}

// XCD-aware tile swizzle (bijective; perf heuristic only)
__device__ __forceinline__ void tile_swizzle(int& bm, int& bn) {
    int nx = gridDim.x;
    int L = blockIdx.y * nx + blockIdx.x;
    int xcd = L & 7;
    int j = L >> 3;
    bm = ((j / nx) * 8 + xcd) * 128;
    bn = (j % nx) * 128;
}

// ---------------- conversions, one dispatch ----------------
// ids [0,4096): x fp32->bf16 vectorized; then transposes:
// [4096,4224): wcat2 (w_s1 rows 0-255, w_s21 rows 256-511)
// [4224,4288): wb_s22 ; [4288,4352): wb_raw ; [4352,4928): wb_pool
__global__ __launch_bounds__(256) void cvt_all_kernel(const float* __restrict__ x,
                                                      const float* __restrict__ w_s1,
                                                      const float* __restrict__ w_s21,
                                                      const float* __restrict__ w_s22,
                                                      const float* __restrict__ w_raw,
                                                      const float* __restrict__ w_pool,
                                                      unsigned short* __restrict__ xbf,
                                                      unsigned short* __restrict__ wcat2,
                                                      unsigned short* __restrict__ wb_s22,
                                                      unsigned short* __restrict__ wb_raw,
                                                      unsigned short* __restrict__ wb_pool) {
    int id = blockIdx.x;
    if (id < 4096) {
        size_t base = (size_t)id * 2048 + threadIdx.x * 8;
        float4 a = *(const float4*)(x + base);
        float4 b = *(const float4*)(x + base + 4);
        unsigned short o[8] = { f2bf(a.x), f2bf(a.y), f2bf(a.z), f2bf(a.w),
                                f2bf(b.x), f2bf(b.y), f2bf(b.z), f2bf(b.w) };
        *(uint4*)(xbf + base) = *(uint4*)o;
        return;
    }
    __shared__ unsigned short tile[32][33];
    const float* src;
    unsigned short* dst;
    int K, N, t;
    if (id < 4160)      { src = w_s1;  dst = wcat2;                     K = 256; N = 256; t = id - 4096; }
    else if (id < 4224) { src = w_s21; dst = wcat2 + (size_t)256 * 256; K = 256; N = 256; t = id - 4160; }
    else if (id < 4288) { src = w_s22; dst = wb_s22;                    K = 256; N = 256; t = id - 4224; }
    else if (id < 4352) { src = w_raw; dst = wb_raw;                    K = 256; N = 256; t = id - 4288; }
    else                { src = w_pool; dst = wb_pool;                  K = 768; N = 768; t = id - 4352; }
    int tiles_x = K >> 5;
    int bk = (t % tiles_x) * 32, bn = (t / tiles_x) * 32;
    int tx = threadIdx.x & 31, ty = threadIdx.x >> 5;
#pragma unroll
    for (int i = 0; i < 32; i += 8)
        tile[ty + i][tx] = f2bf(src[(size_t)(bk + ty + i) * N + bn + tx]);
    __syncthreads();
#pragma unroll
    for (int i = 0; i < 32; i += 8)
        dst[(size_t)(bn + ty + i) * K + bk + tx] = tile[tx][ty + i];
}

// ---------------- edge dtype detection + CSR build ----------------
__global__ __launch_bounds__(256) void detect_kernel(const int* __restrict__ eb, int* __restrict__ flag) {
    int i = blockIdx.x * 256 + threadIdx.x;
    int v = eb[2 * (size_t)i + 1];
    unsigned long long b = __ballot(v != 0);
    if ((threadIdx.x & 63) == 0 && b)
        atomicAdd(flag, (int)__popcll(b));
}

__global__ __launch_bounds__(256) void hist_kernel(const int* __restrict__ eb, const int* __restrict__ flag,
                                                   int* __restrict__ deg) {
    int e = blockIdx.x * 256 + threadIdx.x;
    int st = (*flag == 0) ? 2 : 1;
    unsigned d = ((const unsigned*)eb)[(size_t)(NEDGE + e) * st] & (N_NODES - 1);
    atomicAdd(&deg[d], 1);
}

__global__ __launch_bounds__(1024) void scan_kernel(const int* __restrict__ cnt, int* __restrict__ rowptr,
                                                    int* __restrict__ cursor, float* __restrict__ dinv) {
    __shared__ int part[1024];
    int t = threadIdx.x;
    int base = t * 32;
    int loc[32];
    int s = 0;
#pragma unroll
    for (int i = 0; i < 32; i++) { loc[i] = cnt[base + i]; s += loc[i]; }
    part[t] = s;
    __syncthreads();
    for (int off = 1; off < 1024; off <<= 1) {
        int v = (t >= off) ? part[t - off] : 0;
        __syncthreads();
        part[t] += v;
        __syncthreads();
    }
    int run = (t == 0) ? 0 : part[t - 1];
#pragma unroll
    for (int i = 0; i < 32; i++) {
        rowptr[base + i] = run;
        cursor[base + i] = run;
        dinv[base + i] = rsqrtf((float)loc[i] + 1.0f);
        run += loc[i];
    }
    if (t == 1023) rowptr[N_NODES] = run;
}

__global__ __launch_bounds__(256) void scatter_kernel(const int* __restrict__ eb, const int* __restrict__ flag,
                                                      int* __restrict__ cursor, int* __restrict__ srcs) {
    int e = blockIdx.x * 256 + threadIdx.x;
    int st = (*flag == 0) ? 2 : 1;
    unsigned s = ((const unsigned*)eb)[(size_t)e * st] & (N_NODES - 1);
    unsigned d = ((const unsigned*)eb)[(size_t)(NEDGE + e) * st] & (N_NODES - 1);
    int p = atomicAdd(&cursor[d], 1);
    srcs[p] = (int)s;
}

// ---------------- GEMM body (128x128 tile, BK=64); caller sets A, WT, bm, bn ----------------
#define GEMM_BODY(K_)                                                           \
    __shared__ unsigned short As[128 * 64];                                     \
    __shared__ unsigned short Bs[128 * 64];                                     \
    const int tid = threadIdx.x;                                                \
    const int wave = tid >> 6;                                                  \
    const int lane = tid & 63;                                                  \
    const int wm = (wave >> 1) * 64;                                            \
    const int wn = (wave & 1) * 64;                                             \
    const int l15 = lane & 15;                                                  \
    const int q = lane >> 4;                                                    \
    f32x4 acc[4][4] = {};                                                       \
    const int srow = lane >> 3;                                                 \
    const int schunk = lane & 7;                                                \
    const int gc = schunk ^ srow;                                               \
    const unsigned short* gaA = A + (size_t)(bm + wave * 8 + srow) * (K_) + gc * 8;  \
    const unsigned short* gbB = WT + (size_t)(bn + wave * 8 + srow) * (K_) + gc * 8; \
    const size_t K32 = (size_t)(K_) * 32;                                       \
    unsigned short* const la0 = &As[(wave * 8) * 64];                           \
    unsigned short* const lb0 = &Bs[(wave * 8) * 64];                           \
    for (int k0 = 0; k0 < (K_); k0 += 64) {                                     \
        __syncthreads();                                                        \
        _Pragma("unroll")                                                       \
        for (int t = 0; t < 4; t++) {                                           \
            async_cp16(gaA + t * K32 + k0, la0 + t * 32 * 64);                  \
            async_cp16(gbB + t * K32 + k0, lb0 + t * 32 * 64);                  \
        }                                                                       \
        __syncthreads();                                                        \
        _Pragma("unroll")                                                       \
        for (int h = 0; h < 2; h++) {                                           \
            short8 af[4], bfv[4];                                               \
            int p = (h * 4 + q) ^ (l15 & 7);                                    \
            _Pragma("unroll")                                                   \
            for (int t = 0; t < 4; t++) {                                       \
                int m = wm + t * 16 + l15;                                      \
                int n = wn + t * 16 + l15;                                      \
                af[t] = *(const short8*)&As[m * 64 + p * 8];                    \
                bfv[t] = *(const short8*)&Bs[n * 64 + p * 8];                   \
            }                                                                   \
            _Pragma("unroll")                                                   \
            for (int tm = 0; tm < 4; tm++)                                      \
                _Pragma("unroll")                                               \
                for (int tn = 0; tn < 4; tn++)                                  \
                    acc[tm][tn] = __builtin_amdgcn_mfma_f32_16x16x32_bf16(af[tm], bfv[tn], acc[tm][tn], 0, 0, 0); \
        }                                                                       \
    }

// generic GEMM, runtime K. epi: 0 none, 1 sigmoid, 2 leaky-relu
__global__ __launch_bounds__(256) void gemm_kernel(const unsigned short* __restrict__ A,
                                                   const unsigned short* __restrict__ WT,
                                                   const float* __restrict__ bias,
                                                   unsigned short* __restrict__ C,
                                                   int K, int ldC, int colOff, int epi) {
    int bm, bn;
    tile_swizzle(bm, bn);
    GEMM_BODY(K)
#pragma unroll
    for (int tm = 0; tm < 4; tm++) {
        int row = bm + wm + tm * 16 + q * 4;
#pragma unroll
        for (int tn = 0; tn < 4; tn++) {
            int col = bn + wn + tn * 16 + l15;
            float bv = bias ? bias[col] : 0.0f;
#pragma unroll
            for (int r = 0; r < 4; r++) {
                float v = acc[tm][tn][r] + bv;
                if (epi == 1) v = 1.0f / (1.0f + __expf(-v));
                else if (epi == 2) v = v > 0.f ? v : 0.01f * v;
                C[(size_t)(row + r) * ldC + colOff + col] = f2bf(v);
            }
        }
    }
}

// heterogeneous merged dispatch, grid (6,256):
// swizzled tile-col 0-3: Xa @ wcat2 -> lrelu -> hfin[:,0:256] / t1
// swizzled tile-col 4-5: xbf @ wb_raw + b_raw -> hfin[:,512:768]
__global__ __launch_bounds__(256) void gemmA6_kernel(const unsigned short* __restrict__ Xa,
                                                     const unsigned short* __restrict__ wcat2,
                                                     const unsigned short* __restrict__ xbf,
                                                     const unsigned short* __restrict__ wb_raw,
                                                     const float* __restrict__ b_s1,
                                                     const float* __restrict__ b_s21,
                                                     const float* __restrict__ b_raw,
                                                     unsigned short* __restrict__ hfin,
                                                     unsigned short* __restrict__ t1) {
    const int nx = 6;
    int L = blockIdx.y * nx + blockIdx.x;
    int xcd = L & 7, j = L >> 3;
    int bm = ((j / nx) * 8 + xcd) * 128;
    int bnt = j % nx;
    int sub = (bnt < 4) ? 0 : 1;
    const unsigned short* A = sub ? xbf : Xa;
    const unsigned short* WT = sub ? wb_raw : wcat2;
    int bn = sub ? (bnt - 4) * 128 : bnt * 128;
    GEMM_BODY(256)
#pragma unroll
    for (int tm = 0; tm < 4; tm++) {
        int row = bm + wm + tm * 16 + q * 4;
#pragma unroll
        for (int tn = 0; tn < 4; tn++) {
            int col = bn + wn + tn * 16 + l15;
            if (sub == 0) {
                if (col < 256) {
                    float bv = b_s1[col];
#pragma unroll
                    for (int r = 0; r < 4; r++) {
                        float v = acc[tm][tn][r] + bv;
                        v = v > 0.f ? v : 0.01f * v;
                        hfin[(size_t)(row + r) * 768 + col] = f2bf(v);
                    }
                } else {
                    float bv = b_s21[col - 256];
#pragma unroll
                    for (int r = 0; r < 4; r++) {
                        float v = acc[tm][tn][r] + bv;
                        v = v > 0.f ? v : 0.01f * v;
                        t1[(size_t)(row + r) * 256 + (col - 256)] = f2bf(v);
                    }
                }
            } else {
                float bv = b_raw[col];
#pragma unroll
                for (int r = 0; r < 4; r++)
                    hfin[(size_t)(row + r) * 768 + 512 + col] = f2bf(acc[tm][tn][r] + bv);
            }
        }
    }
}

// ---------------- pure linear GCN aggregation (256-dim) ----------------
__global__ __launch_bounds__(256) void lin_agg_kernel(const unsigned short* __restrict__ h,
                                                      const int* __restrict__ rowptr, const int* __restrict__ srcs,
                                                      const float* __restrict__ dinv,
                                                      unsigned short* __restrict__ out) {
    int wave = threadIdx.x >> 6, lane = threadIdx.x & 63;
    int v = blockIdx.x * 4 + wave;
    int f0 = lane * 4;
    float a0 = 0.f, a1 = 0.f, a2 = 0.f, a3 = 0.f;
    int s = rowptr[v], e = rowptr[v + 1];
    for (int i = s; i < e; i++) {
        int u = srcs[i] & (N_NODES - 1);
        float du = dinv[u];
        uint2 hv = *(const uint2*)(h + (size_t)u * 256 + f0);
        a0 += bf2f((unsigned short)(hv.x & 0xffff)) * du;
        a1 += bf2f((unsigned short)(hv.x >> 16)) * du;
        a2 += bf2f((unsigned short)(hv.y & 0xffff)) * du;
        a3 += bf2f((unsigned short)(hv.y >> 16)) * du;
    }
    float dv = dinv[v], dv2 = dv * dv;
    uint2 sv = *(const uint2*)(h + (size_t)v * 256 + f0);
    float r0 = dv * a0 + bf2f((unsigned short)(sv.x & 0xffff)) * dv2;
    float r1 = dv * a1 + bf2f((unsigned short)(sv.x >> 16)) * dv2;
    float r2 = dv * a2 + bf2f((unsigned short)(sv.y & 0xffff)) * dv2;
    float r3 = dv * a3 + bf2f((unsigned short)(sv.y >> 16)) * dv2;
    uint2 ov = make_uint2(((unsigned)f2bf(r1) << 16) | f2bf(r0), ((unsigned)f2bf(r3) << 16) | f2bf(r2));
    *(uint2*)(out + (size_t)v * 256 + f0) = ov;
}

// ---------------- score matvec ----------------
__global__ __launch_bounds__(256) void score_mv_kernel(const unsigned short* __restrict__ hf,
                                                       const void* __restrict__ wp, const void* __restrict__ wn,
                                                       float* __restrict__ svp, float* __restrict__ svn) {
    int wave = threadIdx.x >> 6, lane = threadIdx.x & 63;
    int v = blockIdx.x * 4 + wave;
    float sp = 0.f, sn = 0.f;
#pragma unroll
    for (int i = 0; i < 3; i++) {
        int k = i * 256 + lane * 4;
        uint2 hv = *(const uint2*)(hf + (size_t)v * 768 + k);
        float x0 = bf2f((unsigned short)(hv.x & 0xffff));
        float x1 = bf2f((unsigned short)(hv.x >> 16));
        float x2 = bf2f((unsigned short)(hv.y & 0xffff));
        float x3 = bf2f((unsigned short)(hv.y >> 16));
        sp += x0 * in_ld(wp, k) + x1 * in_ld(wp, k + 1) + x2 * in_ld(wp, k + 2) + x3 * in_ld(wp, k + 3);
        sn += x0 * in_ld(wn, k) + x1 * in_ld(wn, k + 1) + x2 * in_ld(wn, k + 2) + x3 * in_ld(wn, k + 3);
    }
    for (int off = 32; off >= 1; off >>= 1) {
        sp += __shfl_down(sp, off, 64);
        sn += __shfl_down(sn, off, 64);
    }
    if (lane == 0) { svp[v] = sp; svn[v] = sn; }
}

// ---------------- fused: score aggregation + sigmoid + outputs + dual top-k ----------------
// grid NGRAPH blocks, 512 threads (one node each)
__global__ __launch_bounds__(512) void score_topk_kernel(const float* __restrict__ svp, const float* __restrict__ svn,
                                                         const int* __restrict__ rowptr, const int* __restrict__ srcs,
                                                         const float* __restrict__ dinv,
                                                         const void* __restrict__ bp, const void* __restrict__ bn_,
                                                         unsigned char* __restrict__ maskp,
                                                         unsigned char* __restrict__ maskn,
                                                         void* __restrict__ dout) {
    __shared__ float sp[512], sn[512];
    int g = blockIdx.x, i = threadIdx.x;
    int v = g * 512 + i;
    float ap = 0.f, an = 0.f;
    int s = rowptr[v], e = rowptr[v + 1];
    for (int k = s; k < e; k++) {
        int u = srcs[k] & (N_NODES - 1);
        float du = dinv[u];
        ap += svp[u] * du;
        an += svn[u] * du;
    }
    float dv = dinv[v], dv2 = dv * dv;
    float zp = dv * ap + svp[v] * dv2 + in_ld(bp, 0);
    float zn = dv * an + svn[v] * dv2 + in_ld(bn_, 0);
    float pp = 1.0f / (1.0f + __expf(-zp));
    float pn = 1.0f / (1.0f + __expf(-zn));
    st_out(dout, 1920 + (size_t)v, pp);
    st_out(dout, 1920 + (size_t)N_NODES + v, pn);
    st_out(dout, 1920 + 2 * (size_t)N_NODES + v, (float)g);
    sp[i] = pp; sn[i] = pn;
    __syncthreads();
    int cp = 0, cn = 0;
    for (int j = 0; j < 512; j++) {
        float op = sp[j], on = sn[j];
        cp += (int)((op > pp) || ((op == pp) && (j < i)));
        cn += (int)((on > pn) || ((on == pn) && (j < i)));
    }
    maskp[v] = (cp < TOPK) ? 1 : 0;
    maskn[v] = (cn < TOPK) ? 1 : 0;
}

// ---------------- fused dual-mask readout ----------------
__global__ __launch_bounds__(256) void readout2_kernel(const unsigned short* __restrict__ xt,
                                                       const unsigned char* __restrict__ maskp,
                                                       const unsigned char* __restrict__ maskn,
                                                       float* __restrict__ eout) {
    int g = blockIdx.x;
    int c = blockIdx.y;
    int wv = threadIdx.x >> 6, lane = threadIdx.x & 63;
    int f = c * 64 + lane;
    __shared__ unsigned char mp[512], mn[512];
    __shared__ float red[4][64][4];
    for (int i = threadIdx.x; i < 512; i += 256) {
        mp[i] = maskp[(size_t)g * 512 + i];
        mn[i] = maskn[(size_t)g * 512 + i];
    }
    __syncthreads();
    float sp = 0.f, sn = 0.f, xp = -INFINITY, xn = -INFINITY;
    const unsigned short* base = xt + ((size_t)g * 512 + wv * 128) * 768 + f;
    for (int v = 0; v < 128; v++) {
        unsigned char bp = mp[wv * 128 + v], bn_ = mn[wv * 128 + v];
        if (!(bp | bn_)) continue;
        float x = bf2f(base[(size_t)v * 768]);
        if (bp) { sp += x; xp = fmaxf(xp, x); }
        if (bn_) { sn += x; xn = fmaxf(xn, x); }
    }
    red[wv][lane][0] = sp; red[wv][lane][1] = xp;
    red[wv][lane][2] = sn; red[wv][lane][3] = xn;
    __syncthreads();
    if (wv == 0) {
#pragma unroll
        for (int w = 1; w < 4; w++) {
            sp += red[w][lane][0]; xp = fmaxf(xp, red[w][lane][1]);
            sn += red[w][lane][2]; xn = fmaxf(xn, red[w][lane][3]);
        }
        float* erp = eout + (size_t)g * 1536;
        float* ern = eout + (size_t)(64 + g) * 1536;
        erp[f] = sp * (1.0f / TOPK);
        erp[768 + f] = xp;
        ern[f] = sn * (1.0f / TOPK);
        ern[768 + f] = xn;
    }
}

// ---------------- MLP GEMM, k-split + n-split ----------------
__global__ __launch_bounds__(256) void mlp_gemm2_kernel(const float* __restrict__ in,
                                                        const float* __restrict__ W,
                                                        const float* __restrict__ b,
                                                        float* __restrict__ out, int K) {
    __shared__ float row[1536];
    __shared__ float red[4][64];
    int r = blockIdx.x, cg = blockIdx.y;
    int wv = threadIdx.x >> 6, lane = threadIdx.x & 63;
    int c = cg * 64 + lane;
    for (int k = threadIdx.x; k < K; k += 256) row[k] = in[(size_t)r * K + k];
    __syncthreads();
    int kpw = K >> 2;
    const float* wp = W + (size_t)(wv * kpw) * 256 + c;
    const float* rp = row + wv * kpw;
    float acc = 0.f;
#pragma unroll 4
    for (int k = 0; k < kpw; k++)
        acc += rp[k] * wp[(size_t)k * 256];
    red[wv][lane] = acc;
    __syncthreads();
    if (wv == 0) {
        float v = red[0][lane] + red[1][lane] + red[2][lane] + red[3][lane] + b[c];
        out[(size_t)r * 256 + c] = v;
    }
}

__global__ __launch_bounds__(64) void bn_kernel(const float* __restrict__ z, const void* __restrict__ gamma,
                                                const void* __restrict__ beta, const float* __restrict__ res,
                                                float* __restrict__ out) {
    int f = blockIdx.x & 255, g = blockIdx.x >> 8, r = threadIdx.x;
    size_t idx = (size_t)(g * 64 + r) * 256 + f;
    float x = z[idx];
    float s = x, sq = x * x;
    for (int off = 1; off < 64; off <<= 1) {
        s += __shfl_xor(s, off, 64);
        sq += __shfl_xor(sq, off, 64);
    }
    float m = s * (1.0f / 64.0f);
    float var = sq * (1.0f / 64.0f) - m * m;
    float y = (x - m) * rsqrtf(var + BN_EPS) * in_ld(gamma, f) + in_ld(beta, f);
    y = fmaxf(y, 0.0f);
    if (res) y += res[idx];
    out[idx] = y;
}

// fused logits + softmax: grid 128 (one row), 64 threads
__global__ __launch_bounds__(64) void head_kernel(const float* __restrict__ act, const void* __restrict__ w4,
                                                  const void* __restrict__ b4, void* __restrict__ dout) {
    __shared__ float l[NCLS];
    int r = blockIdx.x, t = threadIdx.x;
    if (t < NCLS) {
        float acc = in_ld(b4, t);
        for (int k = 0; k < 256; k++)
            acc += act[(size_t)r * 256 + k] * in_ld(w4, (size_t)k * NCLS + t);
        l[t] = acc;
    }
    __syncthreads();
    if (t == 0) {
        float mx = -1e30f;
        for (int c = 0; c < NCLS; c++) mx = fmaxf(mx, l[c]);
        float ex[NCLS], sum = 0.f;
        for (int c = 0; c < NCLS; c++) { ex[c] = __expf(l[c] - mx); sum += ex[c]; }
        float inv = 1.0f / sum;
        int g = r >> 6, rr = r & 63;
        if (g == 0) {
            for (int c = 0; c < NCLS; c++) st_out(dout, (size_t)rr * NCLS + c, l[c]);
            for (int c = 0; c < NCLS; c++) st_out(dout, 640 + (size_t)rr * NCLS + c, ex[c] * inv);
        } else {
            for (int c = 0; c < NCLS; c++) st_out(dout, 1280 + (size_t)rr * NCLS + c, ex[c] * inv);
        }
    }
}

// ---------------- host launcher ----------------
extern "C" void kernel_launch(void* const* d_in, const int* in_sizes, int n_in,
                              void* d_out, int out_size, void* d_ws, size_t ws_size,
                              hipStream_t stream) {
    (void)in_sizes; (void)n_in; (void)out_size; (void)ws_size;

    const float* x = (const float*)d_in[0];
    const int* eb = (const int*)d_in[1];
    const float* w_s1 = (const float*)d_in[3];
    const float* b_s1 = (const float*)d_in[4];
    const float* w_s21 = (const float*)d_in[5];
    const float* b_s21 = (const float*)d_in[6];
    const float* w_s22 = (const float*)d_in[7];
    const float* b_s22 = (const float*)d_in[8];
    const float* w_raw = (const float*)d_in[9];
    const float* b_raw = (const float*)d_in[10];
    const void* w_pos = d_in[11];
    const void* b_pos = d_in[12];
    const void* w_neg = d_in[13];
    const void* b_neg = d_in[14];
    const float* w_pool = (const float*)d_in[15];
    const float* b_pool = (const float*)d_in[16];
    const float* w1 = (const float*)d_in[17];  const float* b1 = (const float*)d_in[18];
    const void* g1 = d_in[19];  const void* be1 = d_in[20];
    const float* w2 = (const float*)d_in[21];  const float* b2 = (const float*)d_in[22];
    const void* g2 = d_in[23];  const void* be2 = d_in[24];
    const float* w3 = (const float*)d_in[25];  const float* b3 = (const float*)d_in[26];
    const void* g3 = d_in[27];  const void* be3 = d_in[28];
    const void* w4 = d_in[29];  const void* b4 = d_in[30];

    char* ws = (char*)d_ws;
    size_t off = 0;
    auto alloc = [&](size_t b) -> void* {
        void* p = ws + off;
        off += (b + 255) & ~(size_t)255;
        return p;
    };
    int* flag = (int*)alloc(256);
    int* deg = (int*)alloc((size_t)N_NODES * 4);           // contiguous after flag
    float* dinv = (float*)alloc((size_t)N_NODES * 4);
    int* rowptr = (int*)alloc((size_t)(N_NODES + 1) * 4);
    int* cursor = (int*)alloc((size_t)N_NODES * 4);
    int* srcs = (int*)alloc((size_t)NEDGE * 4);
    unsigned short* xbf = (unsigned short*)alloc((size_t)N_NODES * 256 * 2);
    unsigned short* wcat2 = (unsigned short*)alloc((size_t)512 * 256 * 2);
    unsigned short* wb_s22 = (unsigned short*)alloc((size_t)256 * 256 * 2);
    unsigned short* wb_raw = (unsigned short*)alloc((size_t)256 * 256 * 2);
    unsigned short* wb_pool = (unsigned short*)alloc((size_t)768 * 768 * 2);
    unsigned short* Xa = (unsigned short*)alloc((size_t)N_NODES * 256 * 2);
    unsigned short* t1 = (unsigned short*)alloc((size_t)N_NODES * 256 * 2);
    unsigned short* t1a = (unsigned short*)alloc((size_t)N_NODES * 256 * 2);
    unsigned short* hfin = (unsigned short*)alloc((size_t)N_NODES * 768 * 2);
    unsigned short* xt = (unsigned short*)alloc((size_t)N_NODES * 768 * 2);
    float* svp = (float*)alloc((size_t)N_NODES * 4);
    float* svn = (float*)alloc((size_t)N_NODES * 4);
    unsigned char* maskp = (unsigned char*)alloc(N_NODES);
    unsigned char* maskn = (unsigned char*)alloc(N_NODES);
    float* ebuf = (float*)alloc((size_t)128 * 1536 * 4);
    float* zb = (float*)alloc((size_t)128 * 256 * 4);
    float* act1 = (float*)alloc((size_t)128 * 256 * 4);
    float* act2 = (float*)alloc((size_t)128 * 256 * 4);
    float* act3 = (float*)alloc((size_t)128 * 256 * 4);

    // flag + deg are contiguous: one memset covers both
    hipMemsetAsync(flag, 0, 256 + (size_t)N_NODES * 4, stream);

    detect_kernel<<<NEDGE / 256, 256, 0, stream>>>(eb, flag);
    hist_kernel<<<NEDGE / 256, 256, 0, stream>>>(eb, flag, deg);
    scan_kernel<<<1, 1024, 0, stream>>>(deg, rowptr, cursor, dinv);
    scatter_kernel<<<NEDGE / 256, 256, 0, stream>>>(eb, flag, cursor, srcs);

    cvt_all_kernel<<<4928, 256, 0, stream>>>(x, w_s1, w_s21, w_s22, w_raw, w_pool,
                                             xbf, wcat2, wb_s22, wb_raw, wb_pool);

    dim3 gA6(6, N_NODES / 128);          // merged Xa-gemm + raw-gemm
    dim3 gA1(2, N_NODES / 128);
    dim3 gP(6, N_NODES / 128);

    // GCN pipeline (linearity-restructured)
    lin_agg_kernel<<<N_NODES / 4, 256, 0, stream>>>(xbf, rowptr, srcs, dinv, Xa);
    gemmA6_kernel<<<gA6, 256, 0, stream>>>(Xa, wcat2, xbf, wb_raw, b_s1, b_s21, b_raw, hfin, t1);
    lin_agg_kernel<<<N_NODES / 4, 256, 0, stream>>>(t1, rowptr, srcs, dinv, t1a);
    gemm_kernel<<<gA1, 256, 0, stream>>>(t1a, wb_s22, b_s22, hfin, 256, 768, 256, 2);
    // pool (N=768, proven 64 µs shape)
    gemm_kernel<<<gP, 256, 0, stream>>>(hfin, wb_pool, b_pool, xt, 768, 768, 0, 1);
    // scores + top-k (fused) + readout
    score_mv_kernel<<<N_NODES / 4, 256, 0, stream>>>(hfin, w_pos, w_neg, svp, svn);
    score_topk_kernel<<<NGRAPH, 512, 0, stream>>>(svp, svn, rowptr, srcs, dinv, b_pos, b_neg,
                                                  maskp, maskn, d_out);
    {
        dim3 gR(NGRAPH, FDIM / 64);
        readout2_kernel<<<gR, 256, 0, stream>>>(xt, maskp, maskn, ebuf);
    }
    // MLP
    {
        dim3 gM(128, 4);
        mlp_gemm2_kernel<<<gM, 256, 0, stream>>>(ebuf, w1, b1, zb, 1536);
        bn_kernel<<<512, 64, 0, stream>>>(zb, g1, be1, nullptr, act1);
        mlp_gemm2_kernel<<<gM, 256, 0, stream>>>(act1, w2, b2, zb, 256);
        bn_kernel<<<512, 64, 0, stream>>>(zb, g2, be2, act1, act2);
        mlp_gemm2_kernel<<<gM, 256, 0, stream>>>(act2, w3, b3, zb, 256);
        bn_kernel<<<512, 64, 0, stream>>>(zb, g3, be3, act2, act3);
    }
    head_kernel<<<128, 64, 0, stream>>>(act3, w4, b4, d_out);
}